// Round 2
// baseline (19194.495 us; speedup 1.0000x reference)
//
#include <hip/hip_runtime.h>
#include <cmath>

// LightGlue forward, fp32. N=1024 tokens, D=256, H=4 heads, DH=64, L=9 layers.
#define NTOK 1024
#define DM   256
#define NH   4
#define DH   64
#define NL   9

__device__ __forceinline__ float logsigf(float x) {
    // log(sigmoid(x)) = min(x,0) - log1p(exp(-|x|))
    return fminf(x, 0.0f) - log1pf(expf(-fabsf(x)));
}

// ---------------------------------------------------------------------------
// Generic tiled GEMM: C[M x Nn] = (A[M x K] @ B + bias) * scale + R
// B is [K x Nn] (transB=0) or [Nn x K] (transB=1, i.e. C = A @ B^T).
// C written with leading dim ldc (lets us write into concat buffers).
// R (residual, optional) has leading dim Nn. bias optional.
// Block: 256 threads, 64x64 tile, 4x4 per thread, BK=16.
// ---------------------------------------------------------------------------
__global__ __launch_bounds__(256) void gemm_k(
    const float* __restrict__ A, const float* __restrict__ B,
    const float* __restrict__ bias, const float* __restrict__ R,
    float* __restrict__ C, int M, int K, int Nn, int ldc,
    float scale, int transB)
{
    __shared__ float As[64][17];
    __shared__ float Bs[16][65];
    const int tid = threadIdx.x;
    const int tx = tid & 15, ty = tid >> 4;
    const int row0 = blockIdx.y * 64, col0 = blockIdx.x * 64;
    float acc[4][4] = {};

    for (int k0 = 0; k0 < K; k0 += 16) {
        #pragma unroll
        for (int i = 0; i < 4; ++i) {
            int idx = tid + i * 256;
            int r = idx >> 4, c = idx & 15;
            As[r][c] = A[(size_t)(row0 + r) * K + k0 + c];
        }
        if (!transB) {
            #pragma unroll
            for (int i = 0; i < 4; ++i) {
                int idx = tid + i * 256;
                int r = idx >> 6, c = idx & 63;
                Bs[r][c] = B[(size_t)(k0 + r) * Nn + col0 + c];
            }
        } else {
            #pragma unroll
            for (int i = 0; i < 4; ++i) {
                int idx = tid + i * 256;
                int r = idx & 15, c = idx >> 4;   // consecutive tid -> consecutive k (coalesced)
                Bs[r][c] = B[(size_t)(col0 + c) * K + k0 + r];
            }
        }
        __syncthreads();
        #pragma unroll
        for (int kk = 0; kk < 16; ++kk) {
            float a[4], w[4];
            #pragma unroll
            for (int i = 0; i < 4; ++i) a[i] = As[ty * 4 + i][kk];
            #pragma unroll
            for (int j = 0; j < 4; ++j) w[j] = Bs[kk][tx * 4 + j];
            #pragma unroll
            for (int i = 0; i < 4; ++i)
                #pragma unroll
                for (int j = 0; j < 4; ++j)
                    acc[i][j] = fmaf(a[i], w[j], acc[i][j]);
        }
        __syncthreads();
    }
    #pragma unroll
    for (int i = 0; i < 4; ++i) {
        int r = row0 + ty * 4 + i;
        #pragma unroll
        for (int j = 0; j < 4; ++j) {
            int c = col0 + tx * 4 + j;
            float v = acc[i][j];
            if (bias) v += bias[c];
            v *= scale;
            if (R) v += R[(size_t)r * Nn + c];
            C[(size_t)r * ldc + c] = v;
        }
    }
}

// ---------------------------------------------------------------------------
// Positional encoding: proj = kpts @ Wr (2 -> 32), enc{c,s}[n][2f]=enc[n][2f+1]
// ---------------------------------------------------------------------------
__global__ __launch_bounds__(256) void posenc_k(
    const float* __restrict__ kpts, const float* __restrict__ Wr,
    float* __restrict__ encc, float* __restrict__ encs)
{
    int idx = blockIdx.x * 256 + threadIdx.x;          // N*32
    if (idx >= NTOK * 32) return;
    int i = idx >> 5, f = idx & 31;
    float p = kpts[i * 2 + 0] * Wr[f] + kpts[i * 2 + 1] * Wr[32 + f];
    float c = cosf(p), s = sinf(p);
    encc[i * 64 + 2 * f]     = c;  encc[i * 64 + 2 * f + 1] = c;
    encs[i * 64 + 2 * f]     = s;  encs[i * 64 + 2 * f + 1] = s;
}

// ---------------------------------------------------------------------------
// Split qkv [N x 768] (col = h*192 + d*3 + {q,k,v}) into head-major q/k/v
// [H][N][64], applying RoPE to q and k.
// rope: out[2i] = t[2i]*c - t[2i+1]*s ; out[2i+1] = t[2i+1]*c + t[2i]*s
// ---------------------------------------------------------------------------
__global__ __launch_bounds__(256) void splitrope_k(
    const float* __restrict__ qkv, const float* __restrict__ encc,
    const float* __restrict__ encs, float* __restrict__ qh,
    float* __restrict__ kh, float* __restrict__ vh)
{
    int n = blockIdx.x, t = threadIdx.x;  // t = h*64 + d
    int h = t >> 6, d = t & 63;
    const float* base  = qkv + (size_t)n * 768 + h * 192 + d * 3;
    const float* pbase = qkv + (size_t)n * 768 + h * 192 + (d ^ 1) * 3;
    float c = encc[n * 64 + d], s = encs[n * 64 + d];
    float q = base[0], k = base[1], v = base[2];
    float qp = pbase[0], kp = pbase[1];
    float sgn = (d & 1) ? 1.0f : -1.0f;
    size_t o = ((size_t)h * NTOK + n) * 64 + d;
    qh[o] = q * c + sgn * qp * s;
    kh[o] = k * c + sgn * kp * s;
    vh[o] = v;
}

// Split [N x 256] (col = h*64+d) into head-major [H][N][64] with scale.
__global__ __launch_bounds__(256) void splitscale_k(
    const float* __restrict__ x, float* __restrict__ oh, float scale)
{
    int n = blockIdx.x, t = threadIdx.x;
    int h = t >> 6, d = t & 63;
    oh[((size_t)h * NTOK + n) * 64 + d] = x[(size_t)n * 256 + t] * scale;
}

// cat[:, 0:256] = x  (cat leading dim 512)
__global__ __launch_bounds__(256) void copycat_k(
    const float* __restrict__ x, float* __restrict__ cat)
{
    int n = blockIdx.x, t = threadIdx.x;
    cat[(size_t)n * 512 + t] = x[(size_t)n * 256 + t];
}

__global__ __launch_bounds__(256) void copyvec_k(
    float* __restrict__ dst, const float* __restrict__ src, int n)
{
    int i = blockIdx.x * 256 + threadIdx.x;
    if (i < n) dst[i] = src[i];
}

// ---------------------------------------------------------------------------
// Fused attention row: out[i, h*64+d] = sum_j softmax_j(q_i . k_j * scale) v_j[d]
// Block per (query i, head h). Scores kept in LDS.
// Used for self-attn (scale = DH^-0.5) and both cross directions (scale = 1,
// DH^-0.25 baked into qk projections).
// ---------------------------------------------------------------------------
__global__ __launch_bounds__(256) void attn_k(
    const float* __restrict__ qh, const float* __restrict__ kh,
    const float* __restrict__ vh, float* __restrict__ out, float scale)
{
    const int i = blockIdx.x, h = blockIdx.y, t = threadIdx.x;
    __shared__ float sq[64];
    __shared__ float sc[NTOK];
    __shared__ float red[256];
    if (t < 64) sq[t] = qh[((size_t)h * NTOK + i) * 64 + t];
    __syncthreads();

    const float4* sq4 = (const float4*)sq;
    float lmax = -1e30f;
    for (int j = t; j < NTOK; j += 256) {
        const float4* kp = (const float4*)(kh + ((size_t)h * NTOK + j) * 64);
        float acc = 0.0f;
        #pragma unroll
        for (int d = 0; d < 16; ++d) {
            float4 a = sq4[d], b = kp[d];
            acc += a.x * b.x + a.y * b.y + a.z * b.z + a.w * b.w;
        }
        acc *= scale;
        sc[j] = acc;
        lmax = fmaxf(lmax, acc);
    }
    red[t] = lmax; __syncthreads();
    for (int s = 128; s > 0; s >>= 1) {
        if (t < s) red[t] = fmaxf(red[t], red[t + s]);
        __syncthreads();
    }
    float mx = red[0]; __syncthreads();

    float lsum = 0.0f;
    for (int j = t; j < NTOK; j += 256) {
        float e = expf(sc[j] - mx);
        sc[j] = e; lsum += e;
    }
    red[t] = lsum; __syncthreads();
    for (int s = 128; s > 0; s >>= 1) {
        if (t < s) red[t] += red[t + s];
        __syncthreads();
    }
    float inv = 1.0f / red[0]; __syncthreads();

    // weighted V sum: thread t -> dim d = t&63, j-group jg = t>>6 (stride 4)
    int d = t & 63, jg = t >> 6;
    float acc = 0.0f;
    for (int j = jg; j < NTOK; j += 4)
        acc += sc[j] * vh[((size_t)h * NTOK + j) * 64 + d];
    red[t] = acc; __syncthreads();
    if (t < 64) {
        float o = (red[t] + red[t + 64] + red[t + 128] + red[t + 192]) * inv;
        out[(size_t)i * 256 + h * 64 + d] = o;
    }
}

// ---------------------------------------------------------------------------
// In-place LayerNorm (512 dims) + exact GELU. Block per row, 256 threads.
// ---------------------------------------------------------------------------
__global__ __launch_bounds__(256) void lngelu_k(
    float* __restrict__ x, const float* __restrict__ g,
    const float* __restrict__ beta)
{
    int row = blockIdx.x, t = threadIdx.x;
    __shared__ float red[256];
    float v0 = x[(size_t)row * 512 + t];
    float v1 = x[(size_t)row * 512 + t + 256];
    red[t] = v0 + v1; __syncthreads();
    for (int s = 128; s > 0; s >>= 1) {
        if (t < s) red[t] += red[t + s];
        __syncthreads();
    }
    float mu = red[0] * (1.0f / 512.0f); __syncthreads();
    float d0 = v0 - mu, d1 = v1 - mu;
    red[t] = d0 * d0 + d1 * d1; __syncthreads();
    for (int s = 128; s > 0; s >>= 1) {
        if (t < s) red[t] += red[t + s];
        __syncthreads();
    }
    float rstd = rsqrtf(red[0] * (1.0f / 512.0f) + 1e-5f);
    float y = d0 * rstd * g[t] + beta[t];
    x[(size_t)row * 512 + t] = 0.5f * y * (1.0f + erff(y * 0.70710678118654752f));
    y = d1 * rstd * g[t + 256] + beta[t + 256];
    x[(size_t)row * 512 + t + 256] = 0.5f * y * (1.0f + erff(y * 0.70710678118654752f));
}

// z[i] = dot(x[i], Wz) + bz[0]
__global__ __launch_bounds__(256) void z_k(
    const float* __restrict__ x, const float* __restrict__ Wz,
    const float* __restrict__ bz, float* __restrict__ z)
{
    int row = blockIdx.x, t = threadIdx.x;
    __shared__ float red[256];
    red[t] = x[(size_t)row * 256 + t] * Wz[t];
    __syncthreads();
    for (int s = 128; s > 0; s >>= 1) {
        if (t < s) red[t] += red[t + s];
        __syncthreads();
    }
    if (t == 0) z[row] = red[0] + bz[0];
}

// Row / column logsumexp of sim [N x N]
__global__ __launch_bounds__(256) void rowlse_k(
    const float* __restrict__ sim, float* __restrict__ out)
{
    int row = blockIdx.x, t = threadIdx.x;
    __shared__ float red[256];
    float mx = -1e30f;
    for (int j = t; j < NTOK; j += 256) mx = fmaxf(mx, sim[(size_t)row * NTOK + j]);
    red[t] = mx; __syncthreads();
    for (int s = 128; s > 0; s >>= 1) {
        if (t < s) red[t] = fmaxf(red[t], red[t + s]);
        __syncthreads();
    }
    mx = red[0]; __syncthreads();
    float sum = 0.0f;
    for (int j = t; j < NTOK; j += 256) sum += expf(sim[(size_t)row * NTOK + j] - mx);
    red[t] = sum; __syncthreads();
    for (int s = 128; s > 0; s >>= 1) {
        if (t < s) red[t] += red[t + s];
        __syncthreads();
    }
    if (t == 0) out[row] = mx + logf(red[0]);
}

__global__ __launch_bounds__(256) void collse_k(
    const float* __restrict__ sim, float* __restrict__ out)
{
    int col = blockIdx.x, t = threadIdx.x;
    __shared__ float red[256];
    float mx = -1e30f;
    for (int i = t; i < NTOK; i += 256) mx = fmaxf(mx, sim[(size_t)i * NTOK + col]);
    red[t] = mx; __syncthreads();
    for (int s = 128; s > 0; s >>= 1) {
        if (t < s) red[t] = fmaxf(red[t], red[t + s]);
        __syncthreads();
    }
    mx = red[0]; __syncthreads();
    float sum = 0.0f;
    for (int i = t; i < NTOK; i += 256) sum += expf(sim[(size_t)i * NTOK + col] - mx);
    red[t] = sum; __syncthreads();
    for (int s = 128; s > 0; s >>= 1) {
        if (t < s) red[t] += red[t + s];
        __syncthreads();
    }
    if (t == 0) out[col] = mx + logf(red[0]);
}

// Final (N+1)x(N+1) assembly
// inner = log_softmax(sim,-1) + log_softmax(sim,-2) + cert
//       = 2*sim - rowlse[i] - collse[j] + logsig(z0[i]) + logsig(z1[j])
__global__ __launch_bounds__(256) void assemble_k(
    const float* __restrict__ sim, const float* __restrict__ rls,
    const float* __restrict__ cls, const float* __restrict__ z0,
    const float* __restrict__ z1, float* __restrict__ out)
{
    int idx = blockIdx.x * 256 + threadIdx.x;
    const int W = NTOK + 1;
    if (idx >= W * W) return;
    int i = idx / W, j = idx % W;
    float v;
    if (i < NTOK && j < NTOK) {
        v = 2.0f * sim[(size_t)i * NTOK + j] - rls[i] - cls[j] + logsigf(z0[i]) + logsigf(z1[j]);
    } else if (i < NTOK) {
        v = logsigf(-z0[i]);
    } else if (j < NTOK) {
        v = logsigf(-z1[j]);
    } else {
        v = 0.0f;
    }
    out[idx] = v;
}

// ---------------------------------------------------------------------------
extern "C" void kernel_launch(void* const* d_in, const int* in_sizes, int n_in,
                              void* d_out, int out_size, void* d_ws, size_t ws_size,
                              hipStream_t stream)
{
    const float* desc0 = (const float*)d_in[0];
    const float* desc1 = (const float*)d_in[1];
    const float* kpts0 = (const float*)d_in[2];
    const float* kpts1 = (const float*)d_in[3];
    const float* Wr    = (const float*)d_in[4];
    const float* sWqkv = (const float*)d_in[5];
    const float* sbqkv = (const float*)d_in[6];
    const float* sWo   = (const float*)d_in[7];
    const float* sbo   = (const float*)d_in[8];
    const float* sfW1  = (const float*)d_in[9];
    const float* sfb1  = (const float*)d_in[10];
    const float* sfg   = (const float*)d_in[11];
    const float* sfbt  = (const float*)d_in[12];
    const float* sfW2  = (const float*)d_in[13];
    const float* sfb2  = (const float*)d_in[14];
    const float* cWqk  = (const float*)d_in[15];
    const float* cbqk  = (const float*)d_in[16];
    const float* cWv   = (const float*)d_in[17];
    const float* cbv   = (const float*)d_in[18];
    const float* cWo   = (const float*)d_in[19];
    const float* cbo   = (const float*)d_in[20];
    const float* cfW1  = (const float*)d_in[21];
    const float* cfb1  = (const float*)d_in[22];
    const float* cfg   = (const float*)d_in[23];
    const float* cfbt  = (const float*)d_in[24];
    const float* cfW2  = (const float*)d_in[25];
    const float* cfb2  = (const float*)d_in[26];
    const float* mWp   = (const float*)d_in[27];
    const float* mbp   = (const float*)d_in[28];
    const float* mWz   = (const float*)d_in[29];
    const float* mbz   = (const float*)d_in[30];

    float* ws = (float*)d_ws;
    // Workspace layout (floats). Total ~4.2M floats = ~16.8 MB.
    float* x0    = ws + 0;                 // 262144
    float* x1    = ws + 262144;            // 262144
    float* enc0c = ws + 524288;            // 65536
    float* enc0s = ws + 589824;
    float* enc1c = ws + 655360;
    float* enc1s = ws + 720896;
    float* qkv   = ws + 786432;            // 786432 (also cross 'tmp')
    float* qh    = ws + 1572864;           // 262144 (cross qk0h; assignment: sim base)
    float* kh    = ws + 1835008;           // 262144 (cross qk1h)
    float* vh    = ws + 2097152;           // 262144 (cross v0h)
    float* v2h   = ws + 2359296;           // 262144 (cross v1h)
    float* msg0  = ws + 2621440;           // 262144 (assignment: md0)
    float* msg1  = ws + 2883584;           // 262144 (assignment: md1)
    float* cat   = ws + 3145728;           // 524288
    float* pre   = ws + 3670016;           // 524288
    float* z0b   = ws + 4194304;           // 1024
    float* z1b   = ws + 4195328;           // 1024
    float* rlsb  = ws + 4196352;           // 1024
    float* clsb  = ws + 4197376;           // 1024
    float* sim   = qh;                     // 1048576 (aliases qh..v2h, layers done)
    float* md0   = msg0;
    float* md1   = msg1;

    auto gemm = [&](const float* A, const float* B, const float* bias,
                    const float* R, float* C, int M, int K, int Nn, int ldc,
                    float scale, int transB) {
        dim3 g(Nn / 64, M / 64);
        gemm_k<<<g, 256, 0, stream>>>(A, B, bias, R, C, M, K, Nn, ldc, scale, transB);
    };

    const float SELF_SCALE  = 0.125f;          // DH^-0.5
    const float CROSS_SCALE = 0.35355339059327373f; // DH^-0.25

    copyvec_k<<<(NTOK * DM + 255) / 256, 256, 0, stream>>>(x0, desc0, NTOK * DM);
    copyvec_k<<<(NTOK * DM + 255) / 256, 256, 0, stream>>>(x1, desc1, NTOK * DM);
    posenc_k<<<(NTOK * 32 + 255) / 256, 256, 0, stream>>>(kpts0, Wr, enc0c, enc0s);
    posenc_k<<<(NTOK * 32 + 255) / 256, 256, 0, stream>>>(kpts1, Wr, enc1c, enc1s);

    for (int l = 0; l < NL; ++l) {
        const float* Wqkv_l = sWqkv + (size_t)l * 256 * 768;
        const float* bqkv_l = sbqkv + (size_t)l * 768;
        const float* sWo_l  = sWo  + (size_t)l * 256 * 256;
        const float* sbo_l  = sbo  + (size_t)l * 256;
        const float* sW1_l  = sfW1 + (size_t)l * 512 * 512;
        const float* sb1_l  = sfb1 + (size_t)l * 512;
        const float* sg_l   = sfg  + (size_t)l * 512;
        const float* sbt_l  = sfbt + (size_t)l * 512;
        const float* sW2_l  = sfW2 + (size_t)l * 512 * 256;
        const float* sb2_l  = sfb2 + (size_t)l * 256;

        // ---- self blocks (image 0, image 1) ----
        for (int im = 0; im < 2; ++im) {
            float* x  = im ? x1 : x0;
            const float* ec = im ? enc1c : enc0c;
            const float* es = im ? enc1s : enc0s;
            copycat_k<<<NTOK, 256, 0, stream>>>(x, cat);
            gemm(x, Wqkv_l, bqkv_l, nullptr, qkv, NTOK, 256, 768, 768, 1.0f, 0);
            splitrope_k<<<NTOK, 256, 0, stream>>>(qkv, ec, es, qh, kh, vh);
            attn_k<<<dim3(NTOK, NH), 256, 0, stream>>>(qh, kh, vh, msg0, SELF_SCALE);
            gemm(msg0, sWo_l, sbo_l, nullptr, cat + 256, NTOK, 256, 256, 512, 1.0f, 0);
            gemm(cat, sW1_l, sb1_l, nullptr, pre, NTOK, 512, 512, 512, 1.0f, 0);
            lngelu_k<<<NTOK, 256, 0, stream>>>(pre, sg_l, sbt_l);
            gemm(pre, sW2_l, sb2_l, x, x, NTOK, 512, 256, 256, 1.0f, 0);
        }

        // ---- cross block ----
        const float* Wqk_l = cWqk + (size_t)l * 256 * 256;
        const float* bqk_l = cbqk + (size_t)l * 256;
        const float* Wv_l  = cWv  + (size_t)l * 256 * 256;
        const float* bv_l  = cbv  + (size_t)l * 256;
        const float* cWo_l = cWo  + (size_t)l * 256 * 256;
        const float* cbo_l = cbo  + (size_t)l * 256;
        const float* cW1_l = cfW1 + (size_t)l * 512 * 512;
        const float* cb1_l = cfb1 + (size_t)l * 512;
        const float* cg_l  = cfg  + (size_t)l * 512;
        const float* cbt_l = cfbt + (size_t)l * 512;
        const float* cW2_l = cfW2 + (size_t)l * 512 * 256;
        const float* cb2_l = cfb2 + (size_t)l * 256;

        float* tmp = qkv;
        gemm(x0, Wqk_l, bqk_l, nullptr, tmp, NTOK, 256, 256, 256, 1.0f, 0);
        splitscale_k<<<NTOK, 256, 0, stream>>>(tmp, qh, CROSS_SCALE);   // qk0
        gemm(x1, Wqk_l, bqk_l, nullptr, tmp, NTOK, 256, 256, 256, 1.0f, 0);
        splitscale_k<<<NTOK, 256, 0, stream>>>(tmp, kh, CROSS_SCALE);   // qk1
        gemm(x0, Wv_l, bv_l, nullptr, tmp, NTOK, 256, 256, 256, 1.0f, 0);
        splitscale_k<<<NTOK, 256, 0, stream>>>(tmp, vh, 1.0f);          // v0
        gemm(x1, Wv_l, bv_l, nullptr, tmp, NTOK, 256, 256, 256, 1.0f, 0);
        splitscale_k<<<NTOK, 256, 0, stream>>>(tmp, v2h, 1.0f);         // v1

        // m0[i] = sum_j softmax_j(qk0_i . qk1_j) v1[j]
        attn_k<<<dim3(NTOK, NH), 256, 0, stream>>>(qh, kh, v2h, msg0, 1.0f);
        // m1[j] = sum_i softmax_i(qk1_j . qk0_i) v0[i]
        attn_k<<<dim3(NTOK, NH), 256, 0, stream>>>(kh, qh, vh, msg1, 1.0f);

        for (int im = 0; im < 2; ++im) {
            float* x = im ? x1 : x0;
            float* m = im ? msg1 : msg0;
            copycat_k<<<NTOK, 256, 0, stream>>>(x, cat);
            gemm(m, cWo_l, cbo_l, nullptr, cat + 256, NTOK, 256, 256, 512, 1.0f, 0);
            gemm(cat, cW1_l, cb1_l, nullptr, pre, NTOK, 512, 512, 512, 1.0f, 0);
            lngelu_k<<<NTOK, 256, 0, stream>>>(pre, cg_l, cbt_l);
            gemm(pre, cW2_l, cb2_l, x, x, NTOK, 512, 256, 256, 1.0f, 0);
        }
    }

    // ---- assignment head ----
    const float MD_SCALE = 0.25f; // D^-0.25
    gemm(x0, mWp, mbp, nullptr, md0, NTOK, 256, 256, 256, MD_SCALE, 0);
    gemm(x1, mWp, mbp, nullptr, md1, NTOK, 256, 256, 256, MD_SCALE, 0);
    gemm(md0, md1, nullptr, nullptr, sim, NTOK, 256, NTOK, NTOK, 1.0f, 1); // sim = md0 @ md1^T
    z_k<<<NTOK, 256, 0, stream>>>(x0, mWz, mbz, z0b);
    z_k<<<NTOK, 256, 0, stream>>>(x1, mWz, mbz, z1b);
    rowlse_k<<<NTOK, 256, 0, stream>>>(sim, rlsb);
    collse_k<<<NTOK, 256, 0, stream>>>(sim, clsb);
    const int W = NTOK + 1;
    assemble_k<<<(W * W + 255) / 256, 256, 0, stream>>>(sim, rlsb, clsb, z0b, z1b, (float*)d_out);
}

// Round 3
// 8602.542 us; speedup vs baseline: 2.2313x; 2.2313x over previous
//
#include <hip/hip_runtime.h>
#include <cmath>

// LightGlue forward, fp32, image-batched (M=2048). N=1024, D=256, H=4, DH=64, L=9.
#define NTOK 1024
#define DM   256
#define NH   4
#define DH   64
#define NL   9

__device__ __forceinline__ float logsigf(float x) {
    return fminf(x, 0.0f) - log1pf(expf(-fabsf(x)));
}

// ---------------------------------------------------------------------------
// GEMM v2: C[M x Nn] = (A @ B + bias) * scale + R
// A: dual-source concat (A1 != null -> cols 0-255 from A0 ld 256, cols 256+ from
//    A1 ld 256), else A0 with lda = K.
// B: [K x Nn] or (transB) [Nn x K].
// Store: plain row-major ldc, or headmajor (out[((im*4+h)*1024+n)*64+d], Nn=256).
// Tile TM x 64, BK=16, 256 threads, micro (TM/16) x 4 per thread.
// A-tile staged K-transposed -> inner loop reads are contiguous float4/float2.
// ---------------------------------------------------------------------------
template<int TM>
__global__ __launch_bounds__(256) void gemm_k(
    const float* __restrict__ A0, const float* __restrict__ A1,
    const float* __restrict__ B, const float* __restrict__ bias,
    const float* __restrict__ R, float* __restrict__ C,
    int M, int K, int Nn, int ldc, float scale, int transB, int headmajor)
{
    constexpr int RPT = TM / 16;              // rows per thread
    __shared__ float As[16][TM + 4];          // [k][row]
    __shared__ float Bs[16][68];              // [k][col]
    const int tid = threadIdx.x;
    const int tx = tid & 15, ty = tid >> 4;
    const int row0 = blockIdx.y * TM, col0 = blockIdx.x * 64;
    float acc[RPT][4] = {};

    for (int k0 = 0; k0 < K; k0 += 16) {
        #pragma unroll
        for (int i = 0; i < TM * 16 / 256; ++i) {
            int idx = tid + i * 256;
            int r = idx >> 4, c = idx & 15;
            float v;
            if (A1) {
                int kk = k0 + c;
                v = (kk < 256) ? A0[(size_t)(row0 + r) * 256 + kk]
                               : A1[(size_t)(row0 + r) * 256 + (kk - 256)];
            } else {
                v = A0[(size_t)(row0 + r) * K + k0 + c];
            }
            As[c][r] = v;
        }
        if (!transB) {
            #pragma unroll
            for (int i = 0; i < 4; ++i) {
                int idx = tid + i * 256;
                int r = idx >> 6, c = idx & 63;
                Bs[r][c] = B[(size_t)(k0 + r) * Nn + col0 + c];
            }
        } else {
            #pragma unroll
            for (int i = 0; i < 4; ++i) {
                int idx = tid + i * 256;
                int r = idx & 15, c = idx >> 4;   // consecutive tid -> consecutive k
                Bs[r][c] = B[(size_t)(col0 + c) * K + k0 + r];
            }
        }
        __syncthreads();
        #pragma unroll
        for (int kk = 0; kk < 16; ++kk) {
            float w[4];
            *(float4*)w = *(const float4*)&Bs[kk][tx * 4];
            float a[RPT];
            #pragma unroll
            for (int i = 0; i < RPT; ++i) a[i] = As[kk][ty * RPT + i];
            #pragma unroll
            for (int i = 0; i < RPT; ++i)
                #pragma unroll
                for (int j = 0; j < 4; ++j)
                    acc[i][j] = fmaf(a[i], w[j], acc[i][j]);
        }
        __syncthreads();
    }

    float bv[4] = {0, 0, 0, 0};
    if (bias) *(float4*)bv = *(const float4*)&bias[col0 + tx * 4];
    #pragma unroll
    for (int i = 0; i < RPT; ++i) {
        int r = row0 + ty * RPT + i;
        int c0 = col0 + tx * 4;
        float4 v;
        v.x = (acc[i][0] + bv[0]) * scale;
        v.y = (acc[i][1] + bv[1]) * scale;
        v.z = (acc[i][2] + bv[2]) * scale;
        v.w = (acc[i][3] + bv[3]) * scale;
        if (R) {
            float4 rv = *(const float4*)&R[(size_t)r * Nn + c0];
            v.x += rv.x; v.y += rv.y; v.z += rv.z; v.w += rv.w;
        }
        if (headmajor) {
            int h = c0 >> 6, d = c0 & 63, im = r >> 10, n = r & 1023;
            *(float4*)&C[(((size_t)(im * 4 + h)) * 1024 + n) * 64 + d] = v;
        } else {
            *(float4*)&C[(size_t)r * ldc + c0] = v;
        }
    }
}

// ---------------------------------------------------------------------------
// Positional encoding for one image: proj = kpts @ Wr (2->32), repeat x2.
// enc buffers are [2048][64]; this writes rows [im*1024, im*1024+1024).
// ---------------------------------------------------------------------------
__global__ __launch_bounds__(256) void posenc_k(
    const float* __restrict__ kpts, const float* __restrict__ Wr,
    float* __restrict__ encc, float* __restrict__ encs)
{
    int idx = blockIdx.x * 256 + threadIdx.x;          // N*32
    if (idx >= NTOK * 32) return;
    int i = idx >> 5, f = idx & 31;
    float p = kpts[i * 2 + 0] * Wr[f] + kpts[i * 2 + 1] * Wr[32 + f];
    float c = cosf(p), s = sinf(p);
    encc[i * 64 + 2 * f]     = c;  encc[i * 64 + 2 * f + 1] = c;
    encs[i * 64 + 2 * f]     = s;  encs[i * 64 + 2 * f + 1] = s;
}

// ---------------------------------------------------------------------------
// Split qkv [2048 x 768] (col = h*192 + d*3 + {q,k,v}) into vhead-major
// [8][1024][64] (vhead = im*4+h), applying RoPE to q and k.
// ---------------------------------------------------------------------------
__global__ __launch_bounds__(256) void splitrope_k(
    const float* __restrict__ qkv, const float* __restrict__ encc,
    const float* __restrict__ encs, float* __restrict__ qh,
    float* __restrict__ kh, float* __restrict__ vh)
{
    int n = blockIdx.x, t = threadIdx.x;  // n: 0..2047, t = h*64 + d
    int h = t >> 6, d = t & 63;
    int im = n >> 10, nl = n & 1023;
    const float* base  = qkv + (size_t)n * 768 + h * 192 + d * 3;
    const float* pbase = qkv + (size_t)n * 768 + h * 192 + (d ^ 1) * 3;
    float c = encc[n * 64 + d], s = encs[n * 64 + d];
    float q = base[0], k = base[1], v = base[2];
    float qp = pbase[0], kp = pbase[1];
    float sgn = (d & 1) ? 1.0f : -1.0f;
    size_t o = (((size_t)(im * 4 + h)) * 1024 + nl) * 64 + d;
    qh[o] = q * c + sgn * qp * s;
    kh[o] = k * c + sgn * kp * s;
    vh[o] = v;
}

__global__ __launch_bounds__(256) void copyvec_k(
    float* __restrict__ dst, const float* __restrict__ src, int n)
{
    int i = blockIdx.x * 256 + threadIdx.x;
    if (i < n) dst[i] = src[i];
}

// ---------------------------------------------------------------------------
// Attention v2: block = (16-query tile, head, image/dir). 256 threads.
// Wave-private q-rows (qi = t>>4 stays inside one wave) -> no __syncthreads.
// heads_q/heads_k: score operands (self: q,k; cross: qk,qk with kv image
// flipped). heads_v: values. out: [2048][256] row-major, row = z*1024 + n.
// ---------------------------------------------------------------------------
__global__ __launch_bounds__(256) void attn_k(
    const float* __restrict__ heads_q, const float* __restrict__ heads_k,
    const float* __restrict__ heads_v, float* __restrict__ out,
    float scale, int cross)
{
    const int qt = blockIdx.x, h = blockIdx.y, z = blockIdx.z;
    const int t = threadIdx.x;
    const int qvh = z * 4 + h;
    const int kvh = (cross ? (z ^ 1) : z) * 4 + h;
    const int n0 = qt * 16;
    __shared__ float sq[16][64];
    __shared__ float sc[16][1032];   // pad 1032: qi-groups land 8 banks apart

    // stage Q tile: row = t>>4 matches qi ownership below (same wave)
    {
        int row = t >> 4, d0 = (t & 15) * 4;
        *(float4*)&sq[row][d0] =
            *(const float4*)(heads_q + (((size_t)qvh * 1024) + n0 + row) * 64 + d0);
    }
    const int qi = t >> 4, jl = t & 15;
    const float4* K4  = (const float4*)(heads_k + (size_t)kvh * 1024 * 64);
    const float4* sq4 = (const float4*)&sq[qi][0];

    // pass 1: scores (each thread owns j = jl + 16*jj)
    for (int jj = 0; jj < 64; ++jj) {
        int j = jj * 16 + jl;
        float a = 0.f;
        #pragma unroll
        for (int d4 = 0; d4 < 16; ++d4) {
            float4 qv = sq4[d4];
            float4 kv = K4[j * 16 + d4];
            a += qv.x * kv.x + qv.y * kv.y + qv.z * kv.z + qv.w * kv.w;
        }
        sc[qi][j] = a * scale;
    }
    // softmax per row across the 16 lanes of the row group
    float mx = -1e30f;
    for (int jj = 0; jj < 64; ++jj) mx = fmaxf(mx, sc[qi][jj * 16 + jl]);
    #pragma unroll
    for (int o = 1; o < 16; o <<= 1) mx = fmaxf(mx, __shfl_xor(mx, o, 16));
    float sm = 0.f;
    for (int jj = 0; jj < 64; ++jj) {
        int j = jj * 16 + jl;
        float e = expf(sc[qi][j] - mx);
        sc[qi][j] = e; sm += e;
    }
    #pragma unroll
    for (int o = 1; o < 16; o <<= 1) sm += __shfl_xor(sm, o, 16);
    float inv = 1.0f / sm;

    // pass 2: PV. thread -> (qi, d4); 4 output dims.
    const float4* V4 = (const float4*)(heads_v + (size_t)kvh * 1024 * 64);
    const int d4 = jl;
    float ax = 0.f, ay = 0.f, az = 0.f, aw = 0.f;
    for (int j0 = 0; j0 < 1024; j0 += 4) {
        float4 p4 = *(const float4*)&sc[qi][j0];
        float4 v0 = V4[(size_t)(j0 + 0) * 16 + d4];
        float4 v1 = V4[(size_t)(j0 + 1) * 16 + d4];
        float4 v2 = V4[(size_t)(j0 + 2) * 16 + d4];
        float4 v3 = V4[(size_t)(j0 + 3) * 16 + d4];
        ax = fmaf(p4.x, v0.x, ax); ay = fmaf(p4.x, v0.y, ay);
        az = fmaf(p4.x, v0.z, az); aw = fmaf(p4.x, v0.w, aw);
        ax = fmaf(p4.y, v1.x, ax); ay = fmaf(p4.y, v1.y, ay);
        az = fmaf(p4.y, v1.z, az); aw = fmaf(p4.y, v1.w, aw);
        ax = fmaf(p4.z, v2.x, ax); ay = fmaf(p4.z, v2.y, ay);
        az = fmaf(p4.z, v2.z, az); aw = fmaf(p4.z, v2.w, aw);
        ax = fmaf(p4.w, v3.x, ax); ay = fmaf(p4.w, v3.y, ay);
        az = fmaf(p4.w, v3.z, az); aw = fmaf(p4.w, v3.w, aw);
    }
    float4 o4; o4.x = ax * inv; o4.y = ay * inv; o4.z = az * inv; o4.w = aw * inv;
    int row = z * 1024 + n0 + qi;
    *(float4*)&out[(size_t)row * 256 + h * 64 + d4 * 4] = o4;
}

// ---------------------------------------------------------------------------
// In-place LayerNorm (512) + exact GELU. Block per row (2048 rows).
// ---------------------------------------------------------------------------
__global__ __launch_bounds__(256) void lngelu_k(
    float* __restrict__ x, const float* __restrict__ g,
    const float* __restrict__ beta)
{
    int row = blockIdx.x, t = threadIdx.x;
    __shared__ float red[256];
    float v0 = x[(size_t)row * 512 + t];
    float v1 = x[(size_t)row * 512 + t + 256];
    red[t] = v0 + v1; __syncthreads();
    for (int s = 128; s > 0; s >>= 1) {
        if (t < s) red[t] += red[t + s];
        __syncthreads();
    }
    float mu = red[0] * (1.0f / 512.0f); __syncthreads();
    float d0 = v0 - mu, d1 = v1 - mu;
    red[t] = d0 * d0 + d1 * d1; __syncthreads();
    for (int s = 128; s > 0; s >>= 1) {
        if (t < s) red[t] += red[t + s];
        __syncthreads();
    }
    float rstd = rsqrtf(red[0] * (1.0f / 512.0f) + 1e-5f);
    float y = d0 * rstd * g[t] + beta[t];
    x[(size_t)row * 512 + t] = 0.5f * y * (1.0f + erff(y * 0.70710678118654752f));
    y = d1 * rstd * g[t + 256] + beta[t + 256];
    x[(size_t)row * 512 + t + 256] = 0.5f * y * (1.0f + erff(y * 0.70710678118654752f));
}

// z[i] = dot(x[i], Wz) + bz[0]   (2048 rows)
__global__ __launch_bounds__(256) void z_k(
    const float* __restrict__ x, const float* __restrict__ Wz,
    const float* __restrict__ bz, float* __restrict__ z)
{
    int row = blockIdx.x, t = threadIdx.x;
    __shared__ float red[256];
    red[t] = x[(size_t)row * 256 + t] * Wz[t];
    __syncthreads();
    for (int s = 128; s > 0; s >>= 1) {
        if (t < s) red[t] += red[t + s];
        __syncthreads();
    }
    if (t == 0) z[row] = red[0] + bz[0];
}

__global__ __launch_bounds__(256) void rowlse_k(
    const float* __restrict__ sim, float* __restrict__ out)
{
    int row = blockIdx.x, t = threadIdx.x;
    __shared__ float red[256];
    float mx = -1e30f;
    for (int j = t; j < NTOK; j += 256) mx = fmaxf(mx, sim[(size_t)row * NTOK + j]);
    red[t] = mx; __syncthreads();
    for (int s = 128; s > 0; s >>= 1) {
        if (t < s) red[t] = fmaxf(red[t], red[t + s]);
        __syncthreads();
    }
    mx = red[0]; __syncthreads();
    float sum = 0.0f;
    for (int j = t; j < NTOK; j += 256) sum += expf(sim[(size_t)row * NTOK + j] - mx);
    red[t] = sum; __syncthreads();
    for (int s = 128; s > 0; s >>= 1) {
        if (t < s) red[t] += red[t + s];
        __syncthreads();
    }
    if (t == 0) out[row] = mx + logf(red[0]);
}

__global__ __launch_bounds__(256) void collse_k(
    const float* __restrict__ sim, float* __restrict__ out)
{
    int col = blockIdx.x, t = threadIdx.x;
    __shared__ float red[256];
    float mx = -1e30f;
    for (int i = t; i < NTOK; i += 256) mx = fmaxf(mx, sim[(size_t)i * NTOK + col]);
    red[t] = mx; __syncthreads();
    for (int s = 128; s > 0; s >>= 1) {
        if (t < s) red[t] = fmaxf(red[t], red[t + s]);
        __syncthreads();
    }
    mx = red[0]; __syncthreads();
    float sum = 0.0f;
    for (int i = t; i < NTOK; i += 256) sum += expf(sim[(size_t)i * NTOK + col] - mx);
    red[t] = sum; __syncthreads();
    for (int s = 128; s > 0; s >>= 1) {
        if (t < s) red[t] += red[t + s];
        __syncthreads();
    }
    if (t == 0) out[col] = mx + logf(red[0]);
}

// inner = 2*sim - rowlse[i] - collse[j] + logsig(z0[i]) + logsig(z1[j])
__global__ __launch_bounds__(256) void assemble_k(
    const float* __restrict__ sim, const float* __restrict__ rls,
    const float* __restrict__ cls, const float* __restrict__ z0,
    const float* __restrict__ z1, float* __restrict__ out)
{
    int idx = blockIdx.x * 256 + threadIdx.x;
    const int W = NTOK + 1;
    if (idx >= W * W) return;
    int i = idx / W, j = idx % W;
    float v;
    if (i < NTOK && j < NTOK) {
        v = 2.0f * sim[(size_t)i * NTOK + j] - rls[i] - cls[j] + logsigf(z0[i]) + logsigf(z1[j]);
    } else if (i < NTOK) {
        v = logsigf(-z0[i]);
    } else if (j < NTOK) {
        v = logsigf(-z1[j]);
    } else {
        v = 0.0f;
    }
    out[idx] = v;
}

// ---------------------------------------------------------------------------
extern "C" void kernel_launch(void* const* d_in, const int* in_sizes, int n_in,
                              void* d_out, int out_size, void* d_ws, size_t ws_size,
                              hipStream_t stream)
{
    const float* desc0 = (const float*)d_in[0];
    const float* desc1 = (const float*)d_in[1];
    const float* kpts0 = (const float*)d_in[2];
    const float* kpts1 = (const float*)d_in[3];
    const float* Wr    = (const float*)d_in[4];
    const float* sWqkv = (const float*)d_in[5];
    const float* sbqkv = (const float*)d_in[6];
    const float* sWo   = (const float*)d_in[7];
    const float* sbo   = (const float*)d_in[8];
    const float* sfW1  = (const float*)d_in[9];
    const float* sfb1  = (const float*)d_in[10];
    const float* sfg   = (const float*)d_in[11];
    const float* sfbt  = (const float*)d_in[12];
    const float* sfW2  = (const float*)d_in[13];
    const float* sfb2  = (const float*)d_in[14];
    const float* cWqk  = (const float*)d_in[15];
    const float* cbqk  = (const float*)d_in[16];
    const float* cWv   = (const float*)d_in[17];
    const float* cbv   = (const float*)d_in[18];
    const float* cWo   = (const float*)d_in[19];
    const float* cbo   = (const float*)d_in[20];
    const float* cfW1  = (const float*)d_in[21];
    const float* cfb1  = (const float*)d_in[22];
    const float* cfg   = (const float*)d_in[23];
    const float* cfbt  = (const float*)d_in[24];
    const float* cfW2  = (const float*)d_in[25];
    const float* cfb2  = (const float*)d_in[26];
    const float* mWp   = (const float*)d_in[27];
    const float* mbp   = (const float*)d_in[28];
    const float* mWz   = (const float*)d_in[29];
    const float* mbz   = (const float*)d_in[30];

    float* ws = (float*)d_ws;
    // Layout (floats), total 4,460,544 fl = 17.8 MB:
    float* x    = ws;                  // 524288  [2048][256]
    float* encc = ws + 524288;         // 131072  [2048][64]
    float* encs = ws + 655360;         // 131072
    float* qkv  = ws + 786432;         // 1572864 [2048][768] (self only)
    float* mo   = qkv;                 // 524288  (FFN phase; qkv dead)
    float* pre  = qkv + 524288;        // 1048576 [2048][512]
    float* qh   = ws + 2359296;        // 524288  [8][1024][64]
    float* kh   = ws + 2883584;        // 524288
    float* vh   = ws + 3407872;        // 524288
    float* msg  = ws + 3932160;        // 524288  [2048][256]
    float* zb   = ws + 4456448;        // 2048
    float* rlsb = ws + 4458496;        // 1024
    float* clsb = ws + 4459520;        // 1024
    float* sim  = qh;                  // 1048576 (layers done; spans qh+kh)
    float* md   = msg;                 // [2048][256]

    // TM=64 for wide GEMMs, TM=32 for Nn=256 GEMMs (keeps >=256 blocks).
    auto gemm64 = [&](const float* A0, const float* A1, const float* B,
                      const float* bias, const float* R, float* C,
                      int M, int K, int Nn, int ldc, float scale, int tB, int hm) {
        gemm_k<64><<<dim3(Nn / 64, M / 64), 256, 0, stream>>>(A0, A1, B, bias, R, C, M, K, Nn, ldc, scale, tB, hm);
    };
    auto gemm32 = [&](const float* A0, const float* A1, const float* B,
                      const float* bias, const float* R, float* C,
                      int M, int K, int Nn, int ldc, float scale, int tB, int hm) {
        gemm_k<32><<<dim3(Nn / 64, M / 32), 256, 0, stream>>>(A0, A1, B, bias, R, C, M, K, Nn, ldc, scale, tB, hm);
    };

    const float SELF_SCALE  = 0.125f;               // DH^-0.5
    const float CROSS_SCALE = 0.35355339059327373f; // DH^-0.25

    copyvec_k<<<(NTOK * DM + 255) / 256, 256, 0, stream>>>(x, desc0, NTOK * DM);
    copyvec_k<<<(NTOK * DM + 255) / 256, 256, 0, stream>>>(x + NTOK * DM, desc1, NTOK * DM);
    posenc_k<<<(NTOK * 32 + 255) / 256, 256, 0, stream>>>(kpts0, Wr, encc, encs);
    posenc_k<<<(NTOK * 32 + 255) / 256, 256, 0, stream>>>(kpts1, Wr, encc + 65536, encs + 65536);

    for (int l = 0; l < NL; ++l) {
        // ---- self block (both images batched) ----
        gemm64(x, nullptr, sWqkv + (size_t)l * 256 * 768, sbqkv + (size_t)l * 768,
               nullptr, qkv, 2048, 256, 768, 768, 1.0f, 0, 0);
        splitrope_k<<<2048, 256, 0, stream>>>(qkv, encc, encs, qh, kh, vh);
        attn_k<<<dim3(64, NH, 2), 256, 0, stream>>>(qh, kh, vh, msg, SELF_SCALE, 0);
        gemm32(msg, nullptr, sWo + (size_t)l * 256 * 256, sbo + (size_t)l * 256,
               nullptr, mo, 2048, 256, 256, 256, 1.0f, 0, 0);
        gemm64(x, mo, sfW1 + (size_t)l * 512 * 512, sfb1 + (size_t)l * 512,
               nullptr, pre, 2048, 512, 512, 512, 1.0f, 0, 0);
        lngelu_k<<<2048, 256, 0, stream>>>(pre, sfg + (size_t)l * 512, sfbt + (size_t)l * 512);
        gemm32(pre, nullptr, sfW2 + (size_t)l * 512 * 256, sfb2 + (size_t)l * 256,
               x, x, 2048, 512, 256, 256, 1.0f, 0, 0);

        // ---- cross block ----
        gemm32(x, nullptr, cWqk + (size_t)l * 256 * 256, cbqk + (size_t)l * 256,
               nullptr, qh, 2048, 256, 256, 256, CROSS_SCALE, 0, 1);  // headmajor qk
        gemm32(x, nullptr, cWv + (size_t)l * 256 * 256, cbv + (size_t)l * 256,
               nullptr, vh, 2048, 256, 256, 256, 1.0f, 0, 1);         // headmajor v
        attn_k<<<dim3(64, NH, 2), 256, 0, stream>>>(qh, qh, vh, msg, 1.0f, 1);
        gemm32(msg, nullptr, cWo + (size_t)l * 256 * 256, cbo + (size_t)l * 256,
               nullptr, mo, 2048, 256, 256, 256, 1.0f, 0, 0);
        gemm64(x, mo, cfW1 + (size_t)l * 512 * 512, cfb1 + (size_t)l * 512,
               nullptr, pre, 2048, 512, 512, 512, 1.0f, 0, 0);
        lngelu_k<<<2048, 256, 0, stream>>>(pre, cfg + (size_t)l * 512, cfbt + (size_t)l * 512);
        gemm32(pre, nullptr, cfW2 + (size_t)l * 512 * 256, cfb2 + (size_t)l * 256,
               x, x, 2048, 512, 256, 256, 1.0f, 0, 0);
    }

    // ---- assignment head ----
    const float MD_SCALE = 0.25f; // D^-0.25
    gemm32(x, nullptr, mWp, mbp, nullptr, md, 2048, 256, 256, 256, MD_SCALE, 0, 0);
    z_k<<<2048, 256, 0, stream>>>(x, mWz, mbz, zb);
    gemm64(md, nullptr, md + 1024 * 256, nullptr, nullptr, sim,
           1024, 256, 1024, 1024, 1.0f, 1, 0);   // sim = md0 @ md1^T
    rowlse_k<<<NTOK, 256, 0, stream>>>(sim, rlsb);
    collse_k<<<NTOK, 256, 0, stream>>>(sim, clsb);
    const int W = NTOK + 1;
    assemble_k<<<(W * W + 255) / 256, 256, 0, stream>>>(sim, rlsb, clsb, zb, zb + 1024, (float*)d_out);
}

// Round 4
// 5009.886 us; speedup vs baseline: 3.8313x; 1.7171x over previous
//
#include <hip/hip_runtime.h>
#include <cmath>

// LightGlue forward, fp32, image-batched (M=2048). N=1024, D=256, H=4, DH=64, L=9.
#define NTOK 1024
#define DM   256
#define NH   4
#define DH   64
#define NL   9

__device__ __forceinline__ float logsigf(float x) {
    return fminf(x, 0.0f) - log1pf(expf(-fabsf(x)));
}

// ---------------------------------------------------------------------------
// GEMM v2: C[M x Nn] = (A @ B + bias) * scale + R
// A: dual-source concat (A1 != null -> cols 0-255 from A0 ld 256, cols 256+ from
//    A1 ld 256), else A0 with lda = K.
// B: [K x Nn] or (transB) [Nn x K].
// Store: plain row-major ldc, or headmajor (out[((im*4+h)*1024+n)*64+d], Nn=256).
// Tile TM x 64, BK=16, 256 threads, micro (TM/16) x 4 per thread.
// ---------------------------------------------------------------------------
template<int TM>
__global__ __launch_bounds__(256) void gemm_k(
    const float* __restrict__ A0, const float* __restrict__ A1,
    const float* __restrict__ B, const float* __restrict__ bias,
    const float* __restrict__ R, float* __restrict__ C,
    int M, int K, int Nn, int ldc, float scale, int transB, int headmajor)
{
    constexpr int RPT = TM / 16;              // rows per thread
    __shared__ float As[16][TM + 4];          // [k][row]
    __shared__ float Bs[16][68];              // [k][col]
    const int tid = threadIdx.x;
    const int tx = tid & 15, ty = tid >> 4;
    const int row0 = blockIdx.y * TM, col0 = blockIdx.x * 64;
    float acc[RPT][4] = {};

    for (int k0 = 0; k0 < K; k0 += 16) {
        #pragma unroll
        for (int i = 0; i < TM * 16 / 256; ++i) {
            int idx = tid + i * 256;
            int r = idx >> 4, c = idx & 15;
            float v;
            if (A1) {
                int kk = k0 + c;
                v = (kk < 256) ? A0[(size_t)(row0 + r) * 256 + kk]
                               : A1[(size_t)(row0 + r) * 256 + (kk - 256)];
            } else {
                v = A0[(size_t)(row0 + r) * K + k0 + c];
            }
            As[c][r] = v;
        }
        if (!transB) {
            #pragma unroll
            for (int i = 0; i < 4; ++i) {
                int idx = tid + i * 256;
                int r = idx >> 6, c = idx & 63;
                Bs[r][c] = B[(size_t)(k0 + r) * Nn + col0 + c];
            }
        } else {
            #pragma unroll
            for (int i = 0; i < 4; ++i) {
                int idx = tid + i * 256;
                int r = idx & 15, c = idx >> 4;   // consecutive tid -> consecutive k
                Bs[r][c] = B[(size_t)(col0 + c) * K + k0 + r];
            }
        }
        __syncthreads();
        #pragma unroll
        for (int kk = 0; kk < 16; ++kk) {
            float w[4];
            *(float4*)w = *(const float4*)&Bs[kk][tx * 4];
            float a[RPT];
            #pragma unroll
            for (int i = 0; i < RPT; ++i) a[i] = As[kk][ty * RPT + i];
            #pragma unroll
            for (int i = 0; i < RPT; ++i)
                #pragma unroll
                for (int j = 0; j < 4; ++j)
                    acc[i][j] = fmaf(a[i], w[j], acc[i][j]);
        }
        __syncthreads();
    }

    float bv[4] = {0, 0, 0, 0};
    if (bias) *(float4*)bv = *(const float4*)&bias[col0 + tx * 4];
    #pragma unroll
    for (int i = 0; i < RPT; ++i) {
        int r = row0 + ty * RPT + i;
        int c0 = col0 + tx * 4;
        float4 v;
        v.x = (acc[i][0] + bv[0]) * scale;
        v.y = (acc[i][1] + bv[1]) * scale;
        v.z = (acc[i][2] + bv[2]) * scale;
        v.w = (acc[i][3] + bv[3]) * scale;
        if (R) {
            float4 rv = *(const float4*)&R[(size_t)r * Nn + c0];
            v.x += rv.x; v.y += rv.y; v.z += rv.z; v.w += rv.w;
        }
        if (headmajor) {
            int h = c0 >> 6, d = c0 & 63, im = r >> 10, n = r & 1023;
            *(float4*)&C[(((size_t)(im * 4 + h)) * 1024 + n) * 64 + d] = v;
        } else {
            *(float4*)&C[(size_t)r * ldc + c0] = v;
        }
    }
}

// ---------------------------------------------------------------------------
__global__ __launch_bounds__(256) void posenc_k(
    const float* __restrict__ kpts, const float* __restrict__ Wr,
    float* __restrict__ encc, float* __restrict__ encs)
{
    int idx = blockIdx.x * 256 + threadIdx.x;          // N*32
    if (idx >= NTOK * 32) return;
    int i = idx >> 5, f = idx & 31;
    float p = kpts[i * 2 + 0] * Wr[f] + kpts[i * 2 + 1] * Wr[32 + f];
    float c = cosf(p), s = sinf(p);
    encc[i * 64 + 2 * f]     = c;  encc[i * 64 + 2 * f + 1] = c;
    encs[i * 64 + 2 * f]     = s;  encs[i * 64 + 2 * f + 1] = s;
}

// ---------------------------------------------------------------------------
// Split qkv [2048 x 768] (col = h*192 + d*3 + {q,k,v}) into vhead-major
// [8][1024][64] (vhead = im*4+h), applying RoPE to q and k.
// ---------------------------------------------------------------------------
__global__ __launch_bounds__(256) void splitrope_k(
    const float* __restrict__ qkv, const float* __restrict__ encc,
    const float* __restrict__ encs, float* __restrict__ qh,
    float* __restrict__ kh, float* __restrict__ vh)
{
    int n = blockIdx.x, t = threadIdx.x;  // n: 0..2047, t = h*64 + d
    int h = t >> 6, d = t & 63;
    int im = n >> 10, nl = n & 1023;
    const float* base  = qkv + (size_t)n * 768 + h * 192 + d * 3;
    const float* pbase = qkv + (size_t)n * 768 + h * 192 + (d ^ 1) * 3;
    float c = encc[n * 64 + d], s = encs[n * 64 + d];
    float q = base[0], k = base[1], v = base[2];
    float qp = pbase[0], kp = pbase[1];
    float sgn = (d & 1) ? 1.0f : -1.0f;
    size_t o = (((size_t)(im * 4 + h)) * 1024 + nl) * 64 + d;
    qh[o] = q * c + sgn * qp * s;
    kh[o] = k * c + sgn * kp * s;
    vh[o] = v;
}

__global__ __launch_bounds__(256) void copyvec_k(
    float* __restrict__ dst, const float* __restrict__ src, int n)
{
    int i = blockIdx.x * 256 + threadIdx.x;
    if (i < n) dst[i] = src[i];
}

// ---------------------------------------------------------------------------
// Attention v3: flash-style online softmax, fp32.
// Block = (16-query tile, vhead). Grid (64, 8). 256 threads.
// Thread (tq = t>>4, tl = t&15): q row n0+tq held in registers (full 64 dims);
// K/V staged in LDS in 32-key tiles; scores tile in LDS; online m/l rescale;
// PV accumulated in registers (4 dims per thread).
// cross: kv head = vh ^ 4 (flips image; covers both directions since z spans both).
// out: [2048][256], row = im*1024 + n, col = h*64 + d.
// ---------------------------------------------------------------------------
__global__ __launch_bounds__(256) void attn_k(
    const float* __restrict__ heads_q, const float* __restrict__ heads_k,
    const float* __restrict__ heads_v, float* __restrict__ out,
    float scale, int cross)
{
    const int qt = blockIdx.x, vh = blockIdx.y;
    const int kvh = cross ? (vh ^ 4) : vh;
    const int t = threadIdx.x;
    const int tq = t >> 4, tl = t & 15;
    const int n0 = qt * 16;

    __shared__ float kt[32][68];
    __shared__ float vt[32][68];
    __shared__ float st[16][36];

    // Q row -> registers (16 lanes per row read the same row; once per kernel)
    float4 qreg[16];
    {
        const float4* Qp = (const float4*)(heads_q + (((size_t)vh * 1024) + n0 + tq) * 64);
        #pragma unroll
        for (int d = 0; d < 16; ++d) qreg[d] = Qp[d];
    }

    const float* Kbase = heads_k + (size_t)kvh * 1024 * 64;
    const float* Vbase = heads_v + (size_t)kvh * 1024 * 64;

    float m = -1e30f, l = 0.0f;
    float4 o = {0.f, 0.f, 0.f, 0.f};   // dims tl*4 .. tl*4+3
    const int sr = t >> 3, scol = (t & 7) * 8;   // staging map: 8 floats/thread

    for (int j0 = 0; j0 < 1024; j0 += 32) {
        // stage K,V tile: global -> regs -> (sync) -> LDS -> (sync)
        const float4* kp = (const float4*)(Kbase + (size_t)(j0 + sr) * 64 + scol);
        const float4* vp = (const float4*)(Vbase + (size_t)(j0 + sr) * 64 + scol);
        float4 ka = kp[0], kb = kp[1];
        float4 va = vp[0], vb = vp[1];
        __syncthreads();                       // prior tile fully consumed
        *(float4*)&kt[sr][scol]     = ka;
        *(float4*)&kt[sr][scol + 4] = kb;
        *(float4*)&vt[sr][scol]     = va;
        *(float4*)&vt[sr][scol + 4] = vb;
        __syncthreads();

        // phase A: scores, 2 keys per thread
        #pragma unroll
        for (int u = 0; u < 2; ++u) {
            int j = tl + u * 16;
            const float4* kr = (const float4*)&kt[j][0];
            float a = 0.f;
            #pragma unroll
            for (int d = 0; d < 16; ++d) {
                float4 qv = qreg[d], kv = kr[d];
                a += qv.x * kv.x + qv.y * kv.y + qv.z * kv.z + qv.w * kv.w;
            }
            st[tq][j] = a * scale;
        }
        __syncthreads();

        // phase B: online softmax + PV (4 dims per thread)
        float tm = m;
        #pragma unroll
        for (int j = 0; j < 32; ++j) tm = fmaxf(tm, st[tq][j]);
        float alpha = __expf(m - tm);
        float lsum = 0.f;
        float4 oa = {0.f, 0.f, 0.f, 0.f};
        const int c = tl * 4;
        #pragma unroll 4
        for (int j = 0; j < 32; ++j) {
            float p = __expf(st[tq][j] - tm);
            lsum += p;
            float4 v = *(const float4*)&vt[j][c];
            oa.x = fmaf(p, v.x, oa.x);
            oa.y = fmaf(p, v.y, oa.y);
            oa.z = fmaf(p, v.z, oa.z);
            oa.w = fmaf(p, v.w, oa.w);
        }
        l = l * alpha + lsum;
        o.x = o.x * alpha + oa.x;
        o.y = o.y * alpha + oa.y;
        o.z = o.z * alpha + oa.z;
        o.w = o.w * alpha + oa.w;
        m = tm;
    }

    float inv = 1.0f / l;
    float4 r;
    r.x = o.x * inv; r.y = o.y * inv; r.z = o.z * inv; r.w = o.w * inv;
    int row = (vh >> 2) * 1024 + n0 + tq;
    *(float4*)&out[(size_t)row * 256 + (vh & 3) * 64 + tl * 4] = r;
}

// ---------------------------------------------------------------------------
// In-place LayerNorm (512) + exact GELU. Block per row (2048 rows).
// ---------------------------------------------------------------------------
__global__ __launch_bounds__(256) void lngelu_k(
    float* __restrict__ x, const float* __restrict__ g,
    const float* __restrict__ beta)
{
    int row = blockIdx.x, t = threadIdx.x;
    __shared__ float red[256];
    float v0 = x[(size_t)row * 512 + t];
    float v1 = x[(size_t)row * 512 + t + 256];
    red[t] = v0 + v1; __syncthreads();
    for (int s = 128; s > 0; s >>= 1) {
        if (t < s) red[t] += red[t + s];
        __syncthreads();
    }
    float mu = red[0] * (1.0f / 512.0f); __syncthreads();
    float d0 = v0 - mu, d1 = v1 - mu;
    red[t] = d0 * d0 + d1 * d1; __syncthreads();
    for (int s = 128; s > 0; s >>= 1) {
        if (t < s) red[t] += red[t + s];
        __syncthreads();
    }
    float rstd = rsqrtf(red[0] * (1.0f / 512.0f) + 1e-5f);
    float y = d0 * rstd * g[t] + beta[t];
    x[(size_t)row * 512 + t] = 0.5f * y * (1.0f + erff(y * 0.70710678118654752f));
    y = d1 * rstd * g[t + 256] + beta[t + 256];
    x[(size_t)row * 512 + t + 256] = 0.5f * y * (1.0f + erff(y * 0.70710678118654752f));
}

// z[i] = dot(x[i], Wz) + bz[0]   (2048 rows)
__global__ __launch_bounds__(256) void z_k(
    const float* __restrict__ x, const float* __restrict__ Wz,
    const float* __restrict__ bz, float* __restrict__ z)
{
    int row = blockIdx.x, t = threadIdx.x;
    __shared__ float red[256];
    red[t] = x[(size_t)row * 256 + t] * Wz[t];
    __syncthreads();
    for (int s = 128; s > 0; s >>= 1) {
        if (t < s) red[t] += red[t + s];
        __syncthreads();
    }
    if (t == 0) z[row] = red[0] + bz[0];
}

__global__ __launch_bounds__(256) void rowlse_k(
    const float* __restrict__ sim, float* __restrict__ out)
{
    int row = blockIdx.x, t = threadIdx.x;
    __shared__ float red[256];
    float mx = -1e30f;
    for (int j = t; j < NTOK; j += 256) mx = fmaxf(mx, sim[(size_t)row * NTOK + j]);
    red[t] = mx; __syncthreads();
    for (int s = 128; s > 0; s >>= 1) {
        if (t < s) red[t] = fmaxf(red[t], red[t + s]);
        __syncthreads();
    }
    mx = red[0]; __syncthreads();
    float sum = 0.0f;
    for (int j = t; j < NTOK; j += 256) sum += expf(sim[(size_t)row * NTOK + j] - mx);
    red[t] = sum; __syncthreads();
    for (int s = 128; s > 0; s >>= 1) {
        if (t < s) red[t] += red[t + s];
        __syncthreads();
    }
    if (t == 0) out[row] = mx + logf(red[0]);
}

__global__ __launch_bounds__(256) void collse_k(
    const float* __restrict__ sim, float* __restrict__ out)
{
    int col = blockIdx.x, t = threadIdx.x;
    __shared__ float red[256];
    float mx = -1e30f;
    for (int i = t; i < NTOK; i += 256) mx = fmaxf(mx, sim[(size_t)i * NTOK + col]);
    red[t] = mx; __syncthreads();
    for (int s = 128; s > 0; s >>= 1) {
        if (t < s) red[t] = fmaxf(red[t], red[t + s]);
        __syncthreads();
    }
    mx = red[0]; __syncthreads();
    float sum = 0.0f;
    for (int i = t; i < NTOK; i += 256) sum += expf(sim[(size_t)i * NTOK + col] - mx);
    red[t] = sum; __syncthreads();
    for (int s = 128; s > 0; s >>= 1) {
        if (t < s) red[t] += red[t + s];
        __syncthreads();
    }
    if (t == 0) out[col] = mx + logf(red[0]);
}

// inner = 2*sim - rowlse[i] - collse[j] + logsig(z0[i]) + logsig(z1[j])
__global__ __launch_bounds__(256) void assemble_k(
    const float* __restrict__ sim, const float* __restrict__ rls,
    const float* __restrict__ cls, const float* __restrict__ z0,
    const float* __restrict__ z1, float* __restrict__ out)
{
    int idx = blockIdx.x * 256 + threadIdx.x;
    const int W = NTOK + 1;
    if (idx >= W * W) return;
    int i = idx / W, j = idx % W;
    float v;
    if (i < NTOK && j < NTOK) {
        v = 2.0f * sim[(size_t)i * NTOK + j] - rls[i] - cls[j] + logsigf(z0[i]) + logsigf(z1[j]);
    } else if (i < NTOK) {
        v = logsigf(-z0[i]);
    } else if (j < NTOK) {
        v = logsigf(-z1[j]);
    } else {
        v = 0.0f;
    }
    out[idx] = v;
}

// ---------------------------------------------------------------------------
extern "C" void kernel_launch(void* const* d_in, const int* in_sizes, int n_in,
                              void* d_out, int out_size, void* d_ws, size_t ws_size,
                              hipStream_t stream)
{
    const float* desc0 = (const float*)d_in[0];
    const float* desc1 = (const float*)d_in[1];
    const float* kpts0 = (const float*)d_in[2];
    const float* kpts1 = (const float*)d_in[3];
    const float* Wr    = (const float*)d_in[4];
    const float* sWqkv = (const float*)d_in[5];
    const float* sbqkv = (const float*)d_in[6];
    const float* sWo   = (const float*)d_in[7];
    const float* sbo   = (const float*)d_in[8];
    const float* sfW1  = (const float*)d_in[9];
    const float* sfb1  = (const float*)d_in[10];
    const float* sfg   = (const float*)d_in[11];
    const float* sfbt  = (const float*)d_in[12];
    const float* sfW2  = (const float*)d_in[13];
    const float* sfb2  = (const float*)d_in[14];
    const float* cWqk  = (const float*)d_in[15];
    const float* cbqk  = (const float*)d_in[16];
    const float* cWv   = (const float*)d_in[17];
    const float* cbv   = (const float*)d_in[18];
    const float* cWo   = (const float*)d_in[19];
    const float* cbo   = (const float*)d_in[20];
    const float* cfW1  = (const float*)d_in[21];
    const float* cfb1  = (const float*)d_in[22];
    const float* cfg   = (const float*)d_in[23];
    const float* cfbt  = (const float*)d_in[24];
    const float* cfW2  = (const float*)d_in[25];
    const float* cfb2  = (const float*)d_in[26];
    const float* mWp   = (const float*)d_in[27];
    const float* mbp   = (const float*)d_in[28];
    const float* mWz   = (const float*)d_in[29];
    const float* mbz   = (const float*)d_in[30];

    float* ws = (float*)d_ws;
    // Layout (floats), total 4,460,544 fl = 17.8 MB:
    float* x    = ws;                  // 524288  [2048][256]
    float* encc = ws + 524288;         // 131072  [2048][64]
    float* encs = ws + 655360;         // 131072
    float* qkv  = ws + 786432;         // 1572864 [2048][768] (self only)
    float* mo   = qkv;                 // 524288  (FFN phase; qkv dead)
    float* pre  = qkv + 524288;        // 1048576 [2048][512]
    float* qh   = ws + 2359296;        // 524288  [8][1024][64]
    float* kh   = ws + 2883584;        // 524288
    float* vh   = ws + 3407872;        // 524288
    float* msg  = ws + 3932160;        // 524288  [2048][256]
    float* zb   = ws + 4456448;        // 2048
    float* rlsb = ws + 4458496;        // 1024
    float* clsb = ws + 4459520;        // 1024
    float* sim  = qh;                  // 1048576 (layers done; spans qh+kh)
    float* md   = msg;                 // [2048][256]

    auto gemm64 = [&](const float* A0, const float* A1, const float* B,
                      const float* bias, const float* R, float* C,
                      int M, int K, int Nn, int ldc, float scale, int tB, int hm) {
        gemm_k<64><<<dim3(Nn / 64, M / 64), 256, 0, stream>>>(A0, A1, B, bias, R, C, M, K, Nn, ldc, scale, tB, hm);
    };
    auto gemm32 = [&](const float* A0, const float* A1, const float* B,
                      const float* bias, const float* R, float* C,
                      int M, int K, int Nn, int ldc, float scale, int tB, int hm) {
        gemm_k<32><<<dim3(Nn / 64, M / 32), 256, 0, stream>>>(A0, A1, B, bias, R, C, M, K, Nn, ldc, scale, tB, hm);
    };

    const float SELF_SCALE  = 0.125f;               // DH^-0.5
    const float CROSS_SCALE = 0.35355339059327373f; // DH^-0.25

    copyvec_k<<<(NTOK * DM + 255) / 256, 256, 0, stream>>>(x, desc0, NTOK * DM);
    copyvec_k<<<(NTOK * DM + 255) / 256, 256, 0, stream>>>(x + NTOK * DM, desc1, NTOK * DM);
    posenc_k<<<(NTOK * 32 + 255) / 256, 256, 0, stream>>>(kpts0, Wr, encc, encs);
    posenc_k<<<(NTOK * 32 + 255) / 256, 256, 0, stream>>>(kpts1, Wr, encc + 65536, encs + 65536);

    for (int l = 0; l < NL; ++l) {
        // ---- self block (both images batched) ----
        gemm64(x, nullptr, sWqkv + (size_t)l * 256 * 768, sbqkv + (size_t)l * 768,
               nullptr, qkv, 2048, 256, 768, 768, 1.0f, 0, 0);
        splitrope_k<<<2048, 256, 0, stream>>>(qkv, encc, encs, qh, kh, vh);
        attn_k<<<dim3(64, 8), 256, 0, stream>>>(qh, kh, vh, msg, SELF_SCALE, 0);
        gemm32(msg, nullptr, sWo + (size_t)l * 256 * 256, sbo + (size_t)l * 256,
               nullptr, mo, 2048, 256, 256, 256, 1.0f, 0, 0);
        gemm64(x, mo, sfW1 + (size_t)l * 512 * 512, sfb1 + (size_t)l * 512,
               nullptr, pre, 2048, 512, 512, 512, 1.0f, 0, 0);
        lngelu_k<<<2048, 256, 0, stream>>>(pre, sfg + (size_t)l * 512, sfbt + (size_t)l * 512);
        gemm32(pre, nullptr, sfW2 + (size_t)l * 512 * 256, sfb2 + (size_t)l * 256,
               x, x, 2048, 512, 256, 256, 1.0f, 0, 0);

        // ---- cross block ----
        gemm32(x, nullptr, cWqk + (size_t)l * 256 * 256, cbqk + (size_t)l * 256,
               nullptr, qh, 2048, 256, 256, 256, CROSS_SCALE, 0, 1);  // headmajor qk
        gemm32(x, nullptr, cWv + (size_t)l * 256 * 256, cbv + (size_t)l * 256,
               nullptr, vh, 2048, 256, 256, 256, 1.0f, 0, 1);         // headmajor v
        attn_k<<<dim3(64, 8), 256, 0, stream>>>(qh, qh, vh, msg, 1.0f, 1);
        gemm32(msg, nullptr, cWo + (size_t)l * 256 * 256, cbo + (size_t)l * 256,
               nullptr, mo, 2048, 256, 256, 256, 1.0f, 0, 0);
        gemm64(x, mo, cfW1 + (size_t)l * 512 * 512, cfb1 + (size_t)l * 512,
               nullptr, pre, 2048, 512, 512, 512, 1.0f, 0, 0);
        lngelu_k<<<2048, 256, 0, stream>>>(pre, cfg + (size_t)l * 512, cfbt + (size_t)l * 512);
        gemm32(pre, nullptr, cfW2 + (size_t)l * 512 * 256, cfb2 + (size_t)l * 256,
               x, x, 2048, 512, 256, 256, 1.0f, 0, 0);
    }

    // ---- assignment head ----
    const float MD_SCALE = 0.25f; // D^-0.25
    gemm32(x, nullptr, mWp, mbp, nullptr, md, 2048, 256, 256, 256, MD_SCALE, 0, 0);
    z_k<<<2048, 256, 0, stream>>>(x, mWz, mbz, zb);
    gemm64(md, nullptr, md + 1024 * 256, nullptr, nullptr, sim,
           1024, 256, 1024, 1024, 1.0f, 1, 0);   // sim = md0 @ md1^T
    rowlse_k<<<NTOK, 256, 0, stream>>>(sim, rlsb);
    collse_k<<<NTOK, 256, 0, stream>>>(sim, clsb);
    const int W = NTOK + 1;
    assemble_k<<<(W * W + 255) / 256, 256, 0, stream>>>(sim, rlsb, clsb, zb, zb + 1024, (float*)d_out);
}

// Round 5
// 2970.965 us; speedup vs baseline: 6.4607x; 1.6863x over previous
//
#include <hip/hip_runtime.h>
#include <cmath>

// LightGlue forward. GEMMs in bf16 MFMA (fp32 staging-convert), rest fp32.
// N=1024 tokens, D=256, H=4, DH=64, L=9. Batched over both images (M=2048).
#define NTOK 1024
#define DM   256
#define NH   4
#define DH   64
#define NL   9

typedef __attribute__((ext_vector_type(8))) __bf16 bf16x8;
typedef __attribute__((ext_vector_type(4))) float  f32x4;

__device__ __forceinline__ float logsigf(float x) {
    return fminf(x, 0.0f) - log1pf(expf(-fabsf(x)));
}

__device__ __forceinline__ __bf16 f2bf(float f) {
    unsigned u = __float_as_uint(f);
    u = (u + 0x7FFFu + ((u >> 16) & 1u)) >> 16;          // round-nearest-even
    unsigned short s = (unsigned short)u;
    return __builtin_bit_cast(__bf16, s);
}

// ---------------------------------------------------------------------------
// bf16-MFMA GEMM: C[M x Nn] = (A @ B + bias) * scale + R   (fp32 in/out)
// A: dual-source concat (A1 != null -> cols 0-255 from A0, 256+ from A1, ld 256)
//    else A0 with lda=K. B: [K x Nn] or (transB) [Nn x K].
// Store row-major ldc, or headmajor (out[((im*4+h)*1024+n)*64+d], Nn=256).
// Tile 32(M) x 64(N), BK=32. 256 threads = 4 waves, 2x2 wave grid:
//   wave w: rows (w>>1)*16..+16, cols (w&1)*32..+32  -> 2 MFMAs per k-step.
// LDS: As[m][k] 32x40, Bs[n][k] 64x40 (k-contiguous for b128 frag reads;
// pad 40 shorts keeps b128 conflicts at 2-way = free).
// C/D mapping (HW-verified): col = lane&15, row = (lane>>4)*4 + reg.
// ---------------------------------------------------------------------------
__global__ __launch_bounds__(256) void gemm_bf_k(
    const float* __restrict__ A0, const float* __restrict__ A1,
    const float* __restrict__ B, const float* __restrict__ bias,
    const float* __restrict__ R, float* __restrict__ C,
    int M, int K, int Nn, int ldc, float scale, int transB, int headmajor)
{
    __shared__ __bf16 As[32][40];
    __shared__ __bf16 Bs[64][40];
    const int tid = threadIdx.x;
    const int w = tid >> 6, l = tid & 63;
    const int row0 = blockIdx.y * 32, col0 = blockIdx.x * 64;
    const int wr = (w >> 1) * 16;       // wave row offset in tile
    const int wc = (w & 1) * 32;        // wave col offset in tile
    f32x4 acc0 = {0.f, 0.f, 0.f, 0.f};
    f32x4 acc1 = {0.f, 0.f, 0.f, 0.f};

    const int ar = tid >> 3, ac = (tid & 7) * 4;        // A staging map
    const int bkr = tid >> 4, bnc = (tid & 15) * 4;     // B staging (transB=0)
    const int tnr = tid >> 2, tkc = (tid & 3) * 8;      // B staging (transB=1)

    for (int k0 = 0; k0 < K; k0 += 32) {
        // ---- stage A (32 x 32) ----
        {
            float4 v;
            if (A1) {
                int kk = k0 + ac;      // float4 never straddles the 256 seam
                const float* src = (kk < 256)
                    ? &A0[(size_t)(row0 + ar) * 256 + kk]
                    : &A1[(size_t)(row0 + ar) * 256 + (kk - 256)];
                v = *(const float4*)src;
            } else {
                v = *(const float4*)&A0[(size_t)(row0 + ar) * K + k0 + ac];
            }
            __bf16* d = &As[ar][ac];
            d[0] = f2bf(v.x); d[1] = f2bf(v.y); d[2] = f2bf(v.z); d[3] = f2bf(v.w);
        }
        // ---- stage B (32k x 64n) -> Bs[n][k] ----
        if (!transB) {
            #pragma unroll
            for (int h = 0; h < 2; ++h) {
                int kr = bkr + h * 16;
                float4 v = *(const float4*)&B[(size_t)(k0 + kr) * Nn + col0 + bnc];
                Bs[bnc + 0][kr] = f2bf(v.x);
                Bs[bnc + 1][kr] = f2bf(v.y);
                Bs[bnc + 2][kr] = f2bf(v.z);
                Bs[bnc + 3][kr] = f2bf(v.w);
            }
        } else {
            float4 a = *(const float4*)&B[(size_t)(col0 + tnr) * K + k0 + tkc];
            float4 b = *(const float4*)&B[(size_t)(col0 + tnr) * K + k0 + tkc + 4];
            __bf16* d = &Bs[tnr][tkc];
            d[0] = f2bf(a.x); d[1] = f2bf(a.y); d[2] = f2bf(a.z); d[3] = f2bf(a.w);
            d[4] = f2bf(b.x); d[5] = f2bf(b.y); d[6] = f2bf(b.z); d[7] = f2bf(b.w);
        }
        __syncthreads();
        // ---- compute: 2 MFMAs per wave ----
        bf16x8 af  = *(const bf16x8*)&As[wr + (l & 15)][(l >> 4) * 8];
        bf16x8 bf0 = *(const bf16x8*)&Bs[wc + (l & 15)][(l >> 4) * 8];
        bf16x8 bf1 = *(const bf16x8*)&Bs[wc + 16 + (l & 15)][(l >> 4) * 8];
        acc0 = __builtin_amdgcn_mfma_f32_16x16x32_bf16(af, bf0, acc0, 0, 0, 0);
        acc1 = __builtin_amdgcn_mfma_f32_16x16x32_bf16(af, bf1, acc1, 0, 0, 0);
        __syncthreads();
    }

    // ---- epilogue ----
    #pragma unroll
    for (int t2 = 0; t2 < 2; ++t2) {
        f32x4 a = t2 ? acc1 : acc0;
        int cc = col0 + wc + t2 * 16 + (l & 15);
        float bvv = bias ? bias[cc] : 0.0f;
        #pragma unroll
        for (int rg = 0; rg < 4; ++rg) {
            int rr = row0 + wr + (l >> 4) * 4 + rg;
            float v = (a[rg] + bvv) * scale;
            if (R) v += R[(size_t)rr * Nn + cc];
            if (headmajor) {
                int h = cc >> 6, d = cc & 63, im = rr >> 10, n = rr & 1023;
                C[(((size_t)(im * 4 + h)) * 1024 + n) * 64 + d] = v;
            } else {
                C[(size_t)rr * ldc + cc] = v;
            }
        }
    }
}

// ---------------------------------------------------------------------------
__global__ __launch_bounds__(256) void posenc_k(
    const float* __restrict__ kpts, const float* __restrict__ Wr,
    float* __restrict__ encc, float* __restrict__ encs)
{
    int idx = blockIdx.x * 256 + threadIdx.x;          // N*32
    if (idx >= NTOK * 32) return;
    int i = idx >> 5, f = idx & 31;
    float p = kpts[i * 2 + 0] * Wr[f] + kpts[i * 2 + 1] * Wr[32 + f];
    float c = cosf(p), s = sinf(p);
    encc[i * 64 + 2 * f]     = c;  encc[i * 64 + 2 * f + 1] = c;
    encs[i * 64 + 2 * f]     = s;  encs[i * 64 + 2 * f + 1] = s;
}

// ---------------------------------------------------------------------------
// Split qkv [2048 x 768] (col = h*192 + d*3 + {q,k,v}) into vhead-major
// [8][1024][64] (vhead = im*4+h), applying RoPE to q and k.
// ---------------------------------------------------------------------------
__global__ __launch_bounds__(256) void splitrope_k(
    const float* __restrict__ qkv, const float* __restrict__ encc,
    const float* __restrict__ encs, float* __restrict__ qh,
    float* __restrict__ kh, float* __restrict__ vh)
{
    int n = blockIdx.x, t = threadIdx.x;  // n: 0..2047, t = h*64 + d
    int h = t >> 6, d = t & 63;
    int im = n >> 10, nl = n & 1023;
    const float* base  = qkv + (size_t)n * 768 + h * 192 + d * 3;
    const float* pbase = qkv + (size_t)n * 768 + h * 192 + (d ^ 1) * 3;
    float c = encc[n * 64 + d], s = encs[n * 64 + d];
    float q = base[0], k = base[1], v = base[2];
    float qp = pbase[0], kp = pbase[1];
    float sgn = (d & 1) ? 1.0f : -1.0f;
    size_t o = (((size_t)(im * 4 + h)) * 1024 + nl) * 64 + d;
    qh[o] = q * c + sgn * qp * s;
    kh[o] = k * c + sgn * kp * s;
    vh[o] = v;
}

__global__ __launch_bounds__(256) void copyvec_k(
    float* __restrict__ dst, const float* __restrict__ src, int n)
{
    int i = blockIdx.x * 256 + threadIdx.x;
    if (i < n) dst[i] = src[i];
}

// ---------------------------------------------------------------------------
// Attention v3: flash-style online softmax, fp32.
// Block = (16-query tile, vhead). Grid (64, 8). 256 threads.
// cross: kv head = vh ^ 4. out: [2048][256], row = im*1024+n, col = h*64+d.
// ---------------------------------------------------------------------------
__global__ __launch_bounds__(256) void attn_k(
    const float* __restrict__ heads_q, const float* __restrict__ heads_k,
    const float* __restrict__ heads_v, float* __restrict__ out,
    float scale, int cross)
{
    const int qt = blockIdx.x, vh = blockIdx.y;
    const int kvh = cross ? (vh ^ 4) : vh;
    const int t = threadIdx.x;
    const int tq = t >> 4, tl = t & 15;
    const int n0 = qt * 16;

    __shared__ float kt[32][68];
    __shared__ float vt[32][68];
    __shared__ float st[16][36];

    float4 qreg[16];
    {
        const float4* Qp = (const float4*)(heads_q + (((size_t)vh * 1024) + n0 + tq) * 64);
        #pragma unroll
        for (int d = 0; d < 16; ++d) qreg[d] = Qp[d];
    }

    const float* Kbase = heads_k + (size_t)kvh * 1024 * 64;
    const float* Vbase = heads_v + (size_t)kvh * 1024 * 64;

    float m = -1e30f, l = 0.0f;
    float4 o = {0.f, 0.f, 0.f, 0.f};
    const int sr = t >> 3, scol = (t & 7) * 8;

    for (int j0 = 0; j0 < 1024; j0 += 32) {
        const float4* kp = (const float4*)(Kbase + (size_t)(j0 + sr) * 64 + scol);
        const float4* vp = (const float4*)(Vbase + (size_t)(j0 + sr) * 64 + scol);
        float4 ka = kp[0], kb = kp[1];
        float4 va = vp[0], vb = vp[1];
        __syncthreads();
        *(float4*)&kt[sr][scol]     = ka;
        *(float4*)&kt[sr][scol + 4] = kb;
        *(float4*)&vt[sr][scol]     = va;
        *(float4*)&vt[sr][scol + 4] = vb;
        __syncthreads();

        #pragma unroll
        for (int u = 0; u < 2; ++u) {
            int j = tl + u * 16;
            const float4* kr = (const float4*)&kt[j][0];
            float a = 0.f;
            #pragma unroll
            for (int d = 0; d < 16; ++d) {
                float4 qv = qreg[d], kv = kr[d];
                a += qv.x * kv.x + qv.y * kv.y + qv.z * kv.z + qv.w * kv.w;
            }
            st[tq][j] = a * scale;
        }
        __syncthreads();

        float tm = m;
        #pragma unroll
        for (int j = 0; j < 32; ++j) tm = fmaxf(tm, st[tq][j]);
        float alpha = __expf(m - tm);
        float lsum = 0.f;
        float4 oa = {0.f, 0.f, 0.f, 0.f};
        const int c = tl * 4;
        #pragma unroll 4
        for (int j = 0; j < 32; ++j) {
            float p = __expf(st[tq][j] - tm);
            lsum += p;
            float4 v = *(const float4*)&vt[j][c];
            oa.x = fmaf(p, v.x, oa.x);
            oa.y = fmaf(p, v.y, oa.y);
            oa.z = fmaf(p, v.z, oa.z);
            oa.w = fmaf(p, v.w, oa.w);
        }
        l = l * alpha + lsum;
        o.x = o.x * alpha + oa.x;
        o.y = o.y * alpha + oa.y;
        o.z = o.z * alpha + oa.z;
        o.w = o.w * alpha + oa.w;
        m = tm;
    }

    float inv = 1.0f / l;
    float4 r;
    r.x = o.x * inv; r.y = o.y * inv; r.z = o.z * inv; r.w = o.w * inv;
    int row = (vh >> 2) * 1024 + n0 + tq;
    *(float4*)&out[(size_t)row * 256 + (vh & 3) * 64 + tl * 4] = r;
}

// ---------------------------------------------------------------------------
// In-place LayerNorm (512) + exact GELU. Block per row (2048 rows).
// ---------------------------------------------------------------------------
__global__ __launch_bounds__(256) void lngelu_k(
    float* __restrict__ x, const float* __restrict__ g,
    const float* __restrict__ beta)
{
    int row = blockIdx.x, t = threadIdx.x;
    __shared__ float red[256];
    float v0 = x[(size_t)row * 512 + t];
    float v1 = x[(size_t)row * 512 + t + 256];
    red[t] = v0 + v1; __syncthreads();
    for (int s = 128; s > 0; s >>= 1) {
        if (t < s) red[t] += red[t + s];
        __syncthreads();
    }
    float mu = red[0] * (1.0f / 512.0f); __syncthreads();
    float d0 = v0 - mu, d1 = v1 - mu;
    red[t] = d0 * d0 + d1 * d1; __syncthreads();
    for (int s = 128; s > 0; s >>= 1) {
        if (t < s) red[t] += red[t + s];
        __syncthreads();
    }
    float rstd = rsqrtf(red[0] * (1.0f / 512.0f) + 1e-5f);
    float y = d0 * rstd * g[t] + beta[t];
    x[(size_t)row * 512 + t] = 0.5f * y * (1.0f + erff(y * 0.70710678118654752f));
    y = d1 * rstd * g[t + 256] + beta[t + 256];
    x[(size_t)row * 512 + t + 256] = 0.5f * y * (1.0f + erff(y * 0.70710678118654752f));
}

// z[i] = dot(x[i], Wz) + bz[0]   (2048 rows)
__global__ __launch_bounds__(256) void z_k(
    const float* __restrict__ x, const float* __restrict__ Wz,
    const float* __restrict__ bz, float* __restrict__ z)
{
    int row = blockIdx.x, t = threadIdx.x;
    __shared__ float red[256];
    red[t] = x[(size_t)row * 256 + t] * Wz[t];
    __syncthreads();
    for (int s = 128; s > 0; s >>= 1) {
        if (t < s) red[t] += red[t + s];
        __syncthreads();
    }
    if (t == 0) z[row] = red[0] + bz[0];
}

__global__ __launch_bounds__(256) void rowlse_k(
    const float* __restrict__ sim, float* __restrict__ out)
{
    int row = blockIdx.x, t = threadIdx.x;
    __shared__ float red[256];
    float mx = -1e30f;
    for (int j = t; j < NTOK; j += 256) mx = fmaxf(mx, sim[(size_t)row * NTOK + j]);
    red[t] = mx; __syncthreads();
    for (int s = 128; s > 0; s >>= 1) {
        if (t < s) red[t] = fmaxf(red[t], red[t + s]);
        __syncthreads();
    }
    mx = red[0]; __syncthreads();
    float sum = 0.0f;
    for (int j = t; j < NTOK; j += 256) sum += expf(sim[(size_t)row * NTOK + j] - mx);
    red[t] = sum; __syncthreads();
    for (int s = 128; s > 0; s >>= 1) {
        if (t < s) red[t] += red[t + s];
        __syncthreads();
    }
    if (t == 0) out[row] = mx + logf(red[0]);
}

__global__ __launch_bounds__(256) void collse_k(
    const float* __restrict__ sim, float* __restrict__ out)
{
    int col = blockIdx.x, t = threadIdx.x;
    __shared__ float red[256];
    float mx = -1e30f;
    for (int i = t; i < NTOK; i += 256) mx = fmaxf(mx, sim[(size_t)i * NTOK + col]);
    red[t] = mx; __syncthreads();
    for (int s = 128; s > 0; s >>= 1) {
        if (t < s) red[t] = fmaxf(red[t], red[t + s]);
        __syncthreads();
    }
    mx = red[0]; __syncthreads();
    float sum = 0.0f;
    for (int i = t; i < NTOK; i += 256) sum += expf(sim[(size_t)i * NTOK + col] - mx);
    red[t] = sum; __syncthreads();
    for (int s = 128; s > 0; s >>= 1) {
        if (t < s) red[t] += red[t + s];
        __syncthreads();
    }
    if (t == 0) out[col] = mx + logf(red[0]);
}

// inner = 2*sim - rowlse[i] - collse[j] + logsig(z0[i]) + logsig(z1[j])
__global__ __launch_bounds__(256) void assemble_k(
    const float* __restrict__ sim, const float* __restrict__ rls,
    const float* __restrict__ cls, const float* __restrict__ z0,
    const float* __restrict__ z1, float* __restrict__ out)
{
    int idx = blockIdx.x * 256 + threadIdx.x;
    const int W = NTOK + 1;
    if (idx >= W * W) return;
    int i = idx / W, j = idx % W;
    float v;
    if (i < NTOK && j < NTOK) {
        v = 2.0f * sim[(size_t)i * NTOK + j] - rls[i] - cls[j] + logsigf(z0[i]) + logsigf(z1[j]);
    } else if (i < NTOK) {
        v = logsigf(-z0[i]);
    } else if (j < NTOK) {
        v = logsigf(-z1[j]);
    } else {
        v = 0.0f;
    }
    out[idx] = v;
}

// ---------------------------------------------------------------------------
extern "C" void kernel_launch(void* const* d_in, const int* in_sizes, int n_in,
                              void* d_out, int out_size, void* d_ws, size_t ws_size,
                              hipStream_t stream)
{
    const float* desc0 = (const float*)d_in[0];
    const float* desc1 = (const float*)d_in[1];
    const float* kpts0 = (const float*)d_in[2];
    const float* kpts1 = (const float*)d_in[3];
    const float* Wr    = (const float*)d_in[4];
    const float* sWqkv = (const float*)d_in[5];
    const float* sbqkv = (const float*)d_in[6];
    const float* sWo   = (const float*)d_in[7];
    const float* sbo   = (const float*)d_in[8];
    const float* sfW1  = (const float*)d_in[9];
    const float* sfb1  = (const float*)d_in[10];
    const float* sfg   = (const float*)d_in[11];
    const float* sfbt  = (const float*)d_in[12];
    const float* sfW2  = (const float*)d_in[13];
    const float* sfb2  = (const float*)d_in[14];
    const float* cWqk  = (const float*)d_in[15];
    const float* cbqk  = (const float*)d_in[16];
    const float* cWv   = (const float*)d_in[17];
    const float* cbv   = (const float*)d_in[18];
    const float* cWo   = (const float*)d_in[19];
    const float* cbo   = (const float*)d_in[20];
    const float* cfW1  = (const float*)d_in[21];
    const float* cfb1  = (const float*)d_in[22];
    const float* cfg   = (const float*)d_in[23];
    const float* cfbt  = (const float*)d_in[24];
    const float* cfW2  = (const float*)d_in[25];
    const float* cfb2  = (const float*)d_in[26];
    const float* mWp   = (const float*)d_in[27];
    const float* mbp   = (const float*)d_in[28];
    const float* mWz   = (const float*)d_in[29];
    const float* mbz   = (const float*)d_in[30];

    float* ws = (float*)d_ws;
    // Layout (floats), total 4,460,544 fl = 17.8 MB:
    float* x    = ws;                  // 524288  [2048][256]
    float* encc = ws + 524288;         // 131072  [2048][64]
    float* encs = ws + 655360;         // 131072
    float* qkv  = ws + 786432;         // 1572864 [2048][768] (self only)
    float* mo   = qkv;                 // 524288  (FFN phase; qkv dead)
    float* pre  = qkv + 524288;        // 1048576 [2048][512]
    float* qh   = ws + 2359296;        // 524288  [8][1024][64]
    float* kh   = ws + 2883584;        // 524288
    float* vh   = ws + 3407872;        // 524288
    float* msg  = ws + 3932160;        // 524288  [2048][256]
    float* zb   = ws + 4456448;        // 2048
    float* rlsb = ws + 4458496;        // 1024
    float* clsb = ws + 4459520;        // 1024
    float* sim  = qh;                  // 1048576 (layers done; spans qh+kh)
    float* md   = msg;                 // [2048][256]

    auto gemmb = [&](const float* A0, const float* A1, const float* B,
                     const float* bias, const float* R, float* C,
                     int M, int K, int Nn, int ldc, float scale, int tB, int hm) {
        gemm_bf_k<<<dim3(Nn / 64, M / 32), 256, 0, stream>>>(A0, A1, B, bias, R, C, M, K, Nn, ldc, scale, tB, hm);
    };

    const float SELF_SCALE  = 0.125f;               // DH^-0.5
    const float CROSS_SCALE = 0.35355339059327373f; // DH^-0.25

    copyvec_k<<<(NTOK * DM + 255) / 256, 256, 0, stream>>>(x, desc0, NTOK * DM);
    copyvec_k<<<(NTOK * DM + 255) / 256, 256, 0, stream>>>(x + NTOK * DM, desc1, NTOK * DM);
    posenc_k<<<(NTOK * 32 + 255) / 256, 256, 0, stream>>>(kpts0, Wr, encc, encs);
    posenc_k<<<(NTOK * 32 + 255) / 256, 256, 0, stream>>>(kpts1, Wr, encc + 65536, encs + 65536);

    for (int l = 0; l < NL; ++l) {
        // ---- self block (both images batched) ----
        gemmb(x, nullptr, sWqkv + (size_t)l * 256 * 768, sbqkv + (size_t)l * 768,
              nullptr, qkv, 2048, 256, 768, 768, 1.0f, 0, 0);
        splitrope_k<<<2048, 256, 0, stream>>>(qkv, encc, encs, qh, kh, vh);
        attn_k<<<dim3(64, 8), 256, 0, stream>>>(qh, kh, vh, msg, SELF_SCALE, 0);
        gemmb(msg, nullptr, sWo + (size_t)l * 256 * 256, sbo + (size_t)l * 256,
              nullptr, mo, 2048, 256, 256, 256, 1.0f, 0, 0);
        gemmb(x, mo, sfW1 + (size_t)l * 512 * 512, sfb1 + (size_t)l * 512,
              nullptr, pre, 2048, 512, 512, 512, 1.0f, 0, 0);
        lngelu_k<<<2048, 256, 0, stream>>>(pre, sfg + (size_t)l * 512, sfbt + (size_t)l * 512);
        gemmb(pre, nullptr, sfW2 + (size_t)l * 512 * 256, sfb2 + (size_t)l * 256,
              x, x, 2048, 512, 256, 256, 1.0f, 0, 0);

        // ---- cross block ----
        gemmb(x, nullptr, cWqk + (size_t)l * 256 * 256, cbqk + (size_t)l * 256,
              nullptr, qh, 2048, 256, 256, 256, CROSS_SCALE, 0, 1);  // headmajor qk
        gemmb(x, nullptr, cWv + (size_t)l * 256 * 256, cbv + (size_t)l * 256,
              nullptr, vh, 2048, 256, 256, 256, 1.0f, 0, 1);         // headmajor v
        attn_k<<<dim3(64, 8), 256, 0, stream>>>(qh, qh, vh, msg, 1.0f, 1);
        gemmb(msg, nullptr, cWo + (size_t)l * 256 * 256, cbo + (size_t)l * 256,
              nullptr, mo, 2048, 256, 256, 256, 1.0f, 0, 0);
        gemmb(x, mo, cfW1 + (size_t)l * 512 * 512, cfb1 + (size_t)l * 512,
              nullptr, pre, 2048, 512, 512, 512, 1.0f, 0, 0);
        lngelu_k<<<2048, 256, 0, stream>>>(pre, cfg + (size_t)l * 512, cfbt + (size_t)l * 512);
        gemmb(pre, nullptr, cfW2 + (size_t)l * 512 * 256, cfb2 + (size_t)l * 256,
              x, x, 2048, 512, 256, 256, 1.0f, 0, 0);
    }

    // ---- assignment head ----
    const float MD_SCALE = 0.25f; // D^-0.25
    gemmb(x, nullptr, mWp, mbp, nullptr, md, 2048, 256, 256, 256, MD_SCALE, 0, 0);
    z_k<<<2048, 256, 0, stream>>>(x, mWz, mbz, zb);
    gemmb(md, nullptr, md + 1024 * 256, nullptr, nullptr, sim,
          1024, 256, 1024, 1024, 1.0f, 1, 0);   // sim = md0 @ md1^T
    rowlse_k<<<NTOK, 256, 0, stream>>>(sim, rlsb);
    collse_k<<<NTOK, 256, 0, stream>>>(sim, clsb);
    const int W = NTOK + 1;
    assemble_k<<<(W * W + 255) / 256, 256, 0, stream>>>(sim, rlsb, clsb, zb, zb + 1024, (float*)d_out);
}

// Round 6
// 2143.970 us; speedup vs baseline: 8.9528x; 1.3857x over previous
//
#include <hip/hip_runtime.h>
#include <cmath>

// LightGlue forward. GEMMs + attention in bf16 MFMA (fp32 staging-convert),
// everything else fp32. N=1024, D=256, H=4, DH=64, L=9. Batched (M=2048).
#define NTOK 1024
#define DM   256
#define NH   4
#define DH   64
#define NL   9

typedef __attribute__((ext_vector_type(8))) __bf16 bf16x8;
typedef __attribute__((ext_vector_type(4))) float  f32x4;

__device__ __forceinline__ float logsigf(float x) {
    return fminf(x, 0.0f) - log1pf(expf(-fabsf(x)));
}

__device__ __forceinline__ __bf16 f2bf(float f) {
    unsigned u = __float_as_uint(f);
    u = (u + 0x7FFFu + ((u >> 16) & 1u)) >> 16;          // round-nearest-even
    unsigned short s = (unsigned short)u;
    return __builtin_bit_cast(__bf16, s);
}
__device__ __forceinline__ unsigned short bfbits(float f) {
    return __builtin_bit_cast(unsigned short, f2bf(f));
}

// ---------------------------------------------------------------------------
// bf16-MFMA GEMM (unchanged from round 5): C = (A @ B + bias)*scale + R
// ---------------------------------------------------------------------------
__global__ __launch_bounds__(256) void gemm_bf_k(
    const float* __restrict__ A0, const float* __restrict__ A1,
    const float* __restrict__ B, const float* __restrict__ bias,
    const float* __restrict__ R, float* __restrict__ C,
    int M, int K, int Nn, int ldc, float scale, int transB, int headmajor)
{
    __shared__ __bf16 As[32][40];
    __shared__ __bf16 Bs[64][40];
    const int tid = threadIdx.x;
    const int w = tid >> 6, l = tid & 63;
    const int row0 = blockIdx.y * 32, col0 = blockIdx.x * 64;
    const int wr = (w >> 1) * 16;
    const int wc = (w & 1) * 32;
    f32x4 acc0 = {0.f, 0.f, 0.f, 0.f};
    f32x4 acc1 = {0.f, 0.f, 0.f, 0.f};

    const int ar = tid >> 3, ac = (tid & 7) * 4;
    const int bkr = tid >> 4, bnc = (tid & 15) * 4;
    const int tnr = tid >> 2, tkc = (tid & 3) * 8;

    for (int k0 = 0; k0 < K; k0 += 32) {
        {
            float4 v;
            if (A1) {
                int kk = k0 + ac;
                const float* src = (kk < 256)
                    ? &A0[(size_t)(row0 + ar) * 256 + kk]
                    : &A1[(size_t)(row0 + ar) * 256 + (kk - 256)];
                v = *(const float4*)src;
            } else {
                v = *(const float4*)&A0[(size_t)(row0 + ar) * K + k0 + ac];
            }
            __bf16* d = &As[ar][ac];
            d[0] = f2bf(v.x); d[1] = f2bf(v.y); d[2] = f2bf(v.z); d[3] = f2bf(v.w);
        }
        if (!transB) {
            #pragma unroll
            for (int h = 0; h < 2; ++h) {
                int kr = bkr + h * 16;
                float4 v = *(const float4*)&B[(size_t)(k0 + kr) * Nn + col0 + bnc];
                Bs[bnc + 0][kr] = f2bf(v.x);
                Bs[bnc + 1][kr] = f2bf(v.y);
                Bs[bnc + 2][kr] = f2bf(v.z);
                Bs[bnc + 3][kr] = f2bf(v.w);
            }
        } else {
            float4 a = *(const float4*)&B[(size_t)(col0 + tnr) * K + k0 + tkc];
            float4 b = *(const float4*)&B[(size_t)(col0 + tnr) * K + k0 + tkc + 4];
            __bf16* d = &Bs[tnr][tkc];
            d[0] = f2bf(a.x); d[1] = f2bf(a.y); d[2] = f2bf(a.z); d[3] = f2bf(a.w);
            d[4] = f2bf(b.x); d[5] = f2bf(b.y); d[6] = f2bf(b.z); d[7] = f2bf(b.w);
        }
        __syncthreads();
        bf16x8 af  = *(const bf16x8*)&As[wr + (l & 15)][(l >> 4) * 8];
        bf16x8 bf0 = *(const bf16x8*)&Bs[wc + (l & 15)][(l >> 4) * 8];
        bf16x8 bf1 = *(const bf16x8*)&Bs[wc + 16 + (l & 15)][(l >> 4) * 8];
        acc0 = __builtin_amdgcn_mfma_f32_16x16x32_bf16(af, bf0, acc0, 0, 0, 0);
        acc1 = __builtin_amdgcn_mfma_f32_16x16x32_bf16(af, bf1, acc1, 0, 0, 0);
        __syncthreads();
    }

    #pragma unroll
    for (int t2 = 0; t2 < 2; ++t2) {
        f32x4 a = t2 ? acc1 : acc0;
        int cc = col0 + wc + t2 * 16 + (l & 15);
        float bvv = bias ? bias[cc] : 0.0f;
        #pragma unroll
        for (int rg = 0; rg < 4; ++rg) {
            int rr = row0 + wr + (l >> 4) * 4 + rg;
            float v = (a[rg] + bvv) * scale;
            if (R) v += R[(size_t)rr * Nn + cc];
            if (headmajor) {
                int h = cc >> 6, d = cc & 63, im = rr >> 10, n = rr & 1023;
                C[(((size_t)(im * 4 + h)) * 1024 + n) * 64 + d] = v;
            } else {
                C[(size_t)rr * ldc + cc] = v;
            }
        }
    }
}

// ---------------------------------------------------------------------------
__global__ __launch_bounds__(256) void posenc_k(
    const float* __restrict__ kpts, const float* __restrict__ Wr,
    float* __restrict__ encc, float* __restrict__ encs)
{
    int idx = blockIdx.x * 256 + threadIdx.x;
    if (idx >= NTOK * 32) return;
    int i = idx >> 5, f = idx & 31;
    float p = kpts[i * 2 + 0] * Wr[f] + kpts[i * 2 + 1] * Wr[32 + f];
    float c = cosf(p), s = sinf(p);
    encc[i * 64 + 2 * f]     = c;  encc[i * 64 + 2 * f + 1] = c;
    encs[i * 64 + 2 * f]     = s;  encs[i * 64 + 2 * f + 1] = s;
}

__global__ __launch_bounds__(256) void splitrope_k(
    const float* __restrict__ qkv, const float* __restrict__ encc,
    const float* __restrict__ encs, float* __restrict__ qh,
    float* __restrict__ kh, float* __restrict__ vh)
{
    int n = blockIdx.x, t = threadIdx.x;  // n: 0..2047, t = h*64 + d
    int h = t >> 6, d = t & 63;
    int im = n >> 10, nl = n & 1023;
    const float* base  = qkv + (size_t)n * 768 + h * 192 + d * 3;
    const float* pbase = qkv + (size_t)n * 768 + h * 192 + (d ^ 1) * 3;
    float c = encc[n * 64 + d], s = encs[n * 64 + d];
    float q = base[0], k = base[1], v = base[2];
    float qp = pbase[0], kp = pbase[1];
    float sgn = (d & 1) ? 1.0f : -1.0f;
    size_t o = (((size_t)(im * 4 + h)) * 1024 + nl) * 64 + d;
    qh[o] = q * c + sgn * qp * s;
    kh[o] = k * c + sgn * kp * s;
    vh[o] = v;
}

__global__ __launch_bounds__(256) void copyvec_k(
    float* __restrict__ dst, const float* __restrict__ src, int n)
{
    int i = blockIdx.x * 256 + threadIdx.x;
    if (i < n) dst[i] = src[i];
}

// ---------------------------------------------------------------------------
// Attention v4: flash-style, bf16 MFMA.
// Block = (16-query tile qt, vhead hv). Grid (64, 8). 4 waves; wave w owns
// keys [w*256, w*256+256) in 8 tiles of 32, with wave-private LDS regions
// (no barriers in the hot loop). Final merge of (m,l,O) across waves via LDS.
// Layouts (bf16, strides chosen 16B-aligned & bank-spread):
//   kb[32][72]: K tile, [j][d]   -> S B-frag  = contiguous b128
//   vt[64][40]: V tile, [d][j]   -> PV B-frag = contiguous b128 (transposed write)
//   pt[16][40]: P tile, [q][j]   -> PV A-frag = contiguous b128
// S C-layout (HW-verified): row(q)=quad*4+reg, col(j)=lane&15.
// A/B frags use identical k-slot claims, so frag k-permutations cancel.
// ---------------------------------------------------------------------------
__global__ __launch_bounds__(256) void attn_k(
    const float* __restrict__ Qg, const float* __restrict__ Kg,
    const float* __restrict__ Vg, float* __restrict__ out,
    float scale, int cross)
{
    const int qt = blockIdx.x, hv = blockIdx.y;
    const int kvh = cross ? (hv ^ 4) : hv;
    const int tid = threadIdx.x;
    const int w = tid >> 6, lane = tid & 63;
    const int quad = lane >> 4, l16 = lane & 15;
    const int n0 = qt * 16;

    __shared__ __align__(16) char smem[44032];
    char* base = smem + w * 11008;
    __bf16* kb  = (__bf16*)(base);          // 32 x 72
    __bf16* vtb = (__bf16*)(base + 4608);   // 64 x 40
    __bf16* ptb = (__bf16*)(base + 9728);   // 16 x 40

    // Q fragments (A-operand), held in regs for the whole kernel
    bf16x8 qf[2];
    {
        const float* Qp = Qg + (((size_t)hv * 1024) + n0 + l16) * 64;
        #pragma unroll
        for (int kt = 0; kt < 2; ++kt) {
            const float* p = Qp + kt * 32 + quad * 8;
            float4 a = *(const float4*)p, b = *(const float4*)(p + 4);
            bf16x8 q8;
            q8[0] = f2bf(a.x); q8[1] = f2bf(a.y); q8[2] = f2bf(a.z); q8[3] = f2bf(a.w);
            q8[4] = f2bf(b.x); q8[5] = f2bf(b.y); q8[6] = f2bf(b.z); q8[7] = f2bf(b.w);
            qf[kt] = q8;
        }
    }

    const float* Kbase = Kg + (size_t)kvh * 1024 * 64;
    const float* Vbase = Vg + (size_t)kvh * 1024 * 64;

    float m[4] = {-1e30f, -1e30f, -1e30f, -1e30f};
    float lsum[4] = {0.f, 0.f, 0.f, 0.f};
    f32x4 o[4] = {{0,0,0,0},{0,0,0,0},{0,0,0,0},{0,0,0,0}};

    // staging maps
    const int kj = lane >> 1, kd = (lane & 1) * 32;          // K: row, col-half
    const int vjp = lane & 15, vd0 = (lane >> 4) * 16;       // V: row-pair, col-quarter

    for (int t = 0; t < 8; ++t) {
        const int j0 = w * 256 + t * 32;

        // ---- stage K [j][d] ----
        {
            const float* kp = Kbase + (size_t)(j0 + kj) * 64 + kd;
            __bf16* kr = kb + kj * 72 + kd;
            #pragma unroll
            for (int g = 0; g < 4; ++g) {
                float4 a = *(const float4*)(kp + g * 8);
                float4 b = *(const float4*)(kp + g * 8 + 4);
                bf16x8 k8;
                k8[0] = f2bf(a.x); k8[1] = f2bf(a.y); k8[2] = f2bf(a.z); k8[3] = f2bf(a.w);
                k8[4] = f2bf(b.x); k8[5] = f2bf(b.y); k8[6] = f2bf(b.z); k8[7] = f2bf(b.w);
                *(bf16x8*)(kr + g * 8) = k8;
            }
        }
        // ---- stage V transposed [d][j] ----
        {
            const float* va = Vbase + (size_t)(j0 + 2 * vjp) * 64 + vd0;
            const float* vb = va + 64;
            float fa[16], fb[16];
            #pragma unroll
            for (int g = 0; g < 4; ++g) {
                *(float4*)&fa[g * 4] = *(const float4*)(va + g * 4);
                *(float4*)&fb[g * 4] = *(const float4*)(vb + g * 4);
            }
            #pragma unroll
            for (int i = 0; i < 16; ++i) {
                unsigned pk = ((unsigned)bfbits(fb[i]) << 16) | bfbits(fa[i]);
                *(unsigned*)((char*)vtb + ((vd0 + i) * 40 + 2 * vjp) * 2) = pk;
            }
        }

        // ---- S = Q K^T : 2 j-subtiles x 2 k-tiles ----
        f32x4 s0 = {0,0,0,0}, s1 = {0,0,0,0};
        #pragma unroll
        for (int kt = 0; kt < 2; ++kt) {
            bf16x8 k0 = *(const bf16x8*)(kb + (0 * 16 + l16) * 72 + kt * 32 + quad * 8);
            bf16x8 k1 = *(const bf16x8*)(kb + (1 * 16 + l16) * 72 + kt * 32 + quad * 8);
            s0 = __builtin_amdgcn_mfma_f32_16x16x32_bf16(qf[kt], k0, s0, 0, 0, 0);
            s1 = __builtin_amdgcn_mfma_f32_16x16x32_bf16(qf[kt], k1, s1, 0, 0, 0);
        }

        // ---- online softmax (rows q = quad*4+r live in 16 lanes x 2 regs) ----
        float rm[4], p0[4], p1[4], rs[4];
        #pragma unroll
        for (int r = 0; r < 4; ++r) {
            s0[r] *= scale; s1[r] *= scale;
            rm[r] = fmaxf(s0[r], s1[r]);
        }
        #pragma unroll
        for (int ofs = 1; ofs < 16; ofs <<= 1)
            #pragma unroll
            for (int r = 0; r < 4; ++r)
                rm[r] = fmaxf(rm[r], __shfl_xor(rm[r], ofs));
        #pragma unroll
        for (int r = 0; r < 4; ++r) {
            float mn = fmaxf(m[r], rm[r]);
            float alpha = __expf(m[r] - mn);
            m[r] = mn;
            p0[r] = __expf(s0[r] - mn);
            p1[r] = __expf(s1[r] - mn);
            rs[r] = p0[r] + p1[r];
            lsum[r] *= alpha;
            #pragma unroll
            for (int dt = 0; dt < 4; ++dt) o[dt][r] *= alpha;
        }
        #pragma unroll
        for (int ofs = 1; ofs < 16; ofs <<= 1)
            #pragma unroll
            for (int r = 0; r < 4; ++r)
                rs[r] += __shfl_xor(rs[r], ofs);
        #pragma unroll
        for (int r = 0; r < 4; ++r) lsum[r] += rs[r];

        // ---- P -> LDS (C-layout scatter), read back as A-frag ----
        #pragma unroll
        for (int r = 0; r < 4; ++r) {
            ptb[(quad * 4 + r) * 40 + l16]      = f2bf(p0[r]);
            ptb[(quad * 4 + r) * 40 + 16 + l16] = f2bf(p1[r]);
        }
        bf16x8 pf = *(const bf16x8*)(ptb + l16 * 40 + quad * 8);
        #pragma unroll
        for (int dt = 0; dt < 4; ++dt) {
            bf16x8 vf = *(const bf16x8*)(vtb + (dt * 16 + l16) * 40 + quad * 8);
            o[dt] = __builtin_amdgcn_mfma_f32_16x16x32_bf16(pf, vf, o[dt], 0, 0, 0);
        }
    }

    // ---- merge across 4 waves ----
    __syncthreads();
    float* Om = (float*)smem;          // [64][64] : row = w*16 + q
    float* mm = Om + 4096;             // [64]
    float* lm = mm + 64;               // [64]
    #pragma unroll
    for (int dt = 0; dt < 4; ++dt)
        #pragma unroll
        for (int r = 0; r < 4; ++r)
            Om[(w * 16 + quad * 4 + r) * 64 + dt * 16 + l16] = o[dt][r];
    if (l16 == 0) {
        #pragma unroll
        for (int r = 0; r < 4; ++r) {
            mm[w * 16 + quad * 4 + r] = m[r];
            lm[w * 16 + quad * 4 + r] = lsum[r];
        }
    }
    __syncthreads();

    const int q = tid >> 4, dg = tid & 15;
    float M = -1e30f;
    #pragma unroll
    for (int w2 = 0; w2 < 4; ++w2) M = fmaxf(M, mm[w2 * 16 + q]);
    float L = 0.f;
    float4 acc = {0.f, 0.f, 0.f, 0.f};
    #pragma unroll
    for (int w2 = 0; w2 < 4; ++w2) {
        float e = __expf(mm[w2 * 16 + q] - M);
        L += e * lm[w2 * 16 + q];
        float4 ov = *(const float4*)&Om[(w2 * 16 + q) * 64 + dg * 4];
        acc.x += e * ov.x; acc.y += e * ov.y; acc.z += e * ov.z; acc.w += e * ov.w;
    }
    float inv = 1.0f / L;
    float4 r4;
    r4.x = acc.x * inv; r4.y = acc.y * inv; r4.z = acc.z * inv; r4.w = acc.w * inv;
    int row = (hv >> 2) * 1024 + n0 + q;
    *(float4*)&out[(size_t)row * 256 + (hv & 3) * 64 + dg * 4] = r4;
}

// ---------------------------------------------------------------------------
__global__ __launch_bounds__(256) void lngelu_k(
    float* __restrict__ x, const float* __restrict__ g,
    const float* __restrict__ beta)
{
    int row = blockIdx.x, t = threadIdx.x;
    __shared__ float red[256];
    float v0 = x[(size_t)row * 512 + t];
    float v1 = x[(size_t)row * 512 + t + 256];
    red[t] = v0 + v1; __syncthreads();
    for (int s = 128; s > 0; s >>= 1) {
        if (t < s) red[t] += red[t + s];
        __syncthreads();
    }
    float mu = red[0] * (1.0f / 512.0f); __syncthreads();
    float d0 = v0 - mu, d1 = v1 - mu;
    red[t] = d0 * d0 + d1 * d1; __syncthreads();
    for (int s = 128; s > 0; s >>= 1) {
        if (t < s) red[t] += red[t + s];
        __syncthreads();
    }
    float rstd = rsqrtf(red[0] * (1.0f / 512.0f) + 1e-5f);
    float y = d0 * rstd * g[t] + beta[t];
    x[(size_t)row * 512 + t] = 0.5f * y * (1.0f + erff(y * 0.70710678118654752f));
    y = d1 * rstd * g[t + 256] + beta[t + 256];
    x[(size_t)row * 512 + t + 256] = 0.5f * y * (1.0f + erff(y * 0.70710678118654752f));
}

__global__ __launch_bounds__(256) void z_k(
    const float* __restrict__ x, const float* __restrict__ Wz,
    const float* __restrict__ bz, float* __restrict__ z)
{
    int row = blockIdx.x, t = threadIdx.x;
    __shared__ float red[256];
    red[t] = x[(size_t)row * 256 + t] * Wz[t];
    __syncthreads();
    for (int s = 128; s > 0; s >>= 1) {
        if (t < s) red[t] += red[t + s];
        __syncthreads();
    }
    if (t == 0) z[row] = red[0] + bz[0];
}

__global__ __launch_bounds__(256) void rowlse_k(
    const float* __restrict__ sim, float* __restrict__ out)
{
    int row = blockIdx.x, t = threadIdx.x;
    __shared__ float red[256];
    float mx = -1e30f;
    for (int j = t; j < NTOK; j += 256) mx = fmaxf(mx, sim[(size_t)row * NTOK + j]);
    red[t] = mx; __syncthreads();
    for (int s = 128; s > 0; s >>= 1) {
        if (t < s) red[t] = fmaxf(red[t], red[t + s]);
        __syncthreads();
    }
    mx = red[0]; __syncthreads();
    float sum = 0.0f;
    for (int j = t; j < NTOK; j += 256) sum += expf(sim[(size_t)row * NTOK + j] - mx);
    red[t] = sum; __syncthreads();
    for (int s = 128; s > 0; s >>= 1) {
        if (t < s) red[t] += red[t + s];
        __syncthreads();
    }
    if (t == 0) out[row] = mx + logf(red[0]);
}

__global__ __launch_bounds__(256) void collse_k(
    const float* __restrict__ sim, float* __restrict__ out)
{
    int col = blockIdx.x, t = threadIdx.x;
    __shared__ float red[256];
    float mx = -1e30f;
    for (int i = t; i < NTOK; i += 256) mx = fmaxf(mx, sim[(size_t)i * NTOK + col]);
    red[t] = mx; __syncthreads();
    for (int s = 128; s > 0; s >>= 1) {
        if (t < s) red[t] = fmaxf(red[t], red[t + s]);
        __syncthreads();
    }
    mx = red[0]; __syncthreads();
    float sum = 0.0f;
    for (int i = t; i < NTOK; i += 256) sum += expf(sim[(size_t)i * NTOK + col] - mx);
    red[t] = sum; __syncthreads();
    for (int s = 128; s > 0; s >>= 1) {
        if (t < s) red[t] += red[t + s];
        __syncthreads();
    }
    if (t == 0) out[col] = mx + logf(red[0]);
}

__global__ __launch_bounds__(256) void assemble_k(
    const float* __restrict__ sim, const float* __restrict__ rls,
    const float* __restrict__ cls, const float* __restrict__ z0,
    const float* __restrict__ z1, float* __restrict__ out)
{
    int idx = blockIdx.x * 256 + threadIdx.x;
    const int W = NTOK + 1;
    if (idx >= W * W) return;
    int i = idx / W, j = idx % W;
    float v;
    if (i < NTOK && j < NTOK) {
        v = 2.0f * sim[(size_t)i * NTOK + j] - rls[i] - cls[j] + logsigf(z0[i]) + logsigf(z1[j]);
    } else if (i < NTOK) {
        v = logsigf(-z0[i]);
    } else if (j < NTOK) {
        v = logsigf(-z1[j]);
    } else {
        v = 0.0f;
    }
    out[idx] = v;
}

// ---------------------------------------------------------------------------
extern "C" void kernel_launch(void* const* d_in, const int* in_sizes, int n_in,
                              void* d_out, int out_size, void* d_ws, size_t ws_size,
                              hipStream_t stream)
{
    const float* desc0 = (const float*)d_in[0];
    const float* desc1 = (const float*)d_in[1];
    const float* kpts0 = (const float*)d_in[2];
    const float* kpts1 = (const float*)d_in[3];
    const float* Wr    = (const float*)d_in[4];
    const float* sWqkv = (const float*)d_in[5];
    const float* sbqkv = (const float*)d_in[6];
    const float* sWo   = (const float*)d_in[7];
    const float* sbo   = (const float*)d_in[8];
    const float* sfW1  = (const float*)d_in[9];
    const float* sfb1  = (const float*)d_in[10];
    const float* sfg   = (const float*)d_in[11];
    const float* sfbt  = (const float*)d_in[12];
    const float* sfW2  = (const float*)d_in[13];
    const float* sfb2  = (const float*)d_in[14];
    const float* cWqk  = (const float*)d_in[15];
    const float* cbqk  = (const float*)d_in[16];
    const float* cWv   = (const float*)d_in[17];
    const float* cbv   = (const float*)d_in[18];
    const float* cWo   = (const float*)d_in[19];
    const float* cbo   = (const float*)d_in[20];
    const float* cfW1  = (const float*)d_in[21];
    const float* cfb1  = (const float*)d_in[22];
    const float* cfg   = (const float*)d_in[23];
    const float* cfbt  = (const float*)d_in[24];
    const float* cfW2  = (const float*)d_in[25];
    const float* cfb2  = (const float*)d_in[26];
    const float* mWp   = (const float*)d_in[27];
    const float* mbp   = (const float*)d_in[28];
    const float* mWz   = (const float*)d_in[29];
    const float* mbz   = (const float*)d_in[30];

    float* ws = (float*)d_ws;
    float* x    = ws;                  // 524288  [2048][256]
    float* encc = ws + 524288;         // 131072  [2048][64]
    float* encs = ws + 655360;         // 131072
    float* qkv  = ws + 786432;         // 1572864 [2048][768] (self only)
    float* mo   = qkv;                 // 524288  (FFN phase; qkv dead)
    float* pre  = qkv + 524288;        // 1048576 [2048][512]
    float* qh   = ws + 2359296;        // 524288  [8][1024][64]
    float* kh   = ws + 2883584;        // 524288
    float* vh   = ws + 3407872;        // 524288
    float* msg  = ws + 3932160;        // 524288  [2048][256]
    float* zb   = ws + 4456448;        // 2048
    float* rlsb = ws + 4458496;        // 1024
    float* clsb = ws + 4459520;        // 1024
    float* sim  = qh;                  // 1048576 (layers done; spans qh+kh)
    float* md   = msg;                 // [2048][256]

    auto gemmb = [&](const float* A0, const float* A1, const float* B,
                     const float* bias, const float* R, float* C,
                     int M, int K, int Nn, int ldc, float scale, int tB, int hm) {
        gemm_bf_k<<<dim3(Nn / 64, M / 32), 256, 0, stream>>>(A0, A1, B, bias, R, C, M, K, Nn, ldc, scale, tB, hm);
    };

    const float SELF_SCALE  = 0.125f;               // DH^-0.5
    const float CROSS_SCALE = 0.35355339059327373f; // DH^-0.25

    copyvec_k<<<(NTOK * DM + 255) / 256, 256, 0, stream>>>(x, desc0, NTOK * DM);
    copyvec_k<<<(NTOK * DM + 255) / 256, 256, 0, stream>>>(x + NTOK * DM, desc1, NTOK * DM);
    posenc_k<<<(NTOK * 32 + 255) / 256, 256, 0, stream>>>(kpts0, Wr, encc, encs);
    posenc_k<<<(NTOK * 32 + 255) / 256, 256, 0, stream>>>(kpts1, Wr, encc + 65536, encs + 65536);

    for (int l = 0; l < NL; ++l) {
        // ---- self block (both images batched) ----
        gemmb(x, nullptr, sWqkv + (size_t)l * 256 * 768, sbqkv + (size_t)l * 768,
              nullptr, qkv, 2048, 256, 768, 768, 1.0f, 0, 0);
        splitrope_k<<<2048, 256, 0, stream>>>(qkv, encc, encs, qh, kh, vh);
        attn_k<<<dim3(64, 8), 256, 0, stream>>>(qh, kh, vh, msg, SELF_SCALE, 0);
        gemmb(msg, nullptr, sWo + (size_t)l * 256 * 256, sbo + (size_t)l * 256,
              nullptr, mo, 2048, 256, 256, 256, 1.0f, 0, 0);
        gemmb(x, mo, sfW1 + (size_t)l * 512 * 512, sfb1 + (size_t)l * 512,
              nullptr, pre, 2048, 512, 512, 512, 1.0f, 0, 0);
        lngelu_k<<<2048, 256, 0, stream>>>(pre, sfg + (size_t)l * 512, sfbt + (size_t)l * 512);
        gemmb(pre, nullptr, sfW2 + (size_t)l * 512 * 256, sfb2 + (size_t)l * 256,
              x, x, 2048, 512, 256, 256, 1.0f, 0, 0);

        // ---- cross block ----
        gemmb(x, nullptr, cWqk + (size_t)l * 256 * 256, cbqk + (size_t)l * 256,
              nullptr, qh, 2048, 256, 256, 256, CROSS_SCALE, 0, 1);  // headmajor qk
        gemmb(x, nullptr, cWv + (size_t)l * 256 * 256, cbv + (size_t)l * 256,
              nullptr, vh, 2048, 256, 256, 256, 1.0f, 0, 1);         // headmajor v
        attn_k<<<dim3(64, 8), 256, 0, stream>>>(qh, qh, vh, msg, 1.0f, 1);
        gemmb(msg, nullptr, cWo + (size_t)l * 256 * 256, cbo + (size_t)l * 256,
              nullptr, mo, 2048, 256, 256, 256, 1.0f, 0, 0);
        gemmb(x, mo, cfW1 + (size_t)l * 512 * 512, cfb1 + (size_t)l * 512,
              nullptr, pre, 2048, 512, 512, 512, 1.0f, 0, 0);
        lngelu_k<<<2048, 256, 0, stream>>>(pre, cfg + (size_t)l * 512, cfbt + (size_t)l * 512);
        gemmb(pre, nullptr, cfW2 + (size_t)l * 512 * 256, cfb2 + (size_t)l * 256,
              x, x, 2048, 512, 256, 256, 1.0f, 0, 0);
    }

    // ---- assignment head ----
    const float MD_SCALE = 0.25f; // D^-0.25
    gemmb(x, nullptr, mWp, mbp, nullptr, md, 2048, 256, 256, 256, MD_SCALE, 0, 0);
    z_k<<<2048, 256, 0, stream>>>(x, mWz, mbz, zb);
    gemmb(md, nullptr, md + 1024 * 256, nullptr, nullptr, sim,
          1024, 256, 1024, 1024, 1.0f, 1, 0);   // sim = md0 @ md1^T
    rowlse_k<<<NTOK, 256, 0, stream>>>(sim, rlsb);
    collse_k<<<NTOK, 256, 0, stream>>>(sim, clsb);
    const int W = NTOK + 1;
    assemble_k<<<(W * W + 255) / 256, 256, 0, stream>>>(sim, rlsb, clsb, zb, zb + 1024, (float*)d_out);
}

// Round 9
// 1709.394 us; speedup vs baseline: 11.2288x; 1.2542x over previous
//
#include <hip/hip_runtime.h>
#include <cmath>

// LightGlue forward. GEMMs + attention in bf16 MFMA; Q/K/V stored bf16.
// N=1024, D=256, H=4, DH=64, L=9. Batched over both images (M=2048).
#define NTOK 1024
#define DM   256
#define NH   4
#define DH   64
#define NL   9

typedef __attribute__((ext_vector_type(8))) __bf16 bf16x8;
typedef __attribute__((ext_vector_type(4))) float  f32x4;

__device__ __forceinline__ float logsigf(float x) {
    return fminf(x, 0.0f) - log1pf(expf(-fabsf(x)));
}

__device__ __forceinline__ __bf16 f2bf(float f) {
    unsigned u = __float_as_uint(f);
    u = (u + 0x7FFFu + ((u >> 16) & 1u)) >> 16;          // round-nearest-even
    unsigned short s = (unsigned short)u;
    return __builtin_bit_cast(__bf16, s);
}

// ---------------------------------------------------------------------------
// bf16-MFMA GEMM, fp32 in/out: C = (A @ B + bias)*scale + R
// A: dual-source concat (A1: cols 0-255 from A0, 256+ from A1, ld 256) else lda=K.
// B: [K x Nn] or (transB) [Nn x K]. Tile 32x64, BK=32, 4 waves 2x2.
// ---------------------------------------------------------------------------
__global__ __launch_bounds__(256) void gemm_bf_k(
    const float* __restrict__ A0, const float* __restrict__ A1,
    const float* __restrict__ B, const float* __restrict__ bias,
    const float* __restrict__ R, float* __restrict__ C,
    int M, int K, int Nn, int ldc, float scale, int transB)
{
    __shared__ __bf16 As[32][40];
    __shared__ __bf16 Bs[64][40];
    const int tid = threadIdx.x;
    const int w = tid >> 6, l = tid & 63;
    const int row0 = blockIdx.y * 32, col0 = blockIdx.x * 64;
    const int wr = (w >> 1) * 16;
    const int wc = (w & 1) * 32;
    f32x4 acc0 = {0.f, 0.f, 0.f, 0.f};
    f32x4 acc1 = {0.f, 0.f, 0.f, 0.f};

    const int ar = tid >> 3, ac = (tid & 7) * 4;
    const int bkr = tid >> 4, bnc = (tid & 15) * 4;
    const int tnr = tid >> 2, tkc = (tid & 3) * 8;

    for (int k0 = 0; k0 < K; k0 += 32) {
        {
            float4 v;
            if (A1) {
                int kk = k0 + ac;
                const float* src = (kk < 256)
                    ? &A0[(size_t)(row0 + ar) * 256 + kk]
                    : &A1[(size_t)(row0 + ar) * 256 + (kk - 256)];
                v = *(const float4*)src;
            } else {
                v = *(const float4*)&A0[(size_t)(row0 + ar) * K + k0 + ac];
            }
            __bf16* d = &As[ar][ac];
            d[0] = f2bf(v.x); d[1] = f2bf(v.y); d[2] = f2bf(v.z); d[3] = f2bf(v.w);
        }
        if (!transB) {
            #pragma unroll
            for (int h = 0; h < 2; ++h) {
                int kr = bkr + h * 16;
                float4 v = *(const float4*)&B[(size_t)(k0 + kr) * Nn + col0 + bnc];
                Bs[bnc + 0][kr] = f2bf(v.x);
                Bs[bnc + 1][kr] = f2bf(v.y);
                Bs[bnc + 2][kr] = f2bf(v.z);
                Bs[bnc + 3][kr] = f2bf(v.w);
            }
        } else {
            float4 a = *(const float4*)&B[(size_t)(col0 + tnr) * K + k0 + tkc];
            float4 b = *(const float4*)&B[(size_t)(col0 + tnr) * K + k0 + tkc + 4];
            __bf16* d = &Bs[tnr][tkc];
            d[0] = f2bf(a.x); d[1] = f2bf(a.y); d[2] = f2bf(a.z); d[3] = f2bf(a.w);
            d[4] = f2bf(b.x); d[5] = f2bf(b.y); d[6] = f2bf(b.z); d[7] = f2bf(b.w);
        }
        __syncthreads();
        bf16x8 af  = *(const bf16x8*)&As[wr + (l & 15)][(l >> 4) * 8];
        bf16x8 bf0 = *(const bf16x8*)&Bs[wc + (l & 15)][(l >> 4) * 8];
        bf16x8 bf1 = *(const bf16x8*)&Bs[wc + 16 + (l & 15)][(l >> 4) * 8];
        acc0 = __builtin_amdgcn_mfma_f32_16x16x32_bf16(af, bf0, acc0, 0, 0, 0);
        acc1 = __builtin_amdgcn_mfma_f32_16x16x32_bf16(af, bf1, acc1, 0, 0, 0);
        __syncthreads();
    }

    #pragma unroll
    for (int t2 = 0; t2 < 2; ++t2) {
        f32x4 a = t2 ? acc1 : acc0;
        int cc = col0 + wc + t2 * 16 + (l & 15);
        float bvv = bias ? bias[cc] : 0.0f;
        #pragma unroll
        for (int rg = 0; rg < 4; ++rg) {
            int rr = row0 + wr + (l >> 4) * 4 + rg;
            float v = (a[rg] + bvv) * scale;
            if (R) v += R[(size_t)rr * Nn + cc];
            C[(size_t)rr * ldc + cc] = v;
        }
    }
}

// ---------------------------------------------------------------------------
// Cross qk+v fused GEMM: grid (8, 64). bx<4 -> Wq branch (scaleq), else Wv.
// A = x [2048x256], K=256, Nn=256. Output head-major bf16:
// out[((im*4+h)*1024+n)*64+d].
// ---------------------------------------------------------------------------
__global__ __launch_bounds__(256) void gemm_hm2_k(
    const float* __restrict__ A, const float* __restrict__ Bq,
    const float* __restrict__ bq, const float* __restrict__ Bv,
    const float* __restrict__ bv, __bf16* __restrict__ outq,
    __bf16* __restrict__ outv, float scaleq)
{
    const int bx = blockIdx.x;
    const float* B    = (bx < 4) ? Bq : Bv;
    const float* bias = (bx < 4) ? bq : bv;
    __bf16* C         = (bx < 4) ? outq : outv;
    const float scale = (bx < 4) ? scaleq : 1.0f;

    __shared__ __bf16 As[32][40];
    __shared__ __bf16 Bs[64][40];
    const int tid = threadIdx.x;
    const int w = tid >> 6, l = tid & 63;
    const int row0 = blockIdx.y * 32, col0 = (bx & 3) * 64;
    const int wr = (w >> 1) * 16;
    const int wc = (w & 1) * 32;
    f32x4 acc0 = {0.f, 0.f, 0.f, 0.f};
    f32x4 acc1 = {0.f, 0.f, 0.f, 0.f};

    const int ar = tid >> 3, ac = (tid & 7) * 4;
    const int bkr = tid >> 4, bnc = (tid & 15) * 4;

    for (int k0 = 0; k0 < 256; k0 += 32) {
        {
            float4 v = *(const float4*)&A[(size_t)(row0 + ar) * 256 + k0 + ac];
            __bf16* d = &As[ar][ac];
            d[0] = f2bf(v.x); d[1] = f2bf(v.y); d[2] = f2bf(v.z); d[3] = f2bf(v.w);
        }
        #pragma unroll
        for (int h = 0; h < 2; ++h) {
            int kr = bkr + h * 16;
            float4 v = *(const float4*)&B[(size_t)(k0 + kr) * 256 + col0 + bnc];
            Bs[bnc + 0][kr] = f2bf(v.x);
            Bs[bnc + 1][kr] = f2bf(v.y);
            Bs[bnc + 2][kr] = f2bf(v.z);
            Bs[bnc + 3][kr] = f2bf(v.w);
        }
        __syncthreads();
        bf16x8 af  = *(const bf16x8*)&As[wr + (l & 15)][(l >> 4) * 8];
        bf16x8 bf0 = *(const bf16x8*)&Bs[wc + (l & 15)][(l >> 4) * 8];
        bf16x8 bf1 = *(const bf16x8*)&Bs[wc + 16 + (l & 15)][(l >> 4) * 8];
        acc0 = __builtin_amdgcn_mfma_f32_16x16x32_bf16(af, bf0, acc0, 0, 0, 0);
        acc1 = __builtin_amdgcn_mfma_f32_16x16x32_bf16(af, bf1, acc1, 0, 0, 0);
        __syncthreads();
    }

    #pragma unroll
    for (int t2 = 0; t2 < 2; ++t2) {
        f32x4 a = t2 ? acc1 : acc0;
        int cc = col0 + wc + t2 * 16 + (l & 15);
        float bvv = bias ? bias[cc] : 0.0f;
        int h = cc >> 6, d = cc & 63;
        #pragma unroll
        for (int rg = 0; rg < 4; ++rg) {
            int rr = row0 + wr + (l >> 4) * 4 + rg;
            int im = rr >> 10, n = rr & 1023;
            C[(((size_t)(im * 4 + h)) * 1024 + n) * 64 + d] = f2bf((a[rg] + bvv) * scale);
        }
    }
}

// ---------------------------------------------------------------------------
__global__ __launch_bounds__(256) void posenc_k(
    const float* __restrict__ kpts, const float* __restrict__ Wr,
    float* __restrict__ encc, float* __restrict__ encs)
{
    int idx = blockIdx.x * 256 + threadIdx.x;
    if (idx >= NTOK * 32) return;
    int i = idx >> 5, f = idx & 31;
    float p = kpts[i * 2 + 0] * Wr[f] + kpts[i * 2 + 1] * Wr[32 + f];
    float c = cosf(p), s = sinf(p);
    encc[i * 64 + 2 * f]     = c;  encc[i * 64 + 2 * f + 1] = c;
    encs[i * 64 + 2 * f]     = s;  encs[i * 64 + 2 * f + 1] = s;
}

// Split qkv [2048x768] (col = h*192+d*3+{q,k,v}) -> bf16 vhead-major
// [8][1024][64], RoPE on q,k.
__global__ __launch_bounds__(256) void splitrope_k(
    const float* __restrict__ qkv, const float* __restrict__ encc,
    const float* __restrict__ encs, __bf16* __restrict__ qh,
    __bf16* __restrict__ kh, __bf16* __restrict__ vh)
{
    int n = blockIdx.x, t = threadIdx.x;  // n: 0..2047, t = h*64 + d
    int h = t >> 6, d = t & 63;
    int im = n >> 10, nl = n & 1023;
    const float* base  = qkv + (size_t)n * 768 + h * 192 + d * 3;
    const float* pbase = qkv + (size_t)n * 768 + h * 192 + (d ^ 1) * 3;
    float c = encc[n * 64 + d], s = encs[n * 64 + d];
    float q = base[0], k = base[1], v = base[2];
    float qp = pbase[0], kp = pbase[1];
    float sgn = (d & 1) ? 1.0f : -1.0f;
    size_t o = (((size_t)(im * 4 + h)) * 1024 + nl) * 64 + d;
    qh[o] = f2bf(q * c + sgn * qp * s);
    kh[o] = f2bf(k * c + sgn * kp * s);
    vh[o] = f2bf(v);
}

__global__ __launch_bounds__(256) void copyvec_k(
    float* __restrict__ dst, const float* __restrict__ src, int n)
{
    int i = blockIdx.x * 256 + threadIdx.x;
    if (i < n) dst[i] = src[i];
}

// ---------------------------------------------------------------------------
// Attention v5: flash-style bf16 MFMA, bf16 Q/K/V inputs.
// Block = (16-query tile qt, vhead hv). Grid (64, 8). Wave w owns keys
// [w*256, w*256+256) in 8 tiles of 32; wave-private LDS; merge at end.
//   kb[32][72] bf16 [j][d];  vt[64][40] bf16 [d][j];  pt[16][40] bf16 [q][j]
// ---------------------------------------------------------------------------
__global__ __launch_bounds__(256) void attn_k(
    const __bf16* __restrict__ Qg, const __bf16* __restrict__ Kg,
    const __bf16* __restrict__ Vg, float* __restrict__ out,
    float scale, int cross)
{
    const int qt = blockIdx.x, hv = blockIdx.y;
    const int kvh = cross ? (hv ^ 4) : hv;
    const int tid = threadIdx.x;
    const int w = tid >> 6, lane = tid & 63;
    const int quad = lane >> 4, l16 = lane & 15;
    const int n0 = qt * 16;

    __shared__ __align__(16) char smem[44032];
    char* base = smem + w * 11008;
    __bf16* kb  = (__bf16*)(base);          // 32 x 72
    __bf16* vtb = (__bf16*)(base + 4608);   // 64 x 40
    __bf16* ptb = (__bf16*)(base + 9728);   // 16 x 40

    // Q fragments: direct bf16x8 loads
    bf16x8 qf[2];
    {
        const bf16x8* Qp = (const bf16x8*)(Qg + (((size_t)hv * 1024) + n0 + l16) * 64);
        qf[0] = Qp[quad];
        qf[1] = Qp[4 + quad];
    }

    const __bf16* Kbase = Kg + (size_t)kvh * 1024 * 64;
    const __bf16* Vbase = Vg + (size_t)kvh * 1024 * 64;

    float m[4] = {-1e30f, -1e30f, -1e30f, -1e30f};
    float lsum[4] = {0.f, 0.f, 0.f, 0.f};
    f32x4 o[4] = {{0,0,0,0},{0,0,0,0},{0,0,0,0},{0,0,0,0}};

    const int kj = lane >> 1, kd = (lane & 1) * 32;      // K: 2 lanes/row, 32 dims each
    const int vjp = lane & 15, vd0 = (lane >> 4) * 16;   // V staging map

    for (int t = 0; t < 8; ++t) {
        const int j0 = w * 256 + t * 32;

        // ---- stage K [j][d]: 4 bf16x8 loads = full 32 dims per lane ----
        {
            const bf16x8* kp = (const bf16x8*)(Kbase + (size_t)(j0 + kj) * 64 + kd);
            bf16x8 k0 = kp[0], k1 = kp[1], k2 = kp[2], k3 = kp[3];
            __bf16* kr = kb + kj * 72 + kd;
            *(bf16x8*)(kr)      = k0;
            *(bf16x8*)(kr + 8)  = k1;
            *(bf16x8*)(kr + 16) = k2;
            *(bf16x8*)(kr + 24) = k3;
        }
        // ---- stage V transposed [d][j]: pure bit-packing, no cvt ----
        {
            const uint4* va = (const uint4*)(Vbase + (size_t)(j0 + 2 * vjp) * 64 + vd0);
            const uint4* vb = (const uint4*)(Vbase + (size_t)(j0 + 2 * vjp + 1) * 64 + vd0);
            #pragma unroll
            for (int g = 0; g < 2; ++g) {
                uint4 ua = va[g], ub = vb[g];
                unsigned au[4] = {ua.x, ua.y, ua.z, ua.w};
                unsigned bu[4] = {ub.x, ub.y, ub.z, ub.w};
                #pragma unroll
                for (int e = 0; e < 4; ++e) {
                    int i = g * 8 + e * 2;
                    unsigned pk0 = ((bu[e] & 0xFFFFu) << 16) | (au[e] & 0xFFFFu);
                    unsigned pk1 = (bu[e] & 0xFFFF0000u) | (au[e] >> 16);
                    *(unsigned*)((char*)vtb + ((vd0 + i) * 40 + 2 * vjp) * 2)     = pk0;
                    *(unsigned*)((char*)vtb + ((vd0 + i + 1) * 40 + 2 * vjp) * 2) = pk1;
                }
            }
        }

        // ---- S = Q K^T ----
        f32x4 s0 = {0,0,0,0}, s1 = {0,0,0,0};
        #pragma unroll
        for (int kt = 0; kt < 2; ++kt) {
            bf16x8 k0 = *(const bf16x8*)(kb + (0 * 16 + l16) * 72 + kt * 32 + quad * 8);
            bf16x8 k1 = *(const bf16x8*)(kb + (1 * 16 + l16) * 72 + kt * 32 + quad * 8);
            s0 = __builtin_amdgcn_mfma_f32_16x16x32_bf16(qf[kt], k0, s0, 0, 0, 0);
            s1 = __builtin_amdgcn_mfma_f32_16x16x32_bf16(qf[kt], k1, s1, 0, 0, 0);
        }

        // ---- online softmax ----
        float rm[4], p0[4], p1[4], rs[4];
        #pragma unroll
        for (int r = 0; r < 4; ++r) {
            s0[r] *= scale; s1[r] *= scale;
            rm[r] = fmaxf(s0[r], s1[r]);
        }
        #pragma unroll
        for (int ofs = 1; ofs < 16; ofs <<= 1)
            #pragma unroll
            for (int r = 0; r < 4; ++r)
                rm[r] = fmaxf(rm[r], __shfl_xor(rm[r], ofs));
        #pragma unroll
        for (int r = 0; r < 4; ++r) {
            float mn = fmaxf(m[r], rm[r]);
            float alpha = __expf(m[r] - mn);
            m[r] = mn;
            p0[r] = __expf(s0[r] - mn);
            p1[r] = __expf(s1[r] - mn);
            rs[r] = p0[r] + p1[r];
            lsum[r] *= alpha;
            #pragma unroll
            for (int dt = 0; dt < 4; ++dt) o[dt][r] *= alpha;
        }
        #pragma unroll
        for (int ofs = 1; ofs < 16; ofs <<= 1)
            #pragma unroll
            for (int r = 0; r < 4; ++r)
                rs[r] += __shfl_xor(rs[r], ofs);
        #pragma unroll
        for (int r = 0; r < 4; ++r) lsum[r] += rs[r];

        // ---- P -> LDS (C-layout), read back as A-frag; PV MFMAs ----
        #pragma unroll
        for (int r = 0; r < 4; ++r) {
            ptb[(quad * 4 + r) * 40 + l16]      = f2bf(p0[r]);
            ptb[(quad * 4 + r) * 40 + 16 + l16] = f2bf(p1[r]);
        }
        bf16x8 pf = *(const bf16x8*)(ptb + l16 * 40 + quad * 8);
        #pragma unroll
        for (int dt = 0; dt < 4; ++dt) {
            bf16x8 vf = *(const bf16x8*)(vtb + (dt * 16 + l16) * 40 + quad * 8);
            o[dt] = __builtin_amdgcn_mfma_f32_16x16x32_bf16(pf, vf, o[dt], 0, 0, 0);
        }
    }

    // ---- merge across 4 waves ----
    __syncthreads();
    float* Om = (float*)smem;          // [64][64] : row = w*16 + q
    float* mm = Om + 4096;             // [64]
    float* lm = mm + 64;               // [64]
    #pragma unroll
    for (int dt = 0; dt < 4; ++dt)
        #pragma unroll
        for (int r = 0; r < 4; ++r)
            Om[(w * 16 + quad * 4 + r) * 64 + dt * 16 + l16] = o[dt][r];
    if (l16 == 0) {
        #pragma unroll
        for (int r = 0; r < 4; ++r) {
            mm[w * 16 + quad * 4 + r] = m[r];
            lm[w * 16 + quad * 4 + r] = lsum[r];
        }
    }
    __syncthreads();

    const int q = tid >> 4, dg = tid & 15;
    float M = -1e30f;
    #pragma unroll
    for (int w2 = 0; w2 < 4; ++w2) M = fmaxf(M, mm[w2 * 16 + q]);
    float L = 0.f;
    float4 acc = {0.f, 0.f, 0.f, 0.f};
    #pragma unroll
    for (int w2 = 0; w2 < 4; ++w2) {
        float e = __expf(mm[w2 * 16 + q] - M);
        L += e * lm[w2 * 16 + q];
        float4 ov = *(const float4*)&Om[(w2 * 16 + q) * 64 + dg * 4];
        acc.x += e * ov.x; acc.y += e * ov.y; acc.z += e * ov.z; acc.w += e * ov.w;
    }
    float inv = 1.0f / L;
    float4 r4;
    r4.x = acc.x * inv; r4.y = acc.y * inv; r4.z = acc.z * inv; r4.w = acc.w * inv;
    int row = (hv >> 2) * 1024 + n0 + q;
    *(float4*)&out[(size_t)row * 256 + (hv & 3) * 64 + dg * 4] = r4;
}

// ---------------------------------------------------------------------------
// LayerNorm (512) + exact GELU, wave-per-row (4 rows/block), no barriers.
// ---------------------------------------------------------------------------
__global__ __launch_bounds__(256) void lngelu_k(
    float* __restrict__ x, const float* __restrict__ g,
    const float* __restrict__ beta)
{
    int row = blockIdx.x * 4 + (threadIdx.x >> 6);
    int lane = threadIdx.x & 63;
    float* xr = x + (size_t)row * 512;
    float4 v0 = *(const float4*)&xr[lane * 4];
    float4 v1 = *(const float4*)&xr[256 + lane * 4];
    float s = v0.x + v0.y + v0.z + v0.w + v1.x + v1.y + v1.z + v1.w;
    #pragma unroll
    for (int ofs = 1; ofs < 64; ofs <<= 1) s += __shfl_xor(s, ofs);
    float mu = s * (1.0f / 512.0f);
    float d0x = v0.x - mu, d0y = v0.y - mu, d0z = v0.z - mu, d0w = v0.w - mu;
    float d1x = v1.x - mu, d1y = v1.y - mu, d1z = v1.z - mu, d1w = v1.w - mu;
    float vv = d0x*d0x + d0y*d0y + d0z*d0z + d0w*d0w
             + d1x*d1x + d1y*d1y + d1z*d1z + d1w*d1w;
    #pragma unroll
    for (int ofs = 1; ofs < 64; ofs <<= 1) vv += __shfl_xor(vv, ofs);
    float rstd = rsqrtf(vv * (1.0f / 512.0f) + 1e-5f);
    const float IS2 = 0.70710678118654752f;
    float4 o0, o1;
    {
        float4 gg = *(const float4*)&g[lane * 4];
        float4 bb = *(const float4*)&beta[lane * 4];
        float y;
        y = d0x * rstd * gg.x + bb.x; o0.x = 0.5f * y * (1.0f + erff(y * IS2));
        y = d0y * rstd * gg.y + bb.y; o0.y = 0.5f * y * (1.0f + erff(y * IS2));
        y = d0z * rstd * gg.z + bb.z; o0.z = 0.5f * y * (1.0f + erff(y * IS2));
        y = d0w * rstd * gg.w + bb.w; o0.w = 0.5f * y * (1.0f + erff(y * IS2));
    }
    {
        float4 gg = *(const float4*)&g[256 + lane * 4];
        float4 bb = *(const float4*)&beta[256 + lane * 4];
        float y;
        y = d1x * rstd * gg.x + bb.x; o1.x = 0.5f * y * (1.0f + erff(y * IS2));
        y = d1y * rstd * gg.y + bb.y; o1.y = 0.5f * y * (1.0f + erff(y * IS2));
        y = d1z * rstd * gg.z + bb.z; o1.z = 0.5f * y * (1.0f + erff(y * IS2));
        y = d1w * rstd * gg.w + bb.w; o1.w = 0.5f * y * (1.0f + erff(y * IS2));
    }
    *(float4*)&xr[lane * 4]       = o0;
    *(float4*)&xr[256 + lane * 4] = o1;
}

__global__ __launch_bounds__(256) void z_k(
    const float* __restrict__ x, const float* __restrict__ Wz,
    const float* __restrict__ bz, float* __restrict__ z)
{
    int row = blockIdx.x, t = threadIdx.x;
    __shared__ float red[256];
    red[t] = x[(size_t)row * 256 + t] * Wz[t];
    __syncthreads();
    for (int s = 128; s > 0; s >>= 1) {
        if (t < s) red[t] += red[t + s];
        __syncthreads();
    }
    if (t == 0) z[row] = red[0] + bz[0];
}

__global__ __launch_bounds__(256) void rowlse_k(
    const float* __restrict__ sim, float* __restrict__ out)
{
    int row = blockIdx.x, t = threadIdx.x;
    __shared__ float red[256];
    float mx = -1e30f;
    for (int j = t; j < NTOK; j += 256) mx = fmaxf(mx, sim[(size_t)row * NTOK + j]);
    red[t] = mx; __syncthreads();
    for (int s = 128; s > 0; s >>= 1) {
        if (t < s) red[t] = fmaxf(red[t], red[t + s]);
        __syncthreads();
    }
    mx = red[0]; __syncthreads();
    float sum = 0.0f;
    for (int j = t; j < NTOK; j += 256) sum += expf(sim[(size_t)row * NTOK + j] - mx);
    red[t] = sum; __syncthreads();
    for (int s = 128; s > 0; s >>= 1) {
        if (t < s) red[t] += red[t + s];
        __syncthreads();
    }
    if (t == 0) out[row] = mx + logf(red[0]);
}

__global__ __launch_bounds__(256) void collse_k(
    const float* __restrict__ sim, float* __restrict__ out)
{
    int col = blockIdx.x, t = threadIdx.x;
    __shared__ float red[256];
    float mx = -1e30f;
    for (int i = t; i < NTOK; i += 256) mx = fmaxf(mx, sim[(size_t)i * NTOK + col]);
    red[t] = mx; __syncthreads();
    for (int s = 128; s > 0; s >>= 1) {
        if (t < s) red[t] = fmaxf(red[t], red[t + s]);
        __syncthreads();
    }
    mx = red[0]; __syncthreads();
    float sum = 0.0f;
    for (int i = t; i < NTOK; i += 256) sum += expf(sim[(size_t)i * NTOK + col] - mx);
    red[t] = sum; __syncthreads();
    for (int s = 128; s > 0; s >>= 1) {
        if (t < s) red[t] += red[t + s];
        __syncthreads();
    }
    if (t == 0) out[col] = mx + logf(red[0]);
}

__global__ __launch_bounds__(256) void assemble_k(
    const float* __restrict__ sim, const float* __restrict__ rls,
    const float* __restrict__ cls, const float* __restrict__ z0,
    const float* __restrict__ z1, float* __restrict__ out)
{
    int idx = blockIdx.x * 256 + threadIdx.x;
    const int W = NTOK + 1;
    if (idx >= W * W) return;
    int i = idx / W, j = idx % W;
    float v;
    if (i < NTOK && j < NTOK) {
        v = 2.0f * sim[(size_t)i * NTOK + j] - rls[i] - cls[j] + logsigf(z0[i]) + logsigf(z1[j]);
    } else if (i < NTOK) {
        v = logsigf(-z0[i]);
    } else if (j < NTOK) {
        v = logsigf(-z1[j]);
    } else {
        v = 0.0f;
    }
    out[idx] = v;
}

// ---------------------------------------------------------------------------
extern "C" void kernel_launch(void* const* d_in, const int* in_sizes, int n_in,
                              void* d_out, int out_size, void* d_ws, size_t ws_size,
                              hipStream_t stream)
{
    const float* desc0 = (const float*)d_in[0];
    const float* desc1 = (const float*)d_in[1];
    const float* kpts0 = (const float*)d_in[2];
    const float* kpts1 = (const float*)d_in[3];
    const float* Wr    = (const float*)d_in[4];
    const float* sWqkv = (const float*)d_in[5];
    const float* sbqkv = (const float*)d_in[6];
    const float* sWo   = (const float*)d_in[7];
    const float* sbo   = (const float*)d_in[8];
    const float* sfW1  = (const float*)d_in[9];
    const float* sfb1  = (const float*)d_in[10];
    const float* sfg   = (const float*)d_in[11];
    const float* sfbt  = (const float*)d_in[12];
    const float* sfW2  = (const float*)d_in[13];
    const float* sfb2  = (const float*)d_in[14];
    const float* cWqk  = (const float*)d_in[15];
    const float* cbqk  = (const float*)d_in[16];
    const float* cWv   = (const float*)d_in[17];
    const float* cbv   = (const float*)d_in[18];
    const float* cWo   = (const float*)d_in[19];
    const float* cbo   = (const float*)d_in[20];
    const float* cfW1  = (const float*)d_in[21];
    const float* cfb1  = (const float*)d_in[22];
    const float* cfg   = (const float*)d_in[23];
    const float* cfbt  = (const float*)d_in[24];
    const float* cfW2  = (const float*)d_in[25];
    const float* cfb2  = (const float*)d_in[26];
    const float* mWp   = (const float*)d_in[27];
    const float* mbp   = (const float*)d_in[28];
    const float* mWz   = (const float*)d_in[29];
    const float* mbz   = (const float*)d_in[30];

    float* ws = (float*)d_ws;
    // Layout (float units). NOTE: qh/kh/vh are 8*1024*64 bf16 = 262144 float
    // units EACH (r7/r8 bug: was spaced 131072 -> qh overran kh, vh overran msg).
    float* x    = ws;                      // 524288  [2048][256] fp32
    float* encc = ws + 524288;             // 131072  [2048][64]
    float* encs = ws + 655360;             // 131072
    float* qkv  = ws + 786432;             // 1572864 [2048][768] fp32 (self only)
    float* mo   = qkv;                     // 524288  (FFN phase)
    float* pre  = qkv + 524288;            // 1048576 [2048][512]
    __bf16* qh  = (__bf16*)(ws + 2359296); // 262144 fl = 524288 bf16
    __bf16* kh  = (__bf16*)(ws + 2621440); // 262144 fl
    __bf16* vh  = (__bf16*)(ws + 2883584); // 262144 fl
    float* msg  = ws + 3145728;            // 524288  [2048][256] fp32
    float* zb   = ws + 3670016;            // 2048
    float* rlsb = ws + 3672064;            // 1024
    float* clsb = ws + 3673088;            // 1024  (total 3674112 fl = 14.7 MB)
    float* sim  = qkv;                     // 1048576 (assignment; qkv/mo/pre dead)
    float* md   = msg;

    auto gemmb = [&](const float* A0, const float* A1, const float* B,
                     const float* bias, const float* R, float* C,
                     int M, int K, int Nn, int ldc, float scale, int tB) {
        gemm_bf_k<<<dim3(Nn / 64, M / 32), 256, 0, stream>>>(A0, A1, B, bias, R, C, M, K, Nn, ldc, scale, tB);
    };

    const float SELF_SCALE  = 0.125f;               // DH^-0.5
    const float CROSS_SCALE = 0.35355339059327373f; // DH^-0.25

    copyvec_k<<<(NTOK * DM + 255) / 256, 256, 0, stream>>>(x, desc0, NTOK * DM);
    copyvec_k<<<(NTOK * DM + 255) / 256, 256, 0, stream>>>(x + NTOK * DM, desc1, NTOK * DM);
    posenc_k<<<(NTOK * 32 + 255) / 256, 256, 0, stream>>>(kpts0, Wr, encc, encs);
    posenc_k<<<(NTOK * 32 + 255) / 256, 256, 0, stream>>>(kpts1, Wr, encc + 65536, encs + 65536);

    for (int l = 0; l < NL; ++l) {
        // ---- self block (both images batched) ----
        gemmb(x, nullptr, sWqkv + (size_t)l * 256 * 768, sbqkv + (size_t)l * 768,
              nullptr, qkv, 2048, 256, 768, 768, 1.0f, 0);
        splitrope_k<<<2048, 256, 0, stream>>>(qkv, encc, encs, qh, kh, vh);
        attn_k<<<dim3(64, 8), 256, 0, stream>>>(qh, kh, vh, msg, SELF_SCALE, 0);
        gemmb(msg, nullptr, sWo + (size_t)l * 256 * 256, sbo + (size_t)l * 256,
              nullptr, mo, 2048, 256, 256, 256, 1.0f, 0);
        gemmb(x, mo, sfW1 + (size_t)l * 512 * 512, sfb1 + (size_t)l * 512,
              nullptr, pre, 2048, 512, 512, 512, 1.0f, 0);
        lngelu_k<<<512, 256, 0, stream>>>(pre, sfg + (size_t)l * 512, sfbt + (size_t)l * 512);
        gemmb(pre, nullptr, sfW2 + (size_t)l * 512 * 256, sfb2 + (size_t)l * 256,
              x, x, 2048, 512, 256, 256, 1.0f, 0);

        // ---- cross block ----
        gemm_hm2_k<<<dim3(8, 64), 256, 0, stream>>>(
            x, cWqk + (size_t)l * 256 * 256, cbqk + (size_t)l * 256,
            cWv + (size_t)l * 256 * 256, cbv + (size_t)l * 256,
            qh, vh, CROSS_SCALE);
        attn_k<<<dim3(64, 8), 256, 0, stream>>>(qh, qh, vh, msg, 1.0f, 1);
        gemmb(msg, nullptr, cWo + (size_t)l * 256 * 256, cbo + (size_t)l * 256,
              nullptr, mo, 2048, 256, 256, 256, 1.0f, 0);
        gemmb(x, mo, cfW1 + (size_t)l * 512 * 512, cfb1 + (size_t)l * 512,
              nullptr, pre, 2048, 512, 512, 512, 1.0f, 0);
        lngelu_k<<<512, 256, 0, stream>>>(pre, cfg + (size_t)l * 512, cfbt + (size_t)l * 512);
        gemmb(pre, nullptr, cfW2 + (size_t)l * 512 * 256, cfb2 + (size_t)l * 256,
              x, x, 2048, 512, 256, 256, 1.0f, 0);
    }

    // ---- assignment head ----
    const float MD_SCALE = 0.25f; // D^-0.25
    gemmb(x, nullptr, mWp, mbp, nullptr, md, 2048, 256, 256, 256, MD_SCALE, 0);
    z_k<<<2048, 256, 0, stream>>>(x, mWz, mbz, zb);
    gemmb(md, nullptr, md + 1024 * 256, nullptr, nullptr, sim,
          1024, 256, 1024, 1024, 1.0f, 1);   // sim = md0 @ md1^T
    rowlse_k<<<NTOK, 256, 0, stream>>>(sim, rlsb);
    collse_k<<<NTOK, 256, 0, stream>>>(sim, clsb);
    const int W = NTOK + 1;
    assemble_k<<<(W * W + 255) / 256, 256, 0, stream>>>(sim, rlsb, clsb, zb, zb + 1024, (float*)d_out);
}

// Round 10
// 1311.541 us; speedup vs baseline: 14.6351x; 1.3033x over previous
//
#include <hip/hip_runtime.h>
#include <cmath>

// LightGlue forward. GEMMs + attention in bf16 MFMA; Q/K/V stored bf16;
// weights pre-converted+pre-transposed to bf16 [N][K] once per launch.
// N=1024, D=256, H=4, DH=64, L=9. Batched over both images (M=2048).
#define NTOK 1024
#define DM   256
#define NH   4
#define DH   64
#define NL   9

typedef __attribute__((ext_vector_type(8))) __bf16 bf16x8;
typedef __attribute__((ext_vector_type(4))) __bf16 bf16x4;
typedef __attribute__((ext_vector_type(4))) float  f32x4;

__device__ __forceinline__ float logsigf(float x) {
    return fminf(x, 0.0f) - log1pf(expf(-fabsf(x)));
}

__device__ __forceinline__ __bf16 f2bf(float f) {
    unsigned u = __float_as_uint(f);
    u = (u + 0x7FFFu + ((u >> 16) & 1u)) >> 16;          // round-nearest-even
    unsigned short s = (unsigned short)u;
    return __builtin_bit_cast(__bf16, s);
}

// ---------------------------------------------------------------------------
// Weight pre-transpose: fp32 [K][N] (batched) -> bf16 [N][K].
// Grid (N/32, K/32, batch), 256 threads, LDS 32x36 tile.
// ---------------------------------------------------------------------------
__global__ __launch_bounds__(256) void wtrans_k(
    const float* __restrict__ in, __bf16* __restrict__ out, int K, int N)
{
    __shared__ __bf16 t[32][36];
    const int b = blockIdx.z;
    const float* src = in + (size_t)b * K * N;
    __bf16* dst = out + (size_t)b * K * N;
    const int n0 = blockIdx.x * 32, k0 = blockIdx.y * 32;
    const int tx = threadIdx.x & 31, ty = threadIdx.x >> 5;
    #pragma unroll
    for (int i = 0; i < 4; ++i) {
        int k = ty + i * 8;
        t[tx][k] = f2bf(src[(size_t)(k0 + k) * N + n0 + tx]);
    }
    __syncthreads();
    const int nr = threadIdx.x >> 3, kc = (threadIdx.x & 7) * 4;
    bf16x4 v = *(const bf16x4*)&t[nr][kc];
    *(bf16x4*)&dst[(size_t)(n0 + nr) * K + k0 + kc] = v;
}

// ---------------------------------------------------------------------------
// bf16-MFMA GEMM: C = (A @ B + bias)*scale + R. fp32 A/C, bf16 B [Nn][K].
// A: dual-source concat (A1: cols 0-255 from A0, 256+ from A1, ld 256) else lda=K.
// Tile 32x64, BK=32, 4 waves 2x2.
// ---------------------------------------------------------------------------
__global__ __launch_bounds__(256) void gemm_bf_k(
    const float* __restrict__ A0, const float* __restrict__ A1,
    const __bf16* __restrict__ Bt, const float* __restrict__ bias,
    const float* __restrict__ R, float* __restrict__ C,
    int M, int K, int Nn, int ldc, float scale)
{
    __shared__ __bf16 As[32][40];
    __shared__ __bf16 Bs[64][40];
    const int tid = threadIdx.x;
    const int w = tid >> 6, l = tid & 63;
    const int row0 = blockIdx.y * 32, col0 = blockIdx.x * 64;
    const int wr = (w >> 1) * 16;
    const int wc = (w & 1) * 32;
    f32x4 acc0 = {0.f, 0.f, 0.f, 0.f};
    f32x4 acc1 = {0.f, 0.f, 0.f, 0.f};

    const int ar = tid >> 3, ac = (tid & 7) * 4;
    const int bnr = tid >> 2, bkc = (tid & 3) * 8;

    for (int k0 = 0; k0 < K; k0 += 32) {
        {
            float4 v;
            if (A1) {
                int kk = k0 + ac;
                const float* src = (kk < 256)
                    ? &A0[(size_t)(row0 + ar) * 256 + kk]
                    : &A1[(size_t)(row0 + ar) * 256 + (kk - 256)];
                v = *(const float4*)src;
            } else {
                v = *(const float4*)&A0[(size_t)(row0 + ar) * K + k0 + ac];
            }
            __bf16* d = &As[ar][ac];
            d[0] = f2bf(v.x); d[1] = f2bf(v.y); d[2] = f2bf(v.z); d[3] = f2bf(v.w);
        }
        {
            bf16x8 bv = *(const bf16x8*)&Bt[(size_t)(col0 + bnr) * K + k0 + bkc];
            *(bf16x8*)&Bs[bnr][bkc] = bv;
        }
        __syncthreads();
        bf16x8 af  = *(const bf16x8*)&As[wr + (l & 15)][(l >> 4) * 8];
        bf16x8 bf0 = *(const bf16x8*)&Bs[wc + (l & 15)][(l >> 4) * 8];
        bf16x8 bf1 = *(const bf16x8*)&Bs[wc + 16 + (l & 15)][(l >> 4) * 8];
        acc0 = __builtin_amdgcn_mfma_f32_16x16x32_bf16(af, bf0, acc0, 0, 0, 0);
        acc1 = __builtin_amdgcn_mfma_f32_16x16x32_bf16(af, bf1, acc1, 0, 0, 0);
        __syncthreads();
    }

    #pragma unroll
    for (int t2 = 0; t2 < 2; ++t2) {
        f32x4 a = t2 ? acc1 : acc0;
        int cc = col0 + wc + t2 * 16 + (l & 15);
        float bvv = bias ? bias[cc] : 0.0f;
        #pragma unroll
        for (int rg = 0; rg < 4; ++rg) {
            int rr = row0 + wr + (l >> 4) * 4 + rg;
            float v = (a[rg] + bvv) * scale;
            if (R) v += R[(size_t)rr * Nn + cc];
            C[(size_t)rr * ldc + cc] = v;
        }
    }
}

// ---------------------------------------------------------------------------
// Cross qk+v fused GEMM: grid (8, 64). bx<4 -> Wq branch (scaleq), else Wv.
// A = x [2048x256] fp32, B = bf16 [256][256] pre-transposed. Output head-major
// bf16: out[((im*4+h)*1024+n)*64+d].
// ---------------------------------------------------------------------------
__global__ __launch_bounds__(256) void gemm_hm2_k(
    const float* __restrict__ A, const __bf16* __restrict__ Btq,
    const float* __restrict__ bq, const __bf16* __restrict__ Btv,
    const float* __restrict__ bv, __bf16* __restrict__ outq,
    __bf16* __restrict__ outv, float scaleq)
{
    const int bx = blockIdx.x;
    const __bf16* Bt  = (bx < 4) ? Btq : Btv;
    const float* bias = (bx < 4) ? bq : bv;
    __bf16* C         = (bx < 4) ? outq : outv;
    const float scale = (bx < 4) ? scaleq : 1.0f;

    __shared__ __bf16 As[32][40];
    __shared__ __bf16 Bs[64][40];
    const int tid = threadIdx.x;
    const int w = tid >> 6, l = tid & 63;
    const int row0 = blockIdx.y * 32, col0 = (bx & 3) * 64;
    const int wr = (w >> 1) * 16;
    const int wc = (w & 1) * 32;
    f32x4 acc0 = {0.f, 0.f, 0.f, 0.f};
    f32x4 acc1 = {0.f, 0.f, 0.f, 0.f};

    const int ar = tid >> 3, ac = (tid & 7) * 4;
    const int bnr = tid >> 2, bkc = (tid & 3) * 8;

    for (int k0 = 0; k0 < 256; k0 += 32) {
        {
            float4 v = *(const float4*)&A[(size_t)(row0 + ar) * 256 + k0 + ac];
            __bf16* d = &As[ar][ac];
            d[0] = f2bf(v.x); d[1] = f2bf(v.y); d[2] = f2bf(v.z); d[3] = f2bf(v.w);
        }
        {
            bf16x8 bv8 = *(const bf16x8*)&Bt[(size_t)(col0 + bnr) * 256 + k0 + bkc];
            *(bf16x8*)&Bs[bnr][bkc] = bv8;
        }
        __syncthreads();
        bf16x8 af  = *(const bf16x8*)&As[wr + (l & 15)][(l >> 4) * 8];
        bf16x8 bf0 = *(const bf16x8*)&Bs[wc + (l & 15)][(l >> 4) * 8];
        bf16x8 bf1 = *(const bf16x8*)&Bs[wc + 16 + (l & 15)][(l >> 4) * 8];
        acc0 = __builtin_amdgcn_mfma_f32_16x16x32_bf16(af, bf0, acc0, 0, 0, 0);
        acc1 = __builtin_amdgcn_mfma_f32_16x16x32_bf16(af, bf1, acc1, 0, 0, 0);
        __syncthreads();
    }

    #pragma unroll
    for (int t2 = 0; t2 < 2; ++t2) {
        f32x4 a = t2 ? acc1 : acc0;
        int cc = col0 + wc + t2 * 16 + (l & 15);
        float bvv = bias ? bias[cc] : 0.0f;
        int h = cc >> 6, d = cc & 63;
        #pragma unroll
        for (int rg = 0; rg < 4; ++rg) {
            int rr = row0 + wr + (l >> 4) * 4 + rg;
            int im = rr >> 10, n = rr & 1023;
            C[(((size_t)(im * 4 + h)) * 1024 + n) * 64 + d] = f2bf((a[rg] + bvv) * scale);
        }
    }
}

// ---------------------------------------------------------------------------
// sim = A @ B^T, fp32 A,B (both activations). M=1024 (grid), no bias/scale.
// ---------------------------------------------------------------------------
__global__ __launch_bounds__(256) void gemm_f32t_k(
    const float* __restrict__ A, const float* __restrict__ B,
    float* __restrict__ C, int K, int Nn)
{
    __shared__ __bf16 As[32][40];
    __shared__ __bf16 Bs[64][40];
    const int tid = threadIdx.x;
    const int w = tid >> 6, l = tid & 63;
    const int row0 = blockIdx.y * 32, col0 = blockIdx.x * 64;
    const int wr = (w >> 1) * 16;
    const int wc = (w & 1) * 32;
    f32x4 acc0 = {0.f, 0.f, 0.f, 0.f};
    f32x4 acc1 = {0.f, 0.f, 0.f, 0.f};

    const int ar = tid >> 3, ac = (tid & 7) * 4;
    const int tnr = tid >> 2, tkc = (tid & 3) * 8;

    for (int k0 = 0; k0 < K; k0 += 32) {
        {
            float4 v = *(const float4*)&A[(size_t)(row0 + ar) * K + k0 + ac];
            __bf16* d = &As[ar][ac];
            d[0] = f2bf(v.x); d[1] = f2bf(v.y); d[2] = f2bf(v.z); d[3] = f2bf(v.w);
        }
        {
            float4 a = *(const float4*)&B[(size_t)(col0 + tnr) * K + k0 + tkc];
            float4 b = *(const float4*)&B[(size_t)(col0 + tnr) * K + k0 + tkc + 4];
            __bf16* d = &Bs[tnr][tkc];
            d[0] = f2bf(a.x); d[1] = f2bf(a.y); d[2] = f2bf(a.z); d[3] = f2bf(a.w);
            d[4] = f2bf(b.x); d[5] = f2bf(b.y); d[6] = f2bf(b.z); d[7] = f2bf(b.w);
        }
        __syncthreads();
        bf16x8 af  = *(const bf16x8*)&As[wr + (l & 15)][(l >> 4) * 8];
        bf16x8 bf0 = *(const bf16x8*)&Bs[wc + (l & 15)][(l >> 4) * 8];
        bf16x8 bf1 = *(const bf16x8*)&Bs[wc + 16 + (l & 15)][(l >> 4) * 8];
        acc0 = __builtin_amdgcn_mfma_f32_16x16x32_bf16(af, bf0, acc0, 0, 0, 0);
        acc1 = __builtin_amdgcn_mfma_f32_16x16x32_bf16(af, bf1, acc1, 0, 0, 0);
        __syncthreads();
    }

    #pragma unroll
    for (int t2 = 0; t2 < 2; ++t2) {
        f32x4 a = t2 ? acc1 : acc0;
        int cc = col0 + wc + t2 * 16 + (l & 15);
        #pragma unroll
        for (int rg = 0; rg < 4; ++rg) {
            int rr = row0 + wr + (l >> 4) * 4 + rg;
            C[(size_t)rr * Nn + cc] = a[rg];
        }
    }
}

// ---------------------------------------------------------------------------
__global__ __launch_bounds__(256) void posenc_k(
    const float* __restrict__ kpts, const float* __restrict__ Wr,
    float* __restrict__ encc, float* __restrict__ encs)
{
    int idx = blockIdx.x * 256 + threadIdx.x;
    if (idx >= NTOK * 32) return;
    int i = idx >> 5, f = idx & 31;
    float p = kpts[i * 2 + 0] * Wr[f] + kpts[i * 2 + 1] * Wr[32 + f];
    float c = cosf(p), s = sinf(p);
    encc[i * 64 + 2 * f]     = c;  encc[i * 64 + 2 * f + 1] = c;
    encs[i * 64 + 2 * f]     = s;  encs[i * 64 + 2 * f + 1] = s;
}

// Split qkv [2048x768] (col = h*192+d*3+{q,k,v}) -> bf16 vhead-major
// [8][1024][64], RoPE on q,k.
__global__ __launch_bounds__(256) void splitrope_k(
    const float* __restrict__ qkv, const float* __restrict__ encc,
    const float* __restrict__ encs, __bf16* __restrict__ qh,
    __bf16* __restrict__ kh, __bf16* __restrict__ vh)
{
    int n = blockIdx.x, t = threadIdx.x;  // n: 0..2047, t = h*64 + d
    int h = t >> 6, d = t & 63;
    int im = n >> 10, nl = n & 1023;
    const float* base  = qkv + (size_t)n * 768 + h * 192 + d * 3;
    const float* pbase = qkv + (size_t)n * 768 + h * 192 + (d ^ 1) * 3;
    float c = encc[n * 64 + d], s = encs[n * 64 + d];
    float q = base[0], k = base[1], v = base[2];
    float qp = pbase[0], kp = pbase[1];
    float sgn = (d & 1) ? 1.0f : -1.0f;
    size_t o = (((size_t)(im * 4 + h)) * 1024 + nl) * 64 + d;
    qh[o] = f2bf(q * c + sgn * qp * s);
    kh[o] = f2bf(k * c + sgn * kp * s);
    vh[o] = f2bf(v);
}

__global__ __launch_bounds__(256) void copyvec_k(
    float* __restrict__ dst, const float* __restrict__ src, int n)
{
    int i = blockIdx.x * 256 + threadIdx.x;
    if (i < n) dst[i] = src[i];
}

// ---------------------------------------------------------------------------
// Attention v5: flash-style bf16 MFMA, bf16 Q/K/V inputs.
// Block = (16-query tile qt, vhead hv). Grid (64, 8). Wave w owns keys
// [w*256, w*256+256) in 8 tiles of 32; wave-private LDS; merge at end.
//   kb[32][72] bf16 [j][d];  vt[64][40] bf16 [d][j];  pt[16][40] bf16 [q][j]
// ---------------------------------------------------------------------------
__global__ __launch_bounds__(256) void attn_k(
    const __bf16* __restrict__ Qg, const __bf16* __restrict__ Kg,
    const __bf16* __restrict__ Vg, float* __restrict__ out,
    float scale, int cross)
{
    const int qt = blockIdx.x, hv = blockIdx.y;
    const int kvh = cross ? (hv ^ 4) : hv;
    const int tid = threadIdx.x;
    const int w = tid >> 6, lane = tid & 63;
    const int quad = lane >> 4, l16 = lane & 15;
    const int n0 = qt * 16;

    __shared__ __align__(16) char smem[44032];
    char* base = smem + w * 11008;
    __bf16* kb  = (__bf16*)(base);          // 32 x 72
    __bf16* vtb = (__bf16*)(base + 4608);   // 64 x 40
    __bf16* ptb = (__bf16*)(base + 9728);   // 16 x 40

    bf16x8 qf[2];
    {
        const bf16x8* Qp = (const bf16x8*)(Qg + (((size_t)hv * 1024) + n0 + l16) * 64);
        qf[0] = Qp[quad];
        qf[1] = Qp[4 + quad];
    }

    const __bf16* Kbase = Kg + (size_t)kvh * 1024 * 64;
    const __bf16* Vbase = Vg + (size_t)kvh * 1024 * 64;

    float m[4] = {-1e30f, -1e30f, -1e30f, -1e30f};
    float lsum[4] = {0.f, 0.f, 0.f, 0.f};
    f32x4 o[4] = {{0,0,0,0},{0,0,0,0},{0,0,0,0},{0,0,0,0}};

    const int kj = lane >> 1, kd = (lane & 1) * 32;      // K: 2 lanes/row, 32 dims each
    const int vjp = lane & 15, vd0 = (lane >> 4) * 16;   // V staging map

    for (int t = 0; t < 8; ++t) {
        const int j0 = w * 256 + t * 32;

        {
            const bf16x8* kp = (const bf16x8*)(Kbase + (size_t)(j0 + kj) * 64 + kd);
            bf16x8 k0 = kp[0], k1 = kp[1], k2 = kp[2], k3 = kp[3];
            __bf16* kr = kb + kj * 72 + kd;
            *(bf16x8*)(kr)      = k0;
            *(bf16x8*)(kr + 8)  = k1;
            *(bf16x8*)(kr + 16) = k2;
            *(bf16x8*)(kr + 24) = k3;
        }
        {
            const uint4* va = (const uint4*)(Vbase + (size_t)(j0 + 2 * vjp) * 64 + vd0);
            const uint4* vb = (const uint4*)(Vbase + (size_t)(j0 + 2 * vjp + 1) * 64 + vd0);
            #pragma unroll
            for (int g = 0; g < 2; ++g) {
                uint4 ua = va[g], ub = vb[g];
                unsigned au[4] = {ua.x, ua.y, ua.z, ua.w};
                unsigned bu[4] = {ub.x, ub.y, ub.z, ub.w};
                #pragma unroll
                for (int e = 0; e < 4; ++e) {
                    int i = g * 8 + e * 2;
                    unsigned pk0 = ((bu[e] & 0xFFFFu) << 16) | (au[e] & 0xFFFFu);
                    unsigned pk1 = (bu[e] & 0xFFFF0000u) | (au[e] >> 16);
                    *(unsigned*)((char*)vtb + ((vd0 + i) * 40 + 2 * vjp) * 2)     = pk0;
                    *(unsigned*)((char*)vtb + ((vd0 + i + 1) * 40 + 2 * vjp) * 2) = pk1;
                }
            }
        }

        f32x4 s0 = {0,0,0,0}, s1 = {0,0,0,0};
        #pragma unroll
        for (int kt = 0; kt < 2; ++kt) {
            bf16x8 k0 = *(const bf16x8*)(kb + (0 * 16 + l16) * 72 + kt * 32 + quad * 8);
            bf16x8 k1 = *(const bf16x8*)(kb + (1 * 16 + l16) * 72 + kt * 32 + quad * 8);
            s0 = __builtin_amdgcn_mfma_f32_16x16x32_bf16(qf[kt], k0, s0, 0, 0, 0);
            s1 = __builtin_amdgcn_mfma_f32_16x16x32_bf16(qf[kt], k1, s1, 0, 0, 0);
        }

        float rm[4], p0[4], p1[4], rs[4];
        #pragma unroll
        for (int r = 0; r < 4; ++r) {
            s0[r] *= scale; s1[r] *= scale;
            rm[r] = fmaxf(s0[r], s1[r]);
        }
        #pragma unroll
        for (int ofs = 1; ofs < 16; ofs <<= 1)
            #pragma unroll
            for (int r = 0; r < 4; ++r)
                rm[r] = fmaxf(rm[r], __shfl_xor(rm[r], ofs));
        #pragma unroll
        for (int r = 0; r < 4; ++r) {
            float mn = fmaxf(m[r], rm[r]);
            float alpha = __expf(m[r] - mn);
            m[r] = mn;
            p0[r] = __expf(s0[r] - mn);
            p1[r] = __expf(s1[r] - mn);
            rs[r] = p0[r] + p1[r];
            lsum[r] *= alpha;
            #pragma unroll
            for (int dt = 0; dt < 4; ++dt) o[dt][r] *= alpha;
        }
        #pragma unroll
        for (int ofs = 1; ofs < 16; ofs <<= 1)
            #pragma unroll
            for (int r = 0; r < 4; ++r)
                rs[r] += __shfl_xor(rs[r], ofs);
        #pragma unroll
        for (int r = 0; r < 4; ++r) lsum[r] += rs[r];

        #pragma unroll
        for (int r = 0; r < 4; ++r) {
            ptb[(quad * 4 + r) * 40 + l16]      = f2bf(p0[r]);
            ptb[(quad * 4 + r) * 40 + 16 + l16] = f2bf(p1[r]);
        }
        bf16x8 pf = *(const bf16x8*)(ptb + l16 * 40 + quad * 8);
        #pragma unroll
        for (int dt = 0; dt < 4; ++dt) {
            bf16x8 vf = *(const bf16x8*)(vtb + (dt * 16 + l16) * 40 + quad * 8);
            o[dt] = __builtin_amdgcn_mfma_f32_16x16x32_bf16(pf, vf, o[dt], 0, 0, 0);
        }
    }

    __syncthreads();
    float* Om = (float*)smem;          // [64][64] : row = w*16 + q
    float* mm = Om + 4096;             // [64]
    float* lm = mm + 64;               // [64]
    #pragma unroll
    for (int dt = 0; dt < 4; ++dt)
        #pragma unroll
        for (int r = 0; r < 4; ++r)
            Om[(w * 16 + quad * 4 + r) * 64 + dt * 16 + l16] = o[dt][r];
    if (l16 == 0) {
        #pragma unroll
        for (int r = 0; r < 4; ++r) {
            mm[w * 16 + quad * 4 + r] = m[r];
            lm[w * 16 + quad * 4 + r] = lsum[r];
        }
    }
    __syncthreads();

    const int q = tid >> 4, dg = tid & 15;
    float M = -1e30f;
    #pragma unroll
    for (int w2 = 0; w2 < 4; ++w2) M = fmaxf(M, mm[w2 * 16 + q]);
    float L = 0.f;
    float4 acc = {0.f, 0.f, 0.f, 0.f};
    #pragma unroll
    for (int w2 = 0; w2 < 4; ++w2) {
        float e = __expf(mm[w2 * 16 + q] - M);
        L += e * lm[w2 * 16 + q];
        float4 ov = *(const float4*)&Om[(w2 * 16 + q) * 64 + dg * 4];
        acc.x += e * ov.x; acc.y += e * ov.y; acc.z += e * ov.z; acc.w += e * ov.w;
    }
    float inv = 1.0f / L;
    float4 r4;
    r4.x = acc.x * inv; r4.y = acc.y * inv; r4.z = acc.z * inv; r4.w = acc.w * inv;
    int row = (hv >> 2) * 1024 + n0 + q;
    *(float4*)&out[(size_t)row * 256 + (hv & 3) * 64 + dg * 4] = r4;
}

// ---------------------------------------------------------------------------
// LayerNorm (512) + exact GELU, wave-per-row (4 rows/block), no barriers.
// ---------------------------------------------------------------------------
__global__ __launch_bounds__(256) void lngelu_k(
    float* __restrict__ x, const float* __restrict__ g,
    const float* __restrict__ beta)
{
    int row = blockIdx.x * 4 + (threadIdx.x >> 6);
    int lane = threadIdx.x & 63;
    float* xr = x + (size_t)row * 512;
    float4 v0 = *(const float4*)&xr[lane * 4];
    float4 v1 = *(const float4*)&xr[256 + lane * 4];
    float s = v0.x + v0.y + v0.z + v0.w + v1.x + v1.y + v1.z + v1.w;
    #pragma unroll
    for (int ofs = 1; ofs < 64; ofs <<= 1) s += __shfl_xor(s, ofs);
    float mu = s * (1.0f / 512.0f);
    float d0x = v0.x - mu, d0y = v0.y - mu, d0z = v0.z - mu, d0w = v0.w - mu;
    float d1x = v1.x - mu, d1y = v1.y - mu, d1z = v1.z - mu, d1w = v1.w - mu;
    float vv = d0x*d0x + d0y*d0y + d0z*d0z + d0w*d0w
             + d1x*d1x + d1y*d1y + d1z*d1z + d1w*d1w;
    #pragma unroll
    for (int ofs = 1; ofs < 64; ofs <<= 1) vv += __shfl_xor(vv, ofs);
    float rstd = rsqrtf(vv * (1.0f / 512.0f) + 1e-5f);
    const float IS2 = 0.70710678118654752f;
    float4 o0, o1;
    {
        float4 gg = *(const float4*)&g[lane * 4];
        float4 bb = *(const float4*)&beta[lane * 4];
        float y;
        y = d0x * rstd * gg.x + bb.x; o0.x = 0.5f * y * (1.0f + erff(y * IS2));
        y = d0y * rstd * gg.y + bb.y; o0.y = 0.5f * y * (1.0f + erff(y * IS2));
        y = d0z * rstd * gg.z + bb.z; o0.z = 0.5f * y * (1.0f + erff(y * IS2));
        y = d0w * rstd * gg.w + bb.w; o0.w = 0.5f * y * (1.0f + erff(y * IS2));
    }
    {
        float4 gg = *(const float4*)&g[256 + lane * 4];
        float4 bb = *(const float4*)&beta[256 + lane * 4];
        float y;
        y = d1x * rstd * gg.x + bb.x; o1.x = 0.5f * y * (1.0f + erff(y * IS2));
        y = d1y * rstd * gg.y + bb.y; o1.y = 0.5f * y * (1.0f + erff(y * IS2));
        y = d1z * rstd * gg.z + bb.z; o1.z = 0.5f * y * (1.0f + erff(y * IS2));
        y = d1w * rstd * gg.w + bb.w; o1.w = 0.5f * y * (1.0f + erff(y * IS2));
    }
    *(float4*)&xr[lane * 4]       = o0;
    *(float4*)&xr[256 + lane * 4] = o1;
}

__global__ __launch_bounds__(256) void z_k(
    const float* __restrict__ x, const float* __restrict__ Wz,
    const float* __restrict__ bz, float* __restrict__ z)
{
    int row = blockIdx.x, t = threadIdx.x;
    __shared__ float red[256];
    red[t] = x[(size_t)row * 256 + t] * Wz[t];
    __syncthreads();
    for (int s = 128; s > 0; s >>= 1) {
        if (t < s) red[t] += red[t + s];
        __syncthreads();
    }
    if (t == 0) z[row] = red[0] + bz[0];
}

__global__ __launch_bounds__(256) void rowlse_k(
    const float* __restrict__ sim, float* __restrict__ out)
{
    int row = blockIdx.x, t = threadIdx.x;
    __shared__ float red[256];
    float mx = -1e30f;
    for (int j = t; j < NTOK; j += 256) mx = fmaxf(mx, sim[(size_t)row * NTOK + j]);
    red[t] = mx; __syncthreads();
    for (int s = 128; s > 0; s >>= 1) {
        if (t < s) red[t] = fmaxf(red[t], red[t + s]);
        __syncthreads();
    }
    mx = red[0]; __syncthreads();
    float sum = 0.0f;
    for (int j = t; j < NTOK; j += 256) sum += expf(sim[(size_t)row * NTOK + j] - mx);
    red[t] = sum; __syncthreads();
    for (int s = 128; s > 0; s >>= 1) {
        if (t < s) red[t] += red[t + s];
        __syncthreads();
    }
    if (t == 0) out[row] = mx + logf(red[0]);
}

__global__ __launch_bounds__(256) void collse_k(
    const float* __restrict__ sim, float* __restrict__ out)
{
    int col = blockIdx.x, t = threadIdx.x;
    __shared__ float red[256];
    float mx = -1e30f;
    for (int i = t; i < NTOK; i += 256) mx = fmaxf(mx, sim[(size_t)i * NTOK + col]);
    red[t] = mx; __syncthreads();
    for (int s = 128; s > 0; s >>= 1) {
        if (t < s) red[t] = fmaxf(red[t], red[t + s]);
        __syncthreads();
    }
    mx = red[0]; __syncthreads();
    float sum = 0.0f;
    for (int i = t; i < NTOK; i += 256) sum += expf(sim[(size_t)i * NTOK + col] - mx);
    red[t] = sum; __syncthreads();
    for (int s = 128; s > 0; s >>= 1) {
        if (t < s) red[t] += red[t + s];
        __syncthreads();
    }
    if (t == 0) out[col] = mx + logf(red[0]);
}

__global__ __launch_bounds__(256) void assemble_k(
    const float* __restrict__ sim, const float* __restrict__ rls,
    const float* __restrict__ cls, const float* __restrict__ z0,
    const float* __restrict__ z1, float* __restrict__ out)
{
    int idx = blockIdx.x * 256 + threadIdx.x;
    const int W = NTOK + 1;
    if (idx >= W * W) return;
    int i = idx / W, j = idx % W;
    float v;
    if (i < NTOK && j < NTOK) {
        v = 2.0f * sim[(size_t)i * NTOK + j] - rls[i] - cls[j] + logsigf(z0[i]) + logsigf(z1[j]);
    } else if (i < NTOK) {
        v = logsigf(-z0[i]);
    } else if (j < NTOK) {
        v = logsigf(-z1[j]);
    } else {
        v = 0.0f;
    }
    out[idx] = v;
}

// ---------------------------------------------------------------------------
extern "C" void kernel_launch(void* const* d_in, const int* in_sizes, int n_in,
                              void* d_out, int out_size, void* d_ws, size_t ws_size,
                              hipStream_t stream)
{
    const float* desc0 = (const float*)d_in[0];
    const float* desc1 = (const float*)d_in[1];
    const float* kpts0 = (const float*)d_in[2];
    const float* kpts1 = (const float*)d_in[3];
    const float* Wr    = (const float*)d_in[4];
    const float* sWqkv = (const float*)d_in[5];
    const float* sbqkv = (const float*)d_in[6];
    const float* sWo   = (const float*)d_in[7];
    const float* sbo   = (const float*)d_in[8];
    const float* sfW1  = (const float*)d_in[9];
    const float* sfb1  = (const float*)d_in[10];
    const float* sfg   = (const float*)d_in[11];
    const float* sfbt  = (const float*)d_in[12];
    const float* sfW2  = (const float*)d_in[13];
    const float* sfb2  = (const float*)d_in[14];
    const float* cWqk  = (const float*)d_in[15];
    const float* cbqk  = (const float*)d_in[16];
    const float* cWv   = (const float*)d_in[17];
    const float* cbv   = (const float*)d_in[18];
    const float* cWo   = (const float*)d_in[19];
    const float* cbo   = (const float*)d_in[20];
    const float* cfW1  = (const float*)d_in[21];
    const float* cfb1  = (const float*)d_in[22];
    const float* cfg   = (const float*)d_in[23];
    const float* cfbt  = (const float*)d_in[24];
    const float* cfW2  = (const float*)d_in[25];
    const float* cfb2  = (const float*)d_in[26];
    const float* mWp   = (const float*)d_in[27];
    const float* mbp   = (const float*)d_in[28];
    const float* mWz   = (const float*)d_in[29];
    const float* mbz   = (const float*)d_in[30];

    float* ws = (float*)d_ws;
    // Layout (float units). qh/kh/vh = 8*1024*64 bf16 = 262144 fl EACH.
    float* x    = ws;                      // 524288  [2048][256] fp32
    float* encc = ws + 524288;             // 131072  [2048][64]
    float* encs = ws + 655360;             // 131072
    float* qkv  = ws + 786432;             // 1572864 [2048][768] fp32 (self only)
    float* mo   = qkv;                     // 524288  (FFN phase)
    float* pre  = qkv + 524288;            // 1048576 [2048][512]
    __bf16* qh  = (__bf16*)(ws + 2359296); // 262144 fl = 524288 bf16
    __bf16* kh  = (__bf16*)(ws + 2621440); // 262144 fl
    __bf16* vh  = (__bf16*)(ws + 2883584); // 262144 fl
    float* msg  = ws + 3145728;            // 524288  [2048][256] fp32
    float* zb   = ws + 3670016;            // 2048
    float* rlsb = ws + 3672064;            // 1024
    float* clsb = ws + 3673088;            // 1024
    float* sim  = qkv;                     // 1048576 (assignment; qkv/mo/pre dead)
    float* md   = msg;

    // bf16 pre-transposed weights [N][K], appended after fp32 region.
    // Total 11,272,192 bf16 = 5,636,096 fl -> ws total 9,310,208 fl = 37.3 MB.
    __bf16* wb    = (__bf16*)(ws + 3674112);
    __bf16* tWqkv = wb;                    // 9*768*256 = 1769472
    __bf16* tWo   = tWqkv + 1769472;       // 9*256*256 = 589824
    __bf16* tW1   = tWo   + 589824;        // 9*512*512 = 2359296
    __bf16* tW2   = tW1   + 2359296;       // 9*256*512 = 1179648
    __bf16* tcQk  = tW2   + 1179648;       // 589824
    __bf16* tcV   = tcQk  + 589824;        // 589824
    __bf16* tcWo  = tcV   + 589824;        // 589824
    __bf16* tcW1  = tcWo  + 589824;        // 2359296
    __bf16* tcW2  = tcW1  + 2359296;       // 1179648
    __bf16* tmWp  = tcW2  + 1179648;       // 65536

    // ---- one-time (per launch) weight convert+transpose ----
    wtrans_k<<<dim3(24,  8, 9), 256, 0, stream>>>(sWqkv, tWqkv, 256, 768);
    wtrans_k<<<dim3( 8,  8, 9), 256, 0, stream>>>(sWo,   tWo,   256, 256);
    wtrans_k<<<dim3(16, 16, 9), 256, 0, stream>>>(sfW1,  tW1,   512, 512);
    wtrans_k<<<dim3( 8, 16, 9), 256, 0, stream>>>(sfW2,  tW2,   512, 256);
    wtrans_k<<<dim3( 8,  8, 9), 256, 0, stream>>>(cWqk,  tcQk,  256, 256);
    wtrans_k<<<dim3( 8,  8, 9), 256, 0, stream>>>(cWv,   tcV,   256, 256);
    wtrans_k<<<dim3( 8,  8, 9), 256, 0, stream>>>(cWo,   tcWo,  256, 256);
    wtrans_k<<<dim3(16, 16, 9), 256, 0, stream>>>(cfW1,  tcW1,  512, 512);
    wtrans_k<<<dim3( 8, 16, 9), 256, 0, stream>>>(cfW2,  tcW2,  512, 256);
    wtrans_k<<<dim3( 8,  8, 1), 256, 0, stream>>>(mWp,   tmWp,  256, 256);

    auto gemmb = [&](const float* A0, const float* A1, const __bf16* Bt,
                     const float* bias, const float* R, float* C,
                     int M, int K, int Nn, int ldc, float scale) {
        gemm_bf_k<<<dim3(Nn / 64, M / 32), 256, 0, stream>>>(A0, A1, Bt, bias, R, C, M, K, Nn, ldc, scale);
    };

    const float SELF_SCALE  = 0.125f;               // DH^-0.5
    const float CROSS_SCALE = 0.35355339059327373f; // DH^-0.25

    copyvec_k<<<(NTOK * DM + 255) / 256, 256, 0, stream>>>(x, desc0, NTOK * DM);
    copyvec_k<<<(NTOK * DM + 255) / 256, 256, 0, stream>>>(x + NTOK * DM, desc1, NTOK * DM);
    posenc_k<<<(NTOK * 32 + 255) / 256, 256, 0, stream>>>(kpts0, Wr, encc, encs);
    posenc_k<<<(NTOK * 32 + 255) / 256, 256, 0, stream>>>(kpts1, Wr, encc + 65536, encs + 65536);

    for (int l = 0; l < NL; ++l) {
        // ---- self block (both images batched) ----
        gemmb(x, nullptr, tWqkv + (size_t)l * 196608, sbqkv + (size_t)l * 768,
              nullptr, qkv, 2048, 256, 768, 768, 1.0f);
        splitrope_k<<<2048, 256, 0, stream>>>(qkv, encc, encs, qh, kh, vh);
        attn_k<<<dim3(64, 8), 256, 0, stream>>>(qh, kh, vh, msg, SELF_SCALE, 0);
        gemmb(msg, nullptr, tWo + (size_t)l * 65536, sbo + (size_t)l * 256,
              nullptr, mo, 2048, 256, 256, 256, 1.0f);
        gemmb(x, mo, tW1 + (size_t)l * 262144, sfb1 + (size_t)l * 512,
              nullptr, pre, 2048, 512, 512, 512, 1.0f);
        lngelu_k<<<512, 256, 0, stream>>>(pre, sfg + (size_t)l * 512, sfbt + (size_t)l * 512);
        gemmb(pre, nullptr, tW2 + (size_t)l * 131072, sfb2 + (size_t)l * 256,
              x, x, 2048, 512, 256, 256, 1.0f);

        // ---- cross block ----
        gemm_hm2_k<<<dim3(8, 64), 256, 0, stream>>>(
            x, tcQk + (size_t)l * 65536, cbqk + (size_t)l * 256,
            tcV + (size_t)l * 65536, cbv + (size_t)l * 256,
            qh, vh, CROSS_SCALE);
        attn_k<<<dim3(64, 8), 256, 0, stream>>>(qh, qh, vh, msg, 1.0f, 1);
        gemmb(msg, nullptr, tcWo + (size_t)l * 65536, cbo + (size_t)l * 256,
              nullptr, mo, 2048, 256, 256, 256, 1.0f);
        gemmb(x, mo, tcW1 + (size_t)l * 262144, cfb1 + (size_t)l * 512,
              nullptr, pre, 2048, 512, 512, 512, 1.0f);
        lngelu_k<<<512, 256, 0, stream>>>(pre, cfg + (size_t)l * 512, cfbt + (size_t)l * 512);
        gemmb(pre, nullptr, tcW2 + (size_t)l * 131072, cfb2 + (size_t)l * 256,
              x, x, 2048, 512, 256, 256, 1.0f);
    }

    // ---- assignment head ----
    const float MD_SCALE = 0.25f; // D^-0.25
    gemmb(x, nullptr, tmWp, mbp, nullptr, md, 2048, 256, 256, 256, MD_SCALE);
    z_k<<<2048, 256, 0, stream>>>(x, mWz, mbz, zb);
    gemm_f32t_k<<<dim3(16, 32), 256, 0, stream>>>(md, md + 1024 * 256, sim, 256, 1024);
    rowlse_k<<<NTOK, 256, 0, stream>>>(sim, rlsb);
    collse_k<<<NTOK, 256, 0, stream>>>(sim, clsb);
    const int W = NTOK + 1;
    assemble_k<<<(W * W + 255) / 256, 256, 0, stream>>>(sim, rlsb, clsb, zb, zb + 1024, (float*)d_out);
}

// Round 11
// 1106.369 us; speedup vs baseline: 17.3491x; 1.1854x over previous
//
#include <hip/hip_runtime.h>
#include <cmath>

// LightGlue forward. GEMMs + attention in bf16 MFMA; Q/K/V stored bf16;
// weights pre-converted+pre-transposed to bf16 [N][K] once per launch.
// GEMMs deep-stage a full K=256 phase (60 KB LDS) to pay global latency once.
// N=1024, D=256, H=4, DH=64, L=9. Batched over both images (M=2048).
#define NTOK 1024
#define DM   256
#define NH   4
#define DH   64
#define NL   9

typedef __attribute__((ext_vector_type(8))) __bf16 bf16x8;
typedef __attribute__((ext_vector_type(4))) __bf16 bf16x4;
typedef __attribute__((ext_vector_type(4))) float  f32x4;

__device__ __forceinline__ float logsigf(float x) {
    return fminf(x, 0.0f) - log1pf(expf(-fabsf(x)));
}

__device__ __forceinline__ __bf16 f2bf(float f) {
    unsigned u = __float_as_uint(f);
    u = (u + 0x7FFFu + ((u >> 16) & 1u)) >> 16;          // round-nearest-even
    unsigned short s = (unsigned short)u;
    return __builtin_bit_cast(__bf16, s);
}

// ---------------------------------------------------------------------------
// All weight transposes in ONE dispatch. fp32 [K][N] (batched) -> bf16 [N][K].
// Grid (24, 16, 82); blocks outside a group's (N/32, K/32) early-exit.
// ---------------------------------------------------------------------------
__global__ __launch_bounds__(256) void wtrans_all_k(
    const float* __restrict__ sWqkv, const float* __restrict__ sWo,
    const float* __restrict__ sfW1,  const float* __restrict__ sfW2,
    const float* __restrict__ cWqk,  const float* __restrict__ cWv,
    const float* __restrict__ cWo,   const float* __restrict__ cfW1,
    const float* __restrict__ cfW2,  const float* __restrict__ mWp,
    __bf16* __restrict__ wb)
{
    const int z = blockIdx.z;
    const float* src; __bf16* dst; int K, N, b;
    if      (z <  9) { src = sWqkv; dst = wb;            K = 256; N = 768; b = z;      }
    else if (z < 18) { src = sWo;   dst = wb + 1769472;  K = 256; N = 256; b = z - 9;  }
    else if (z < 27) { src = sfW1;  dst = wb + 2359296;  K = 512; N = 512; b = z - 18; }
    else if (z < 36) { src = sfW2;  dst = wb + 4718592;  K = 512; N = 256; b = z - 27; }
    else if (z < 45) { src = cWqk;  dst = wb + 5898240;  K = 256; N = 256; b = z - 36; }
    else if (z < 54) { src = cWv;   dst = wb + 6488064;  K = 256; N = 256; b = z - 45; }
    else if (z < 63) { src = cWo;   dst = wb + 7077888;  K = 256; N = 256; b = z - 54; }
    else if (z < 72) { src = cfW1;  dst = wb + 7667712;  K = 512; N = 512; b = z - 63; }
    else if (z < 81) { src = cfW2;  dst = wb + 10027008; K = 512; N = 256; b = z - 72; }
    else             { src = mWp;   dst = wb + 11206656; K = 256; N = 256; b = 0;      }
    const int n0 = blockIdx.x * 32, k0 = blockIdx.y * 32;
    if (n0 >= N || k0 >= K) return;
    src += (size_t)b * K * N;
    dst += (size_t)b * K * N;

    __shared__ __bf16 t[32][36];
    const int tx = threadIdx.x & 31, ty = threadIdx.x >> 5;
    #pragma unroll
    for (int i = 0; i < 4; ++i) {
        int k = ty + i * 8;
        t[tx][k] = f2bf(src[(size_t)(k0 + k) * N + n0 + tx]);
    }
    __syncthreads();
    const int nr = threadIdx.x >> 3, kc = (threadIdx.x & 7) * 4;
    bf16x4 v = *(const bf16x4*)&t[nr][kc];
    *(bf16x4*)&dst[(size_t)(n0 + nr) * K + k0 + kc] = v;
}

// ---------------------------------------------------------------------------
// Deep-staged bf16-MFMA GEMM: C = (A @ B + bias)*scale + R. fp32 A/C, bf16 B [Nn][K].
// Stages a full 256-k phase (8 chunks of 32) -> one global latency per phase.
// A: dual-source concat (A1: cols 0-255 from A0, 256+ from A1) else lda=K.
// Tile 32x64, 4 waves 2x2. LDS 60 KB.
// ---------------------------------------------------------------------------
__global__ __launch_bounds__(256) void gemm_bf_k(
    const float* __restrict__ A0, const float* __restrict__ A1,
    const __bf16* __restrict__ Bt, const float* __restrict__ bias,
    const float* __restrict__ R, float* __restrict__ C,
    int M, int K, int Nn, int ldc, float scale)
{
    __shared__ __bf16 As[8][32][40];
    __shared__ __bf16 Bs[8][64][40];
    const int tid = threadIdx.x;
    const int w = tid >> 6, l = tid & 63;
    const int row0 = blockIdx.y * 32, col0 = blockIdx.x * 64;
    const int wr = (w >> 1) * 16, wc = (w & 1) * 32;
    f32x4 acc0 = {0.f, 0.f, 0.f, 0.f};
    f32x4 acc1 = {0.f, 0.f, 0.f, 0.f};

    const int ar = tid >> 3, ac = (tid & 7) * 4;       // A: 8 threads/row, 4 k each
    const int bnr = tid >> 2, bkc = (tid & 3) * 8;     // B: 4 threads/row, 8 k each

    for (int p0 = 0; p0 < K; p0 += 256) {
        #pragma unroll
        for (int c = 0; c < 8; ++c) {
            const int k0 = p0 + c * 32;
            float4 v;
            if (A1) {
                int kk = k0 + ac;                       // chunk never straddles seam
                const float* src = (kk < 256)
                    ? &A0[(size_t)(row0 + ar) * 256 + kk]
                    : &A1[(size_t)(row0 + ar) * 256 + (kk - 256)];
                v = *(const float4*)src;
            } else {
                v = *(const float4*)&A0[(size_t)(row0 + ar) * K + k0 + ac];
            }
            __bf16* d = &As[c][ar][ac];
            d[0] = f2bf(v.x); d[1] = f2bf(v.y); d[2] = f2bf(v.z); d[3] = f2bf(v.w);
            bf16x8 bv = *(const bf16x8*)&Bt[(size_t)(col0 + bnr) * K + k0 + bkc];
            *(bf16x8*)&Bs[c][bnr][bkc] = bv;
        }
        __syncthreads();
        #pragma unroll
        for (int c = 0; c < 8; ++c) {
            bf16x8 af  = *(const bf16x8*)&As[c][wr + (l & 15)][(l >> 4) * 8];
            bf16x8 bf0 = *(const bf16x8*)&Bs[c][wc + (l & 15)][(l >> 4) * 8];
            bf16x8 bf1 = *(const bf16x8*)&Bs[c][wc + 16 + (l & 15)][(l >> 4) * 8];
            acc0 = __builtin_amdgcn_mfma_f32_16x16x32_bf16(af, bf0, acc0, 0, 0, 0);
            acc1 = __builtin_amdgcn_mfma_f32_16x16x32_bf16(af, bf1, acc1, 0, 0, 0);
        }
        __syncthreads();
    }

    #pragma unroll
    for (int t2 = 0; t2 < 2; ++t2) {
        f32x4 a = t2 ? acc1 : acc0;
        int cc = col0 + wc + t2 * 16 + (l & 15);
        float bvv = bias ? bias[cc] : 0.0f;
        #pragma unroll
        for (int rg = 0; rg < 4; ++rg) {
            int rr = row0 + wr + (l >> 4) * 4 + rg;
            float v = (a[rg] + bvv) * scale;
            if (R) v += R[(size_t)rr * Nn + cc];
            C[(size_t)rr * ldc + cc] = v;
        }
    }
}

// ---------------------------------------------------------------------------
// Cross qk+v fused GEMM (deep-staged, K=256): grid (8, 64). bx<4 -> Wq, else Wv.
// Output head-major bf16: out[((im*4+h)*1024+n)*64+d].
// ---------------------------------------------------------------------------
__global__ __launch_bounds__(256) void gemm_hm2_k(
    const float* __restrict__ A, const __bf16* __restrict__ Btq,
    const float* __restrict__ bq, const __bf16* __restrict__ Btv,
    const float* __restrict__ bv, __bf16* __restrict__ outq,
    __bf16* __restrict__ outv, float scaleq)
{
    const int bx = blockIdx.x;
    const __bf16* Bt  = (bx < 4) ? Btq : Btv;
    const float* bias = (bx < 4) ? bq : bv;
    __bf16* C         = (bx < 4) ? outq : outv;
    const float scale = (bx < 4) ? scaleq : 1.0f;

    __shared__ __bf16 As[8][32][40];
    __shared__ __bf16 Bs[8][64][40];
    const int tid = threadIdx.x;
    const int w = tid >> 6, l = tid & 63;
    const int row0 = blockIdx.y * 32, col0 = (bx & 3) * 64;
    const int wr = (w >> 1) * 16, wc = (w & 1) * 32;
    f32x4 acc0 = {0.f, 0.f, 0.f, 0.f};
    f32x4 acc1 = {0.f, 0.f, 0.f, 0.f};

    const int ar = tid >> 3, ac = (tid & 7) * 4;
    const int bnr = tid >> 2, bkc = (tid & 3) * 8;

    #pragma unroll
    for (int c = 0; c < 8; ++c) {
        const int k0 = c * 32;
        float4 v = *(const float4*)&A[(size_t)(row0 + ar) * 256 + k0 + ac];
        __bf16* d = &As[c][ar][ac];
        d[0] = f2bf(v.x); d[1] = f2bf(v.y); d[2] = f2bf(v.z); d[3] = f2bf(v.w);
        bf16x8 bv8 = *(const bf16x8*)&Bt[(size_t)(col0 + bnr) * 256 + k0 + bkc];
        *(bf16x8*)&Bs[c][bnr][bkc] = bv8;
    }
    __syncthreads();
    #pragma unroll
    for (int c = 0; c < 8; ++c) {
        bf16x8 af  = *(const bf16x8*)&As[c][wr + (l & 15)][(l >> 4) * 8];
        bf16x8 bf0 = *(const bf16x8*)&Bs[c][wc + (l & 15)][(l >> 4) * 8];
        bf16x8 bf1 = *(const bf16x8*)&Bs[c][wc + 16 + (l & 15)][(l >> 4) * 8];
        acc0 = __builtin_amdgcn_mfma_f32_16x16x32_bf16(af, bf0, acc0, 0, 0, 0);
        acc1 = __builtin_amdgcn_mfma_f32_16x16x32_bf16(af, bf1, acc1, 0, 0, 0);
    }

    #pragma unroll
    for (int t2 = 0; t2 < 2; ++t2) {
        f32x4 a = t2 ? acc1 : acc0;
        int cc = col0 + wc + t2 * 16 + (l & 15);
        float bvv = bias ? bias[cc] : 0.0f;
        int h = cc >> 6, d = cc & 63;
        #pragma unroll
        for (int rg = 0; rg < 4; ++rg) {
            int rr = row0 + wr + (l >> 4) * 4 + rg;
            int im = rr >> 10, n = rr & 1023;
            C[(((size_t)(im * 4 + h)) * 1024 + n) * 64 + d] = f2bf((a[rg] + bvv) * scale);
        }
    }
}

// ---------------------------------------------------------------------------
// sim = A @ B^T, fp32 A,B (both activations), K=256, deep-staged.
// ---------------------------------------------------------------------------
__global__ __launch_bounds__(256) void gemm_f32t_k(
    const float* __restrict__ A, const float* __restrict__ B,
    float* __restrict__ C, int K, int Nn)
{
    __shared__ __bf16 As[8][32][40];
    __shared__ __bf16 Bs[8][64][40];
    const int tid = threadIdx.x;
    const int w = tid >> 6, l = tid & 63;
    const int row0 = blockIdx.y * 32, col0 = blockIdx.x * 64;
    const int wr = (w >> 1) * 16, wc = (w & 1) * 32;
    f32x4 acc0 = {0.f, 0.f, 0.f, 0.f};
    f32x4 acc1 = {0.f, 0.f, 0.f, 0.f};

    const int ar = tid >> 3, ac = (tid & 7) * 4;
    const int tnr = tid >> 2, tkc = (tid & 3) * 8;

    #pragma unroll
    for (int c = 0; c < 8; ++c) {
        const int k0 = c * 32;
        float4 v = *(const float4*)&A[(size_t)(row0 + ar) * K + k0 + ac];
        __bf16* d = &As[c][ar][ac];
        d[0] = f2bf(v.x); d[1] = f2bf(v.y); d[2] = f2bf(v.z); d[3] = f2bf(v.w);
        float4 a = *(const float4*)&B[(size_t)(col0 + tnr) * K + k0 + tkc];
        float4 b = *(const float4*)&B[(size_t)(col0 + tnr) * K + k0 + tkc + 4];
        __bf16* d2 = &Bs[c][tnr][tkc];
        d2[0] = f2bf(a.x); d2[1] = f2bf(a.y); d2[2] = f2bf(a.z); d2[3] = f2bf(a.w);
        d2[4] = f2bf(b.x); d2[5] = f2bf(b.y); d2[6] = f2bf(b.z); d2[7] = f2bf(b.w);
    }
    __syncthreads();
    #pragma unroll
    for (int c = 0; c < 8; ++c) {
        bf16x8 af  = *(const bf16x8*)&As[c][wr + (l & 15)][(l >> 4) * 8];
        bf16x8 bf0 = *(const bf16x8*)&Bs[c][wc + (l & 15)][(l >> 4) * 8];
        bf16x8 bf1 = *(const bf16x8*)&Bs[c][wc + 16 + (l & 15)][(l >> 4) * 8];
        acc0 = __builtin_amdgcn_mfma_f32_16x16x32_bf16(af, bf0, acc0, 0, 0, 0);
        acc1 = __builtin_amdgcn_mfma_f32_16x16x32_bf16(af, bf1, acc1, 0, 0, 0);
    }

    #pragma unroll
    for (int t2 = 0; t2 < 2; ++t2) {
        f32x4 a = t2 ? acc1 : acc0;
        int cc = col0 + wc + t2 * 16 + (l & 15);
        #pragma unroll
        for (int rg = 0; rg < 4; ++rg) {
            int rr = row0 + wr + (l >> 4) * 4 + rg;
            C[(size_t)rr * Nn + cc] = a[rg];
        }
    }
}

// ---------------------------------------------------------------------------
// Fused init: desc copies + posenc for both images. Grid 2304 x 256.
// ---------------------------------------------------------------------------
__global__ __launch_bounds__(256) void init_k(
    const float* __restrict__ desc0, const float* __restrict__ desc1,
    const float* __restrict__ kpts0, const float* __restrict__ kpts1,
    const float* __restrict__ Wr, float* __restrict__ x,
    float* __restrict__ encc, float* __restrict__ encs)
{
    int idx = blockIdx.x * 256 + threadIdx.x;
    if (idx < 524288) {
        x[idx] = (idx < 262144) ? desc0[idx] : desc1[idx - 262144];
    } else {
        int p = idx - 524288;            // 0..65535
        int im = p >> 15, q = p & 32767;
        int i = q >> 5, f = q & 31;
        const float* kp = im ? kpts1 : kpts0;
        float* ec = encc + im * 65536;
        float* es = encs + im * 65536;
        float pr = kp[i * 2] * Wr[f] + kp[i * 2 + 1] * Wr[32 + f];
        float c = cosf(pr), s = sinf(pr);
        ec[i * 64 + 2 * f] = c; ec[i * 64 + 2 * f + 1] = c;
        es[i * 64 + 2 * f] = s; es[i * 64 + 2 * f + 1] = s;
    }
}

// Split qkv [2048x768] (col = h*192+d*3+{q,k,v}) -> bf16 vhead-major
// [8][1024][64], RoPE on q,k.
__global__ __launch_bounds__(256) void splitrope_k(
    const float* __restrict__ qkv, const float* __restrict__ encc,
    const float* __restrict__ encs, __bf16* __restrict__ qh,
    __bf16* __restrict__ kh, __bf16* __restrict__ vh)
{
    int n = blockIdx.x, t = threadIdx.x;  // n: 0..2047, t = h*64 + d
    int h = t >> 6, d = t & 63;
    int im = n >> 10, nl = n & 1023;
    const float* base  = qkv + (size_t)n * 768 + h * 192 + d * 3;
    const float* pbase = qkv + (size_t)n * 768 + h * 192 + (d ^ 1) * 3;
    float c = encc[n * 64 + d], s = encs[n * 64 + d];
    float q = base[0], k = base[1], v = base[2];
    float qp = pbase[0], kp = pbase[1];
    float sgn = (d & 1) ? 1.0f : -1.0f;
    size_t o = (((size_t)(im * 4 + h)) * 1024 + nl) * 64 + d;
    qh[o] = f2bf(q * c + sgn * qp * s);
    kh[o] = f2bf(k * c + sgn * kp * s);
    vh[o] = f2bf(v);
}

// ---------------------------------------------------------------------------
// Attention v5: flash-style bf16 MFMA, bf16 Q/K/V inputs. (unchanged)
// ---------------------------------------------------------------------------
__global__ __launch_bounds__(256) void attn_k(
    const __bf16* __restrict__ Qg, const __bf16* __restrict__ Kg,
    const __bf16* __restrict__ Vg, float* __restrict__ out,
    float scale, int cross)
{
    const int qt = blockIdx.x, hv = blockIdx.y;
    const int kvh = cross ? (hv ^ 4) : hv;
    const int tid = threadIdx.x;
    const int w = tid >> 6, lane = tid & 63;
    const int quad = lane >> 4, l16 = lane & 15;
    const int n0 = qt * 16;

    __shared__ __align__(16) char smem[44032];
    char* base = smem + w * 11008;
    __bf16* kb  = (__bf16*)(base);          // 32 x 72
    __bf16* vtb = (__bf16*)(base + 4608);   // 64 x 40
    __bf16* ptb = (__bf16*)(base + 9728);   // 16 x 40

    bf16x8 qf[2];
    {
        const bf16x8* Qp = (const bf16x8*)(Qg + (((size_t)hv * 1024) + n0 + l16) * 64);
        qf[0] = Qp[quad];
        qf[1] = Qp[4 + quad];
    }

    const __bf16* Kbase = Kg + (size_t)kvh * 1024 * 64;
    const __bf16* Vbase = Vg + (size_t)kvh * 1024 * 64;

    float m[4] = {-1e30f, -1e30f, -1e30f, -1e30f};
    float lsum[4] = {0.f, 0.f, 0.f, 0.f};
    f32x4 o[4] = {{0,0,0,0},{0,0,0,0},{0,0,0,0},{0,0,0,0}};

    const int kj = lane >> 1, kd = (lane & 1) * 32;
    const int vjp = lane & 15, vd0 = (lane >> 4) * 16;

    for (int t = 0; t < 8; ++t) {
        const int j0 = w * 256 + t * 32;

        {
            const bf16x8* kp = (const bf16x8*)(Kbase + (size_t)(j0 + kj) * 64 + kd);
            bf16x8 k0 = kp[0], k1 = kp[1], k2 = kp[2], k3 = kp[3];
            __bf16* kr = kb + kj * 72 + kd;
            *(bf16x8*)(kr)      = k0;
            *(bf16x8*)(kr + 8)  = k1;
            *(bf16x8*)(kr + 16) = k2;
            *(bf16x8*)(kr + 24) = k3;
        }
        {
            const uint4* va = (const uint4*)(Vbase + (size_t)(j0 + 2 * vjp) * 64 + vd0);
            const uint4* vb = (const uint4*)(Vbase + (size_t)(j0 + 2 * vjp + 1) * 64 + vd0);
            #pragma unroll
            for (int g = 0; g < 2; ++g) {
                uint4 ua = va[g], ub = vb[g];
                unsigned au[4] = {ua.x, ua.y, ua.z, ua.w};
                unsigned bu[4] = {ub.x, ub.y, ub.z, ub.w};
                #pragma unroll
                for (int e = 0; e < 4; ++e) {
                    int i = g * 8 + e * 2;
                    unsigned pk0 = ((bu[e] & 0xFFFFu) << 16) | (au[e] & 0xFFFFu);
                    unsigned pk1 = (bu[e] & 0xFFFF0000u) | (au[e] >> 16);
                    *(unsigned*)((char*)vtb + ((vd0 + i) * 40 + 2 * vjp) * 2)     = pk0;
                    *(unsigned*)((char*)vtb + ((vd0 + i + 1) * 40 + 2 * vjp) * 2) = pk1;
                }
            }
        }

        f32x4 s0 = {0,0,0,0}, s1 = {0,0,0,0};
        #pragma unroll
        for (int kt = 0; kt < 2; ++kt) {
            bf16x8 k0 = *(const bf16x8*)(kb + (0 * 16 + l16) * 72 + kt * 32 + quad * 8);
            bf16x8 k1 = *(const bf16x8*)(kb + (1 * 16 + l16) * 72 + kt * 32 + quad * 8);
            s0 = __builtin_amdgcn_mfma_f32_16x16x32_bf16(qf[kt], k0, s0, 0, 0, 0);
            s1 = __builtin_amdgcn_mfma_f32_16x16x32_bf16(qf[kt], k1, s1, 0, 0, 0);
        }

        float rm[4], p0[4], p1[4], rs[4];
        #pragma unroll
        for (int r = 0; r < 4; ++r) {
            s0[r] *= scale; s1[r] *= scale;
            rm[r] = fmaxf(s0[r], s1[r]);
        }
        #pragma unroll
        for (int ofs = 1; ofs < 16; ofs <<= 1)
            #pragma unroll
            for (int r = 0; r < 4; ++r)
                rm[r] = fmaxf(rm[r], __shfl_xor(rm[r], ofs));
        #pragma unroll
        for (int r = 0; r < 4; ++r) {
            float mn = fmaxf(m[r], rm[r]);
            float alpha = __expf(m[r] - mn);
            m[r] = mn;
            p0[r] = __expf(s0[r] - mn);
            p1[r] = __expf(s1[r] - mn);
            rs[r] = p0[r] + p1[r];
            lsum[r] *= alpha;
            #pragma unroll
            for (int dt = 0; dt < 4; ++dt) o[dt][r] *= alpha;
        }
        #pragma unroll
        for (int ofs = 1; ofs < 16; ofs <<= 1)
            #pragma unroll
            for (int r = 0; r < 4; ++r)
                rs[r] += __shfl_xor(rs[r], ofs);
        #pragma unroll
        for (int r = 0; r < 4; ++r) lsum[r] += rs[r];

        #pragma unroll
        for (int r = 0; r < 4; ++r) {
            ptb[(quad * 4 + r) * 40 + l16]      = f2bf(p0[r]);
            ptb[(quad * 4 + r) * 40 + 16 + l16] = f2bf(p1[r]);
        }
        bf16x8 pf = *(const bf16x8*)(ptb + l16 * 40 + quad * 8);
        #pragma unroll
        for (int dt = 0; dt < 4; ++dt) {
            bf16x8 vf = *(const bf16x8*)(vtb + (dt * 16 + l16) * 40 + quad * 8);
            o[dt] = __builtin_amdgcn_mfma_f32_16x16x32_bf16(pf, vf, o[dt], 0, 0, 0);
        }
    }

    __syncthreads();
    float* Om = (float*)smem;          // [64][64] : row = w*16 + q
    float* mm = Om + 4096;             // [64]
    float* lm = mm + 64;               // [64]
    #pragma unroll
    for (int dt = 0; dt < 4; ++dt)
        #pragma unroll
        for (int r = 0; r < 4; ++r)
            Om[(w * 16 + quad * 4 + r) * 64 + dt * 16 + l16] = o[dt][r];
    if (l16 == 0) {
        #pragma unroll
        for (int r = 0; r < 4; ++r) {
            mm[w * 16 + quad * 4 + r] = m[r];
            lm[w * 16 + quad * 4 + r] = lsum[r];
        }
    }
    __syncthreads();

    const int q = tid >> 4, dg = tid & 15;
    float M = -1e30f;
    #pragma unroll
    for (int w2 = 0; w2 < 4; ++w2) M = fmaxf(M, mm[w2 * 16 + q]);
    float L = 0.f;
    float4 acc = {0.f, 0.f, 0.f, 0.f};
    #pragma unroll
    for (int w2 = 0; w2 < 4; ++w2) {
        float e = __expf(mm[w2 * 16 + q] - M);
        L += e * lm[w2 * 16 + q];
        float4 ov = *(const float4*)&Om[(w2 * 16 + q) * 64 + dg * 4];
        acc.x += e * ov.x; acc.y += e * ov.y; acc.z += e * ov.z; acc.w += e * ov.w;
    }
    float inv = 1.0f / L;
    float4 r4;
    r4.x = acc.x * inv; r4.y = acc.y * inv; r4.z = acc.z * inv; r4.w = acc.w * inv;
    int row = (hv >> 2) * 1024 + n0 + q;
    *(float4*)&out[(size_t)row * 256 + (hv & 3) * 64 + dg * 4] = r4;
}

// ---------------------------------------------------------------------------
// LayerNorm (512) + exact GELU, wave-per-row (4 rows/block), no barriers.
// ---------------------------------------------------------------------------
__global__ __launch_bounds__(256) void lngelu_k(
    float* __restrict__ x, const float* __restrict__ g,
    const float* __restrict__ beta)
{
    int row = blockIdx.x * 4 + (threadIdx.x >> 6);
    int lane = threadIdx.x & 63;
    float* xr = x + (size_t)row * 512;
    float4 v0 = *(const float4*)&xr[lane * 4];
    float4 v1 = *(const float4*)&xr[256 + lane * 4];
    float s = v0.x + v0.y + v0.z + v0.w + v1.x + v1.y + v1.z + v1.w;
    #pragma unroll
    for (int ofs = 1; ofs < 64; ofs <<= 1) s += __shfl_xor(s, ofs);
    float mu = s * (1.0f / 512.0f);
    float d0x = v0.x - mu, d0y = v0.y - mu, d0z = v0.z - mu, d0w = v0.w - mu;
    float d1x = v1.x - mu, d1y = v1.y - mu, d1z = v1.z - mu, d1w = v1.w - mu;
    float vv = d0x*d0x + d0y*d0y + d0z*d0z + d0w*d0w
             + d1x*d1x + d1y*d1y + d1z*d1z + d1w*d1w;
    #pragma unroll
    for (int ofs = 1; ofs < 64; ofs <<= 1) vv += __shfl_xor(vv, ofs);
    float rstd = rsqrtf(vv * (1.0f / 512.0f) + 1e-5f);
    const float IS2 = 0.70710678118654752f;
    float4 o0, o1;
    {
        float4 gg = *(const float4*)&g[lane * 4];
        float4 bb = *(const float4*)&beta[lane * 4];
        float y;
        y = d0x * rstd * gg.x + bb.x; o0.x = 0.5f * y * (1.0f + erff(y * IS2));
        y = d0y * rstd * gg.y + bb.y; o0.y = 0.5f * y * (1.0f + erff(y * IS2));
        y = d0z * rstd * gg.z + bb.z; o0.z = 0.5f * y * (1.0f + erff(y * IS2));
        y = d0w * rstd * gg.w + bb.w; o0.w = 0.5f * y * (1.0f + erff(y * IS2));
    }
    {
        float4 gg = *(const float4*)&g[256 + lane * 4];
        float4 bb = *(const float4*)&beta[256 + lane * 4];
        float y;
        y = d1x * rstd * gg.x + bb.x; o1.x = 0.5f * y * (1.0f + erff(y * IS2));
        y = d1y * rstd * gg.y + bb.y; o1.y = 0.5f * y * (1.0f + erff(y * IS2));
        y = d1z * rstd * gg.z + bb.z; o1.z = 0.5f * y * (1.0f + erff(y * IS2));
        y = d1w * rstd * gg.w + bb.w; o1.w = 0.5f * y * (1.0f + erff(y * IS2));
    }
    *(float4*)&xr[lane * 4]       = o0;
    *(float4*)&xr[256 + lane * 4] = o1;
}

__global__ __launch_bounds__(256) void z_k(
    const float* __restrict__ x, const float* __restrict__ Wz,
    const float* __restrict__ bz, float* __restrict__ z)
{
    int row = blockIdx.x, t = threadIdx.x;
    __shared__ float red[256];
    red[t] = x[(size_t)row * 256 + t] * Wz[t];
    __syncthreads();
    for (int s = 128; s > 0; s >>= 1) {
        if (t < s) red[t] += red[t + s];
        __syncthreads();
    }
    if (t == 0) z[row] = red[0] + bz[0];
}

// Row lse (blocks 0..1023) and col lse (blocks 1024..2047) in one dispatch.
__global__ __launch_bounds__(256) void lse_k(
    const float* __restrict__ sim, float* __restrict__ rls,
    float* __restrict__ cls)
{
    const int b = blockIdx.x, t = threadIdx.x;
    const int isCol = b >> 10, rc = b & 1023;
    const size_t base = isCol ? (size_t)rc : (size_t)rc * 1024;
    const size_t stride = isCol ? 1024 : 1;
    __shared__ float red[256];
    float mx = -1e30f;
    for (int j = t; j < NTOK; j += 256) mx = fmaxf(mx, sim[base + stride * j]);
    red[t] = mx; __syncthreads();
    for (int s = 128; s > 0; s >>= 1) {
        if (t < s) red[t] = fmaxf(red[t], red[t + s]);
        __syncthreads();
    }
    mx = red[0]; __syncthreads();
    float sum = 0.0f;
    for (int j = t; j < NTOK; j += 256) sum += expf(sim[base + stride * j] - mx);
    red[t] = sum; __syncthreads();
    for (int s = 128; s > 0; s >>= 1) {
        if (t < s) red[t] += red[t + s];
        __syncthreads();
    }
    if (t == 0) (isCol ? cls : rls)[rc] = mx + logf(red[0]);
}

__global__ __launch_bounds__(256) void assemble_k(
    const float* __restrict__ sim, const float* __restrict__ rls,
    const float* __restrict__ cls, const float* __restrict__ z0,
    const float* __restrict__ z1, float* __restrict__ out)
{
    int idx = blockIdx.x * 256 + threadIdx.x;
    const int W = NTOK + 1;
    if (idx >= W * W) return;
    int i = idx / W, j = idx % W;
    float v;
    if (i < NTOK && j < NTOK) {
        v = 2.0f * sim[(size_t)i * NTOK + j] - rls[i] - cls[j] + logsigf(z0[i]) + logsigf(z1[j]);
    } else if (i < NTOK) {
        v = logsigf(-z0[i]);
    } else if (j < NTOK) {
        v = logsigf(-z1[j]);
    } else {
        v = 0.0f;
    }
    out[idx] = v;
}

// ---------------------------------------------------------------------------
extern "C" void kernel_launch(void* const* d_in, const int* in_sizes, int n_in,
                              void* d_out, int out_size, void* d_ws, size_t ws_size,
                              hipStream_t stream)
{
    const float* desc0 = (const float*)d_in[0];
    const float* desc1 = (const float*)d_in[1];
    const float* kpts0 = (const float*)d_in[2];
    const float* kpts1 = (const float*)d_in[3];
    const float* Wr    = (const float*)d_in[4];
    const float* sWqkv = (const float*)d_in[5];
    const float* sbqkv = (const float*)d_in[6];
    const float* sWo   = (const float*)d_in[7];
    const float* sbo   = (const float*)d_in[8];
    const float* sfW1  = (const float*)d_in[9];
    const float* sfb1  = (const float*)d_in[10];
    const float* sfg   = (const float*)d_in[11];
    const float* sfbt  = (const float*)d_in[12];
    const float* sfW2  = (const float*)d_in[13];
    const float* sfb2  = (const float*)d_in[14];
    const float* cWqk  = (const float*)d_in[15];
    const float* cbqk  = (const float*)d_in[16];
    const float* cWv   = (const float*)d_in[17];
    const float* cbv   = (const float*)d_in[18];
    const float* cWo   = (const float*)d_in[19];
    const float* cbo   = (const float*)d_in[20];
    const float* cfW1  = (const float*)d_in[21];
    const float* cfb1  = (const float*)d_in[22];
    const float* cfg   = (const float*)d_in[23];
    const float* cfbt  = (const float*)d_in[24];
    const float* cfW2  = (const float*)d_in[25];
    const float* cfb2  = (const float*)d_in[26];
    const float* mWp   = (const float*)d_in[27];
    const float* mbp   = (const float*)d_in[28];
    const float* mWz   = (const float*)d_in[29];
    const float* mbz   = (const float*)d_in[30];

    float* ws = (float*)d_ws;
    // Layout (float units). qh/kh/vh = 8*1024*64 bf16 = 262144 fl EACH.
    float* x    = ws;                      // 524288  [2048][256] fp32
    float* encc = ws + 524288;             // 131072  [2048][64]
    float* encs = ws + 655360;             // 131072
    float* qkv  = ws + 786432;             // 1572864 [2048][768] fp32 (self only)
    float* mo   = qkv;                     // 524288  (FFN phase)
    float* pre  = qkv + 524288;            // 1048576 [2048][512]
    __bf16* qh  = (__bf16*)(ws + 2359296); // 262144 fl = 524288 bf16
    __bf16* kh  = (__bf16*)(ws + 2621440); // 262144 fl
    __bf16* vh  = (__bf16*)(ws + 2883584); // 262144 fl
    float* msg  = ws + 3145728;            // 524288  [2048][256] fp32
    float* zb   = ws + 3670016;            // 2048
    float* rlsb = ws + 3672064;            // 1024
    float* clsb = ws + 3673088;            // 1024
    float* sim  = qkv;                     // 1048576 (assignment; qkv/mo/pre dead)
    float* md   = msg;

    // bf16 pre-transposed weights [N][K] (11,272,192 bf16 = 5,636,096 fl).
    __bf16* wb    = (__bf16*)(ws + 3674112);
    __bf16* tWqkv = wb;                    // 9*768*256
    __bf16* tWo   = tWqkv + 1769472;
    __bf16* tW1   = tWo   + 589824;
    __bf16* tW2   = tW1   + 2359296;
    __bf16* tcQk  = tW2   + 1179648;
    __bf16* tcV   = tcQk  + 589824;
    __bf16* tcWo  = tcV   + 589824;
    __bf16* tcW1  = tcWo  + 589824;
    __bf16* tcW2  = tcW1  + 2359296;
    __bf16* tmWp  = tcW2  + 1179648;

    // ---- one dispatch: all weight convert+transposes ----
    wtrans_all_k<<<dim3(24, 16, 82), 256, 0, stream>>>(
        sWqkv, sWo, sfW1, sfW2, cWqk, cWv, cWo, cfW1, cfW2, mWp, wb);

    auto gemmb = [&](const float* A0, const float* A1, const __bf16* Bt,
                     const float* bias, const float* R, float* C,
                     int M, int K, int Nn, int ldc, float scale) {
        gemm_bf_k<<<dim3(Nn / 64, M / 32), 256, 0, stream>>>(A0, A1, Bt, bias, R, C, M, K, Nn, ldc, scale);
    };

    const float SELF_SCALE  = 0.125f;               // DH^-0.5
    const float CROSS_SCALE = 0.35355339059327373f; // DH^-0.25

    init_k<<<2304, 256, 0, stream>>>(desc0, desc1, kpts0, kpts1, Wr, x, encc, encs);

    for (int l = 0; l < NL; ++l) {
        // ---- self block (both images batched) ----
        gemmb(x, nullptr, tWqkv + (size_t)l * 196608, sbqkv + (size_t)l * 768,
              nullptr, qkv, 2048, 256, 768, 768, 1.0f);
        splitrope_k<<<2048, 256, 0, stream>>>(qkv, encc, encs, qh, kh, vh);
        attn_k<<<dim3(64, 8), 256, 0, stream>>>(qh, kh, vh, msg, SELF_SCALE, 0);
        gemmb(msg, nullptr, tWo + (size_t)l * 65536, sbo + (size_t)l * 256,
              nullptr, mo, 2048, 256, 256, 256, 1.0f);
        gemmb(x, mo, tW1 + (size_t)l * 262144, sfb1 + (size_t)l * 512,
              nullptr, pre, 2048, 512, 512, 512, 1.0f);
        lngelu_k<<<512, 256, 0, stream>>>(pre, sfg + (size_t)l * 512, sfbt + (size_t)l * 512);
        gemmb(pre, nullptr, tW2 + (size_t)l * 131072, sfb2 + (size_t)l * 256,
              x, x, 2048, 512, 256, 256, 1.0f);

        // ---- cross block ----
        gemm_hm2_k<<<dim3(8, 64), 256, 0, stream>>>(
            x, tcQk + (size_t)l * 65536, cbqk + (size_t)l * 256,
            tcV + (size_t)l * 65536, cbv + (size_t)l * 256,
            qh, vh, CROSS_SCALE);
        attn_k<<<dim3(64, 8), 256, 0, stream>>>(qh, qh, vh, msg, 1.0f, 1);
        gemmb(msg, nullptr, tcWo + (size_t)l * 65536, cbo + (size_t)l * 256,
              nullptr, mo, 2048, 256, 256, 256, 1.0f);
        gemmb(x, mo, tcW1 + (size_t)l * 262144, cfb1 + (size_t)l * 512,
              nullptr, pre, 2048, 512, 512, 512, 1.0f);
        lngelu_k<<<512, 256, 0, stream>>>(pre, cfg + (size_t)l * 512, cfbt + (size_t)l * 512);
        gemmb(pre, nullptr, tcW2 + (size_t)l * 131072, cfb2 + (size_t)l * 256,
              x, x, 2048, 512, 256, 256, 1.0f);
    }

    // ---- assignment head ----
    const float MD_SCALE = 0.25f; // D^-0.25
    gemmb(x, nullptr, tmWp, mbp, nullptr, md, 2048, 256, 256, 256, MD_SCALE);
    z_k<<<2048, 256, 0, stream>>>(x, mWz, mbz, zb);
    gemm_f32t_k<<<dim3(16, 32), 256, 0, stream>>>(md, md + 1024 * 256, sim, 256, 1024);
    lse_k<<<2048, 256, 0, stream>>>(sim, rlsb, clsb);
    const int W = NTOK + 1;
    assemble_k<<<(W * W + 255) / 256, 256, 0, stream>>>(sim, rlsb, clsb, zb, zb + 1024, (float*)d_out);
}

// Round 12
// 1031.054 us; speedup vs baseline: 18.6164x; 1.0730x over previous
//
#include <hip/hip_runtime.h>
#include <cmath>

// LightGlue forward. GEMMs + attention in bf16 MFMA; Q/K/V stored bf16;
// weights pre-converted+pre-transposed to bf16 [N][K] once per launch.
// Wo GEMM eliminated via pre-fused Wf = Wo @ W1b (per layer, one batched GEMM).
// Attention software-pipelines K/V global loads across key tiles.
// N=1024, D=256, H=4, DH=64, L=9. Batched over both images (M=2048).
#define NTOK 1024
#define DM   256
#define NH   4
#define DH   64
#define NL   9

typedef __attribute__((ext_vector_type(8))) __bf16 bf16x8;
typedef __attribute__((ext_vector_type(4))) __bf16 bf16x4;
typedef __attribute__((ext_vector_type(4))) float  f32x4;

__device__ __forceinline__ float logsigf(float x) {
    return fminf(x, 0.0f) - log1pf(expf(-fabsf(x)));
}

__device__ __forceinline__ __bf16 f2bf(float f) {
    unsigned u = __float_as_uint(f);
    u = (u + 0x7FFFu + ((u >> 16) & 1u)) >> 16;          // round-nearest-even
    unsigned short s = (unsigned short)u;
    return __builtin_bit_cast(__bf16, s);
}

// ---------------------------------------------------------------------------
// All weight transposes in ONE dispatch. fp32 [K][N] (batched) -> bf16 [N][K].
// Grid (24, 16, 82); blocks outside a group's (N/32, K/32) early-exit.
// ---------------------------------------------------------------------------
__global__ __launch_bounds__(256) void wtrans_all_k(
    const float* __restrict__ sWqkv, const float* __restrict__ sWo,
    const float* __restrict__ sfW1,  const float* __restrict__ sfW2,
    const float* __restrict__ cWqk,  const float* __restrict__ cWv,
    const float* __restrict__ cWo,   const float* __restrict__ cfW1,
    const float* __restrict__ cfW2,  const float* __restrict__ mWp,
    __bf16* __restrict__ wb)
{
    const int z = blockIdx.z;
    const float* src; __bf16* dst; int K, N, b;
    if      (z <  9) { src = sWqkv; dst = wb;            K = 256; N = 768; b = z;      }
    else if (z < 18) { src = sWo;   dst = wb + 1769472;  K = 256; N = 256; b = z - 9;  }
    else if (z < 27) { src = sfW1;  dst = wb + 2359296;  K = 512; N = 512; b = z - 18; }
    else if (z < 36) { src = sfW2;  dst = wb + 4718592;  K = 512; N = 256; b = z - 27; }
    else if (z < 45) { src = cWqk;  dst = wb + 5898240;  K = 256; N = 256; b = z - 36; }
    else if (z < 54) { src = cWv;   dst = wb + 6488064;  K = 256; N = 256; b = z - 45; }
    else if (z < 63) { src = cWo;   dst = wb + 7077888;  K = 256; N = 256; b = z - 54; }
    else if (z < 72) { src = cfW1;  dst = wb + 7667712;  K = 512; N = 512; b = z - 63; }
    else if (z < 81) { src = cfW2;  dst = wb + 10027008; K = 512; N = 256; b = z - 72; }
    else             { src = mWp;   dst = wb + 11206656; K = 256; N = 256; b = 0;      }
    const int n0 = blockIdx.x * 32, k0 = blockIdx.y * 32;
    if (n0 >= N || k0 >= K) return;
    src += (size_t)b * K * N;
    dst += (size_t)b * K * N;

    __shared__ __bf16 t[32][36];
    const int tx = threadIdx.x & 31, ty = threadIdx.x >> 5;
    #pragma unroll
    for (int i = 0; i < 4; ++i) {
        int k = ty + i * 8;
        t[tx][k] = f2bf(src[(size_t)(k0 + k) * N + n0 + tx]);
    }
    __syncthreads();
    const int nr = threadIdx.x >> 3, kc = (threadIdx.x & 7) * 4;
    bf16x4 v = *(const bf16x4*)&t[nr][kc];
    *(bf16x4*)&dst[(size_t)(n0 + nr) * K + k0 + kc] = v;
}

// ---------------------------------------------------------------------------
// Weight fusion: tW1f[z][o][0:256] = tW1[z][o][0:256] (copy, bx<4);
// tW1f[z][o][256+k] = sum_m tW1[z][o][256+m] * tWo[z][m][k]  (bx>=4, MFMA).
// z<9 self (tW1, tWo), z>=9 cross (tcW1, tcWo). Grid (8, 16, 18).
// ---------------------------------------------------------------------------
__global__ __launch_bounds__(256) void wfuse_k(
    const __bf16* __restrict__ tW1s, const __bf16* __restrict__ tWos,
    const __bf16* __restrict__ tW1c, const __bf16* __restrict__ tWoc,
    __bf16* __restrict__ tW1f)
{
    const int z = blockIdx.z, bx = blockIdx.x, tid = threadIdx.x;
    const __bf16* A  = (z < 9) ? tW1s + (size_t)z * 262144 : tW1c + (size_t)(z - 9) * 262144;
    const __bf16* B  = (z < 9) ? tWos + (size_t)z * 65536  : tWoc + (size_t)(z - 9) * 65536;
    __bf16* dst      = tW1f + (size_t)z * 262144;
    const int row0 = blockIdx.y * 32;

    if (bx < 4) {  // copy x-part columns [bx*64, bx*64+64)
        const int row = tid >> 3, kc = (tid & 7) * 8;
        bf16x8 v = *(const bf16x8*)&A[(size_t)(row0 + row) * 512 + bx * 64 + kc];
        *(bf16x8*)&dst[(size_t)(row0 + row) * 512 + bx * 64 + kc] = v;
        return;
    }

    __shared__ __bf16 As[8][32][40];
    __shared__ __bf16 Bs[8][64][40];
    const int w = tid >> 6, l = tid & 63;
    const int col0 = (bx - 4) * 64;
    const int wr = (w >> 1) * 16, wc = (w & 1) * 32;
    f32x4 acc0 = {0.f, 0.f, 0.f, 0.f};
    f32x4 acc1 = {0.f, 0.f, 0.f, 0.f};

    const int ar = tid >> 3, ac = (tid & 7) * 4;
    const int tnr = tid >> 3, tkc = (tid & 7) * 8;

    #pragma unroll
    for (int c = 0; c < 8; ++c) {
        bf16x4 av = *(const bf16x4*)&A[(size_t)(row0 + ar) * 512 + 256 + c * 32 + ac];
        *(bf16x4*)&As[c][ar][ac] = av;
        bf16x8 bv = *(const bf16x8*)&B[(size_t)(c * 32 + tnr) * 256 + col0 + tkc];
        #pragma unroll
        for (int e = 0; e < 8; ++e) Bs[c][tkc + e][tnr] = bv[e];
    }
    __syncthreads();
    #pragma unroll
    for (int c = 0; c < 8; ++c) {
        bf16x8 af  = *(const bf16x8*)&As[c][wr + (l & 15)][(l >> 4) * 8];
        bf16x8 bf0 = *(const bf16x8*)&Bs[c][wc + (l & 15)][(l >> 4) * 8];
        bf16x8 bf1 = *(const bf16x8*)&Bs[c][wc + 16 + (l & 15)][(l >> 4) * 8];
        acc0 = __builtin_amdgcn_mfma_f32_16x16x32_bf16(af, bf0, acc0, 0, 0, 0);
        acc1 = __builtin_amdgcn_mfma_f32_16x16x32_bf16(af, bf1, acc1, 0, 0, 0);
    }
    #pragma unroll
    for (int t2 = 0; t2 < 2; ++t2) {
        f32x4 a = t2 ? acc1 : acc0;
        int cc = col0 + wc + t2 * 16 + (l & 15);
        #pragma unroll
        for (int rg = 0; rg < 4; ++rg) {
            int rr = row0 + wr + (l >> 4) * 4 + rg;
            dst[(size_t)rr * 512 + 256 + cc] = f2bf(a[rg]);
        }
    }
}

// bfused[z][o] = b1[z][o] + sum_m bo[z][m] * W1[z][256+m][o]   (fp32)
__global__ __launch_bounds__(256) void bfuse_k(
    const float* __restrict__ sbo, const float* __restrict__ sfW1,
    const float* __restrict__ sfb1, const float* __restrict__ cbo,
    const float* __restrict__ cfW1, const float* __restrict__ cfb1,
    float* __restrict__ bf)
{
    const int z = blockIdx.y;
    const float* bo = (z < 9) ? sbo + z * 256 : cbo + (z - 9) * 256;
    const float* W1 = (z < 9) ? sfW1 + (size_t)z * 262144 : cfW1 + (size_t)(z - 9) * 262144;
    const float* b1 = (z < 9) ? sfb1 + z * 512 : cfb1 + (z - 9) * 512;
    const int o = blockIdx.x * 256 + threadIdx.x;
    float acc = 0.f;
    for (int m = 0; m < 256; ++m)
        acc += bo[m] * W1[(size_t)(256 + m) * 512 + o];
    bf[(size_t)z * 512 + o] = b1[o] + acc;
}

// ---------------------------------------------------------------------------
// Deep-staged bf16-MFMA GEMM: C = (A @ B + bias)*scale + R. fp32 A/C, bf16 B [Nn][K].
// ---------------------------------------------------------------------------
__global__ __launch_bounds__(256) void gemm_bf_k(
    const float* __restrict__ A0, const float* __restrict__ A1,
    const __bf16* __restrict__ Bt, const float* __restrict__ bias,
    const float* __restrict__ R, float* __restrict__ C,
    int M, int K, int Nn, int ldc, float scale)
{
    __shared__ __bf16 As[8][32][40];
    __shared__ __bf16 Bs[8][64][40];
    const int tid = threadIdx.x;
    const int w = tid >> 6, l = tid & 63;
    const int row0 = blockIdx.y * 32, col0 = blockIdx.x * 64;
    const int wr = (w >> 1) * 16, wc = (w & 1) * 32;
    f32x4 acc0 = {0.f, 0.f, 0.f, 0.f};
    f32x4 acc1 = {0.f, 0.f, 0.f, 0.f};

    const int ar = tid >> 3, ac = (tid & 7) * 4;
    const int bnr = tid >> 2, bkc = (tid & 3) * 8;

    for (int p0 = 0; p0 < K; p0 += 256) {
        #pragma unroll
        for (int c = 0; c < 8; ++c) {
            const int k0 = p0 + c * 32;
            float4 v;
            if (A1) {
                int kk = k0 + ac;
                const float* src = (kk < 256)
                    ? &A0[(size_t)(row0 + ar) * 256 + kk]
                    : &A1[(size_t)(row0 + ar) * 256 + (kk - 256)];
                v = *(const float4*)src;
            } else {
                v = *(const float4*)&A0[(size_t)(row0 + ar) * K + k0 + ac];
            }
            __bf16* d = &As[c][ar][ac];
            d[0] = f2bf(v.x); d[1] = f2bf(v.y); d[2] = f2bf(v.z); d[3] = f2bf(v.w);
            bf16x8 bv = *(const bf16x8*)&Bt[(size_t)(col0 + bnr) * K + k0 + bkc];
            *(bf16x8*)&Bs[c][bnr][bkc] = bv;
        }
        __syncthreads();
        #pragma unroll
        for (int c = 0; c < 8; ++c) {
            bf16x8 af  = *(const bf16x8*)&As[c][wr + (l & 15)][(l >> 4) * 8];
            bf16x8 bf0 = *(const bf16x8*)&Bs[c][wc + (l & 15)][(l >> 4) * 8];
            bf16x8 bf1 = *(const bf16x8*)&Bs[c][wc + 16 + (l & 15)][(l >> 4) * 8];
            acc0 = __builtin_amdgcn_mfma_f32_16x16x32_bf16(af, bf0, acc0, 0, 0, 0);
            acc1 = __builtin_amdgcn_mfma_f32_16x16x32_bf16(af, bf1, acc1, 0, 0, 0);
        }
        __syncthreads();
    }

    #pragma unroll
    for (int t2 = 0; t2 < 2; ++t2) {
        f32x4 a = t2 ? acc1 : acc0;
        int cc = col0 + wc + t2 * 16 + (l & 15);
        float bvv = bias ? bias[cc] : 0.0f;
        #pragma unroll
        for (int rg = 0; rg < 4; ++rg) {
            int rr = row0 + wr + (l >> 4) * 4 + rg;
            float v = (a[rg] + bvv) * scale;
            if (R) v += R[(size_t)rr * Nn + cc];
            C[(size_t)rr * ldc + cc] = v;
        }
    }
}

// ---------------------------------------------------------------------------
// Cross qk+v fused GEMM (deep-staged, K=256): grid (8, 64). bx<4 -> Wq, else Wv.
// ---------------------------------------------------------------------------
__global__ __launch_bounds__(256) void gemm_hm2_k(
    const float* __restrict__ A, const __bf16* __restrict__ Btq,
    const float* __restrict__ bq, const __bf16* __restrict__ Btv,
    const float* __restrict__ bv, __bf16* __restrict__ outq,
    __bf16* __restrict__ outv, float scaleq)
{
    const int bx = blockIdx.x;
    const __bf16* Bt  = (bx < 4) ? Btq : Btv;
    const float* bias = (bx < 4) ? bq : bv;
    __bf16* C         = (bx < 4) ? outq : outv;
    const float scale = (bx < 4) ? scaleq : 1.0f;

    __shared__ __bf16 As[8][32][40];
    __shared__ __bf16 Bs[8][64][40];
    const int tid = threadIdx.x;
    const int w = tid >> 6, l = tid & 63;
    const int row0 = blockIdx.y * 32, col0 = (bx & 3) * 64;
    const int wr = (w >> 1) * 16, wc = (w & 1) * 32;
    f32x4 acc0 = {0.f, 0.f, 0.f, 0.f};
    f32x4 acc1 = {0.f, 0.f, 0.f, 0.f};

    const int ar = tid >> 3, ac = (tid & 7) * 4;
    const int bnr = tid >> 2, bkc = (tid & 3) * 8;

    #pragma unroll
    for (int c = 0; c < 8; ++c) {
        const int k0 = c * 32;
        float4 v = *(const float4*)&A[(size_t)(row0 + ar) * 256 + k0 + ac];
        __bf16* d = &As[c][ar][ac];
        d[0] = f2bf(v.x); d[1] = f2bf(v.y); d[2] = f2bf(v.z); d[3] = f2bf(v.w);
        bf16x8 bv8 = *(const bf16x8*)&Bt[(size_t)(col0 + bnr) * 256 + k0 + bkc];
        *(bf16x8*)&Bs[c][bnr][bkc] = bv8;
    }
    __syncthreads();
    #pragma unroll
    for (int c = 0; c < 8; ++c) {
        bf16x8 af  = *(const bf16x8*)&As[c][wr + (l & 15)][(l >> 4) * 8];
        bf16x8 bf0 = *(const bf16x8*)&Bs[c][wc + (l & 15)][(l >> 4) * 8];
        bf16x8 bf1 = *(const bf16x8*)&Bs[c][wc + 16 + (l & 15)][(l >> 4) * 8];
        acc0 = __builtin_amdgcn_mfma_f32_16x16x32_bf16(af, bf0, acc0, 0, 0, 0);
        acc1 = __builtin_amdgcn_mfma_f32_16x16x32_bf16(af, bf1, acc1, 0, 0, 0);
    }

    #pragma unroll
    for (int t2 = 0; t2 < 2; ++t2) {
        f32x4 a = t2 ? acc1 : acc0;
        int cc = col0 + wc + t2 * 16 + (l & 15);
        float bvv = bias ? bias[cc] : 0.0f;
        int h = cc >> 6, d = cc & 63;
        #pragma unroll
        for (int rg = 0; rg < 4; ++rg) {
            int rr = row0 + wr + (l >> 4) * 4 + rg;
            int im = rr >> 10, n = rr & 1023;
            C[(((size_t)(im * 4 + h)) * 1024 + n) * 64 + d] = f2bf((a[rg] + bvv) * scale);
        }
    }
}

// ---------------------------------------------------------------------------
// sim = A @ B^T, fp32 A,B (both activations), K=256, deep-staged.
// ---------------------------------------------------------------------------
__global__ __launch_bounds__(256) void gemm_f32t_k(
    const float* __restrict__ A, const float* __restrict__ B,
    float* __restrict__ C, int K, int Nn)
{
    __shared__ __bf16 As[8][32][40];
    __shared__ __bf16 Bs[8][64][40];
    const int tid = threadIdx.x;
    const int w = tid >> 6, l = tid & 63;
    const int row0 = blockIdx.y * 32, col0 = blockIdx.x * 64;
    const int wr = (w >> 1) * 16, wc = (w & 1) * 32;
    f32x4 acc0 = {0.f, 0.f, 0.f, 0.f};
    f32x4 acc1 = {0.f, 0.f, 0.f, 0.f};

    const int ar = tid >> 3, ac = (tid & 7) * 4;
    const int tnr = tid >> 2, tkc = (tid & 3) * 8;

    #pragma unroll
    for (int c = 0; c < 8; ++c) {
        const int k0 = c * 32;
        float4 v = *(const float4*)&A[(size_t)(row0 + ar) * K + k0 + ac];
        __bf16* d = &As[c][ar][ac];
        d[0] = f2bf(v.x); d[1] = f2bf(v.y); d[2] = f2bf(v.z); d[3] = f2bf(v.w);
        float4 a = *(const float4*)&B[(size_t)(col0 + tnr) * K + k0 + tkc];
        float4 b = *(const float4*)&B[(size_t)(col0 + tnr) * K + k0 + tkc + 4];
        __bf16* d2 = &Bs[c][tnr][tkc];
        d2[0] = f2bf(a.x); d2[1] = f2bf(a.y); d2[2] = f2bf(a.z); d2[3] = f2bf(a.w);
        d2[4] = f2bf(b.x); d2[5] = f2bf(b.y); d2[6] = f2bf(b.z); d2[7] = f2bf(b.w);
    }
    __syncthreads();
    #pragma unroll
    for (int c = 0; c < 8; ++c) {
        bf16x8 af  = *(const bf16x8*)&As[c][wr + (l & 15)][(l >> 4) * 8];
        bf16x8 bf0 = *(const bf16x8*)&Bs[c][wc + (l & 15)][(l >> 4) * 8];
        bf16x8 bf1 = *(const bf16x8*)&Bs[c][wc + 16 + (l & 15)][(l >> 4) * 8];
        acc0 = __builtin_amdgcn_mfma_f32_16x16x32_bf16(af, bf0, acc0, 0, 0, 0);
        acc1 = __builtin_amdgcn_mfma_f32_16x16x32_bf16(af, bf1, acc1, 0, 0, 0);
    }

    #pragma unroll
    for (int t2 = 0; t2 < 2; ++t2) {
        f32x4 a = t2 ? acc1 : acc0;
        int cc = col0 + wc + t2 * 16 + (l & 15);
        #pragma unroll
        for (int rg = 0; rg < 4; ++rg) {
            int rr = row0 + wr + (l >> 4) * 4 + rg;
            C[(size_t)rr * Nn + cc] = a[rg];
        }
    }
}

// ---------------------------------------------------------------------------
// Fused init: desc copies + posenc for both images. Grid 2304 x 256.
// ---------------------------------------------------------------------------
__global__ __launch_bounds__(256) void init_k(
    const float* __restrict__ desc0, const float* __restrict__ desc1,
    const float* __restrict__ kpts0, const float* __restrict__ kpts1,
    const float* __restrict__ Wr, float* __restrict__ x,
    float* __restrict__ encc, float* __restrict__ encs)
{
    int idx = blockIdx.x * 256 + threadIdx.x;
    if (idx < 524288) {
        x[idx] = (idx < 262144) ? desc0[idx] : desc1[idx - 262144];
    } else {
        int p = idx - 524288;            // 0..65535
        int im = p >> 15, q = p & 32767;
        int i = q >> 5, f = q & 31;
        const float* kp = im ? kpts1 : kpts0;
        float* ec = encc + im * 65536;
        float* es = encs + im * 65536;
        float pr = kp[i * 2] * Wr[f] + kp[i * 2 + 1] * Wr[32 + f];
        float c = cosf(pr), s = sinf(pr);
        ec[i * 64 + 2 * f] = c; ec[i * 64 + 2 * f + 1] = c;
        es[i * 64 + 2 * f] = s; es[i * 64 + 2 * f + 1] = s;
    }
}

// Split qkv [2048x768] (col = h*192+d*3+{q,k,v}) -> bf16 vhead-major
// [8][1024][64], RoPE on q,k.
__global__ __launch_bounds__(256) void splitrope_k(
    const float* __restrict__ qkv, const float* __restrict__ encc,
    const float* __restrict__ encs, __bf16* __restrict__ qh,
    __bf16* __restrict__ kh, __bf16* __restrict__ vh)
{
    int n = blockIdx.x, t = threadIdx.x;  // n: 0..2047, t = h*64 + d
    int h = t >> 6, d = t & 63;
    int im = n >> 10, nl = n & 1023;
    const float* base  = qkv + (size_t)n * 768 + h * 192 + d * 3;
    const float* pbase = qkv + (size_t)n * 768 + h * 192 + (d ^ 1) * 3;
    float c = encc[n * 64 + d], s = encs[n * 64 + d];
    float q = base[0], k = base[1], v = base[2];
    float qp = pbase[0], kp = pbase[1];
    float sgn = (d & 1) ? 1.0f : -1.0f;
    size_t o = (((size_t)(im * 4 + h)) * 1024 + nl) * 64 + d;
    qh[o] = f2bf(q * c + sgn * qp * s);
    kh[o] = f2bf(k * c + sgn * kp * s);
    vh[o] = f2bf(v);
}

// ---------------------------------------------------------------------------
// Attention v6: flash-style bf16 MFMA with K/V register prefetch pipelining.
// Block = (16-query tile qt, vhead hv). Grid (64, 8). Wave w owns keys
// [w*256, w*256+256) in 8 tiles of 32; wave-private LDS; merge at end.
// ---------------------------------------------------------------------------
__global__ __launch_bounds__(256) void attn_k(
    const __bf16* __restrict__ Qg, const __bf16* __restrict__ Kg,
    const __bf16* __restrict__ Vg, float* __restrict__ out,
    float scale, int cross)
{
    const int qt = blockIdx.x, hv = blockIdx.y;
    const int kvh = cross ? (hv ^ 4) : hv;
    const int tid = threadIdx.x;
    const int w = tid >> 6, lane = tid & 63;
    const int quad = lane >> 4, l16 = lane & 15;
    const int n0 = qt * 16;

    __shared__ __align__(16) char smem[44032];
    char* base = smem + w * 11008;
    __bf16* kb  = (__bf16*)(base);          // 32 x 72
    __bf16* vtb = (__bf16*)(base + 4608);   // 64 x 40
    __bf16* ptb = (__bf16*)(base + 9728);   // 16 x 40

    bf16x8 qf[2];
    {
        const bf16x8* Qp = (const bf16x8*)(Qg + (((size_t)hv * 1024) + n0 + l16) * 64);
        qf[0] = Qp[quad];
        qf[1] = Qp[4 + quad];
    }

    const __bf16* Kbase = Kg + (size_t)kvh * 1024 * 64;
    const __bf16* Vbase = Vg + (size_t)kvh * 1024 * 64;

    float m[4] = {-1e30f, -1e30f, -1e30f, -1e30f};
    float lsum[4] = {0.f, 0.f, 0.f, 0.f};
    f32x4 o[4] = {{0,0,0,0},{0,0,0,0},{0,0,0,0},{0,0,0,0}};

    const int kj = lane >> 1, kd = (lane & 1) * 32;
    const int vjp = lane & 15, vd0 = (lane >> 4) * 16;

    // prefetch tile 0
    bf16x8 kr[4];
    uint4  vr[4];
    {
        const int j0 = w * 256;
        const bf16x8* kp = (const bf16x8*)(Kbase + (size_t)(j0 + kj) * 64 + kd);
        kr[0] = kp[0]; kr[1] = kp[1]; kr[2] = kp[2]; kr[3] = kp[3];
        const uint4* va = (const uint4*)(Vbase + (size_t)(j0 + 2 * vjp) * 64 + vd0);
        const uint4* vb = (const uint4*)(Vbase + (size_t)(j0 + 2 * vjp + 1) * 64 + vd0);
        vr[0] = va[0]; vr[1] = va[1]; vr[2] = vb[0]; vr[3] = vb[1];
    }

    for (int t = 0; t < 8; ++t) {
        // ---- store prefetched tile to wave-private LDS ----
        {
            __bf16* krow = kb + kj * 72 + kd;
            *(bf16x8*)(krow)      = kr[0];
            *(bf16x8*)(krow + 8)  = kr[1];
            *(bf16x8*)(krow + 16) = kr[2];
            *(bf16x8*)(krow + 24) = kr[3];
            #pragma unroll
            for (int g = 0; g < 2; ++g) {
                uint4 ua = vr[g], ub = vr[2 + g];
                unsigned au[4] = {ua.x, ua.y, ua.z, ua.w};
                unsigned bu[4] = {ub.x, ub.y, ub.z, ub.w};
                #pragma unroll
                for (int e = 0; e < 4; ++e) {
                    int i = g * 8 + e * 2;
                    unsigned pk0 = ((bu[e] & 0xFFFFu) << 16) | (au[e] & 0xFFFFu);
                    unsigned pk1 = (bu[e] & 0xFFFF0000u) | (au[e] >> 16);
                    *(unsigned*)((char*)vtb + ((vd0 + i) * 40 + 2 * vjp) * 2)     = pk0;
                    *(unsigned*)((char*)vtb + ((vd0 + i + 1) * 40 + 2 * vjp) * 2) = pk1;
                }
            }
        }
        // ---- issue prefetch for tile t+1 (overlaps with compute below) ----
        if (t < 7) {
            const int j1 = w * 256 + (t + 1) * 32;
            const bf16x8* kp = (const bf16x8*)(Kbase + (size_t)(j1 + kj) * 64 + kd);
            kr[0] = kp[0]; kr[1] = kp[1]; kr[2] = kp[2]; kr[3] = kp[3];
            const uint4* va = (const uint4*)(Vbase + (size_t)(j1 + 2 * vjp) * 64 + vd0);
            const uint4* vb = (const uint4*)(Vbase + (size_t)(j1 + 2 * vjp + 1) * 64 + vd0);
            vr[0] = va[0]; vr[1] = va[1]; vr[2] = vb[0]; vr[3] = vb[1];
        }

        // ---- S = Q K^T ----
        f32x4 s0 = {0,0,0,0}, s1 = {0,0,0,0};
        #pragma unroll
        for (int kt = 0; kt < 2; ++kt) {
            bf16x8 k0 = *(const bf16x8*)(kb + (0 * 16 + l16) * 72 + kt * 32 + quad * 8);
            bf16x8 k1 = *(const bf16x8*)(kb + (1 * 16 + l16) * 72 + kt * 32 + quad * 8);
            s0 = __builtin_amdgcn_mfma_f32_16x16x32_bf16(qf[kt], k0, s0, 0, 0, 0);
            s1 = __builtin_amdgcn_mfma_f32_16x16x32_bf16(qf[kt], k1, s1, 0, 0, 0);
        }

        // ---- online softmax ----
        float rm[4], p0[4], p1[4], rs[4];
        #pragma unroll
        for (int r = 0; r < 4; ++r) {
            s0[r] *= scale; s1[r] *= scale;
            rm[r] = fmaxf(s0[r], s1[r]);
        }
        #pragma unroll
        for (int ofs = 1; ofs < 16; ofs <<= 1)
            #pragma unroll
            for (int r = 0; r < 4; ++r)
                rm[r] = fmaxf(rm[r], __shfl_xor(rm[r], ofs));
        #pragma unroll
        for (int r = 0; r < 4; ++r) {
            float mn = fmaxf(m[r], rm[r]);
            float alpha = __expf(m[r] - mn);
            m[r] = mn;
            p0[r] = __expf(s0[r] - mn);
            p1[r] = __expf(s1[r] - mn);
            rs[r] = p0[r] + p1[r];
            lsum[r] *= alpha;
            #pragma unroll
            for (int dt = 0; dt < 4; ++dt) o[dt][r] *= alpha;
        }
        #pragma unroll
        for (int ofs = 1; ofs < 16; ofs <<= 1)
            #pragma unroll
            for (int r = 0; r < 4; ++r)
                rs[r] += __shfl_xor(rs[r], ofs);
        #pragma unroll
        for (int r = 0; r < 4; ++r) lsum[r] += rs[r];

        // ---- P -> LDS (C-layout), read back as A-frag; PV MFMAs ----
        #pragma unroll
        for (int r = 0; r < 4; ++r) {
            ptb[(quad * 4 + r) * 40 + l16]      = f2bf(p0[r]);
            ptb[(quad * 4 + r) * 40 + 16 + l16] = f2bf(p1[r]);
        }
        bf16x8 pf = *(const bf16x8*)(ptb + l16 * 40 + quad * 8);
        #pragma unroll
        for (int dt = 0; dt < 4; ++dt) {
            bf16x8 vf = *(const bf16x8*)(vtb + (dt * 16 + l16) * 40 + quad * 8);
            o[dt] = __builtin_amdgcn_mfma_f32_16x16x32_bf16(pf, vf, o[dt], 0, 0, 0);
        }
    }

    __syncthreads();
    float* Om = (float*)smem;          // [64][64] : row = w*16 + q
    float* mm = Om + 4096;             // [64]
    float* lm = mm + 64;               // [64]
    #pragma unroll
    for (int dt = 0; dt < 4; ++dt)
        #pragma unroll
        for (int r = 0; r < 4; ++r)
            Om[(w * 16 + quad * 4 + r) * 64 + dt * 16 + l16] = o[dt][r];
    if (l16 == 0) {
        #pragma unroll
        for (int r = 0; r < 4; ++r) {
            mm[w * 16 + quad * 4 + r] = m[r];
            lm[w * 16 + quad * 4 + r] = lsum[r];
        }
    }
    __syncthreads();

    const int q = tid >> 4, dg = tid & 15;
    float M = -1e30f;
    #pragma unroll
    for (int w2 = 0; w2 < 4; ++w2) M = fmaxf(M, mm[w2 * 16 + q]);
    float L = 0.f;
    float4 acc = {0.f, 0.f, 0.f, 0.f};
    #pragma unroll
    for (int w2 = 0; w2 < 4; ++w2) {
        float e = __expf(mm[w2 * 16 + q] - M);
        L += e * lm[w2 * 16 + q];
        float4 ov = *(const float4*)&Om[(w2 * 16 + q) * 64 + dg * 4];
        acc.x += e * ov.x; acc.y += e * ov.y; acc.z += e * ov.z; acc.w += e * ov.w;
    }
    float inv = 1.0f / L;
    float4 r4;
    r4.x = acc.x * inv; r4.y = acc.y * inv; r4.z = acc.z * inv; r4.w = acc.w * inv;
    int row = (hv >> 2) * 1024 + n0 + q;
    *(float4*)&out[(size_t)row * 256 + (hv & 3) * 64 + dg * 4] = r4;
}

// ---------------------------------------------------------------------------
// LayerNorm (512) + exact GELU, wave-per-row (4 rows/block), no barriers.
// ---------------------------------------------------------------------------
__global__ __launch_bounds__(256) void lngelu_k(
    float* __restrict__ x, const float* __restrict__ g,
    const float* __restrict__ beta)
{
    int row = blockIdx.x * 4 + (threadIdx.x >> 6);
    int lane = threadIdx.x & 63;
    float* xr = x + (size_t)row * 512;
    float4 v0 = *(const float4*)&xr[lane * 4];
    float4 v1 = *(const float4*)&xr[256 + lane * 4];
    float s = v0.x + v0.y + v0.z + v0.w + v1.x + v1.y + v1.z + v1.w;
    #pragma unroll
    for (int ofs = 1; ofs < 64; ofs <<= 1) s += __shfl_xor(s, ofs);
    float mu = s * (1.0f / 512.0f);
    float d0x = v0.x - mu, d0y = v0.y - mu, d0z = v0.z - mu, d0w = v0.w - mu;
    float d1x = v1.x - mu, d1y = v1.y - mu, d1z = v1.z - mu, d1w = v1.w - mu;
    float vv = d0x*d0x + d0y*d0y + d0z*d0z + d0w*d0w
             + d1x*d1x + d1y*d1y + d1z*d1z + d1w*d1w;
    #pragma unroll
    for (int ofs = 1; ofs < 64; ofs <<= 1) vv += __shfl_xor(vv, ofs);
    float rstd = rsqrtf(vv * (1.0f / 512.0f) + 1e-5f);
    const float IS2 = 0.70710678118654752f;
    float4 o0, o1;
    {
        float4 gg = *(const float4*)&g[lane * 4];
        float4 bb = *(const float4*)&beta[lane * 4];
        float y;
        y = d0x * rstd * gg.x + bb.x; o0.x = 0.5f * y * (1.0f + erff(y * IS2));
        y = d0y * rstd * gg.y + bb.y; o0.y = 0.5f * y * (1.0f + erff(y * IS2));
        y = d0z * rstd * gg.z + bb.z; o0.z = 0.5f * y * (1.0f + erff(y * IS2));
        y = d0w * rstd * gg.w + bb.w; o0.w = 0.5f * y * (1.0f + erff(y * IS2));
    }
    {
        float4 gg = *(const float4*)&g[256 + lane * 4];
        float4 bb = *(const float4*)&beta[256 + lane * 4];
        float y;
        y = d1x * rstd * gg.x + bb.x; o1.x = 0.5f * y * (1.0f + erff(y * IS2));
        y = d1y * rstd * gg.y + bb.y; o1.y = 0.5f * y * (1.0f + erff(y * IS2));
        y = d1z * rstd * gg.z + bb.z; o1.z = 0.5f * y * (1.0f + erff(y * IS2));
        y = d1w * rstd * gg.w + bb.w; o1.w = 0.5f * y * (1.0f + erff(y * IS2));
    }
    *(float4*)&xr[lane * 4]       = o0;
    *(float4*)&xr[256 + lane * 4] = o1;
}

__global__ __launch_bounds__(256) void z_k(
    const float* __restrict__ x, const float* __restrict__ Wz,
    const float* __restrict__ bz, float* __restrict__ z)
{
    int row = blockIdx.x, t = threadIdx.x;
    __shared__ float red[256];
    red[t] = x[(size_t)row * 256 + t] * Wz[t];
    __syncthreads();
    for (int s = 128; s > 0; s >>= 1) {
        if (t < s) red[t] += red[t + s];
        __syncthreads();
    }
    if (t == 0) z[row] = red[0] + bz[0];
}

// Row lse (blocks 0..1023) and col lse (blocks 1024..2047) in one dispatch.
__global__ __launch_bounds__(256) void lse_k(
    const float* __restrict__ sim, float* __restrict__ rls,
    float* __restrict__ cls)
{
    const int b = blockIdx.x, t = threadIdx.x;
    const int isCol = b >> 10, rc = b & 1023;
    const size_t base = isCol ? (size_t)rc : (size_t)rc * 1024;
    const size_t stride = isCol ? 1024 : 1;
    __shared__ float red[256];
    float mx = -1e30f;
    for (int j = t; j < NTOK; j += 256) mx = fmaxf(mx, sim[base + stride * j]);
    red[t] = mx; __syncthreads();
    for (int s = 128; s > 0; s >>= 1) {
        if (t < s) red[t] = fmaxf(red[t], red[t + s]);
        __syncthreads();
    }
    mx = red[0]; __syncthreads();
    float sum = 0.0f;
    for (int j = t; j < NTOK; j += 256) sum += expf(sim[base + stride * j] - mx);
    red[t] = sum; __syncthreads();
    for (int s = 128; s > 0; s >>= 1) {
        if (t < s) red[t] += red[t + s];
        __syncthreads();
    }
    if (t == 0) (isCol ? cls : rls)[rc] = mx + logf(red[0]);
}

__global__ __launch_bounds__(256) void assemble_k(
    const float* __restrict__ sim, const float* __restrict__ rls,
    const float* __restrict__ cls, const float* __restrict__ z0,
    const float* __restrict__ z1, float* __restrict__ out)
{
    int idx = blockIdx.x * 256 + threadIdx.x;
    const int W = NTOK + 1;
    if (idx >= W * W) return;
    int i = idx / W, j = idx % W;
    float v;
    if (i < NTOK && j < NTOK) {
        v = 2.0f * sim[(size_t)i * NTOK + j] - rls[i] - cls[j] + logsigf(z0[i]) + logsigf(z1[j]);
    } else if (i < NTOK) {
        v = logsigf(-z0[i]);
    } else if (j < NTOK) {
        v = logsigf(-z1[j]);
    } else {
        v = 0.0f;
    }
    out[idx] = v;
}

// ---------------------------------------------------------------------------
extern "C" void kernel_launch(void* const* d_in, const int* in_sizes, int n_in,
                              void* d_out, int out_size, void* d_ws, size_t ws_size,
                              hipStream_t stream)
{
    const float* desc0 = (const float*)d_in[0];
    const float* desc1 = (const float*)d_in[1];
    const float* kpts0 = (const float*)d_in[2];
    const float* kpts1 = (const float*)d_in[3];
    const float* Wr    = (const float*)d_in[4];
    const float* sWqkv = (const float*)d_in[5];
    const float* sbqkv = (const float*)d_in[6];
    const float* sWo   = (const float*)d_in[7];
    const float* sbo   = (const float*)d_in[8];
    const float* sfW1  = (const float*)d_in[9];
    const float* sfb1  = (const float*)d_in[10];
    const float* sfg   = (const float*)d_in[11];
    const float* sfbt  = (const float*)d_in[12];
    const float* sfW2  = (const float*)d_in[13];
    const float* sfb2  = (const float*)d_in[14];
    const float* cWqk  = (const float*)d_in[15];
    const float* cbqk  = (const float*)d_in[16];
    const float* cWv   = (const float*)d_in[17];
    const float* cbv   = (const float*)d_in[18];
    const float* cWo   = (const float*)d_in[19];
    const float* cbo   = (const float*)d_in[20];
    const float* cfW1  = (const float*)d_in[21];
    const float* cfb1  = (const float*)d_in[22];
    const float* cfg   = (const float*)d_in[23];
    const float* cfbt  = (const float*)d_in[24];
    const float* cfW2  = (const float*)d_in[25];
    const float* cfb2  = (const float*)d_in[26];
    const float* mWp   = (const float*)d_in[27];
    const float* mbp   = (const float*)d_in[28];
    const float* mWz   = (const float*)d_in[29];
    const float* mbz   = (const float*)d_in[30];

    float* ws = (float*)d_ws;
    // Layout (float units). qh/kh/vh = 8*1024*64 bf16 = 262144 fl EACH.
    float* x    = ws;                      // 524288  [2048][256] fp32
    float* encc = ws + 524288;             // 131072  [2048][64]
    float* encs = ws + 655360;             // 131072
    float* qkv  = ws + 786432;             // 1572864 [2048][768] fp32 (self only)
    float* pre  = qkv + 524288;            // 1048576 [2048][512]
    __bf16* qh  = (__bf16*)(ws + 2359296); // 262144 fl = 524288 bf16
    __bf16* kh  = (__bf16*)(ws + 2621440); // 262144 fl
    __bf16* vh  = (__bf16*)(ws + 2883584); // 262144 fl
    float* msg  = ws + 3145728;            // 524288  [2048][256] fp32
    float* zb   = ws + 3670016;            // 2048
    float* rlsb = ws + 3672064;            // 1024
    float* clsb = ws + 3673088;            // 1024
    float* sim  = qkv;                     // 1048576 (assignment; qkv/pre dead)
    float* md   = msg;

    // bf16 pre-transposed weights [N][K] (11,272,192 bf16 = 5,636,096 fl).
    __bf16* wb    = (__bf16*)(ws + 3674112);
    __bf16* tWqkv = wb;                    // 9*768*256
    __bf16* tWo   = tWqkv + 1769472;
    __bf16* tW1   = tWo   + 589824;
    __bf16* tW2   = tW1   + 2359296;
    __bf16* tcQk  = tW2   + 1179648;
    __bf16* tcV   = tcQk  + 589824;
    __bf16* tcWo  = tcV   + 589824;
    __bf16* tcW1  = tcWo  + 589824;
    __bf16* tcW2  = tcW1  + 2359296;
    __bf16* tmWp  = tcW2  + 1179648;       // 65536
    // fused FFN1 weights [512][512] x 18 (self 0..8, cross 9..17)
    __bf16* tW1f  = (__bf16*)(ws + 9310208);   // 4718592 bf16 = 2359296 fl
    float*  bfb   = ws + 11669504;             // 18*512 = 9216 fl
    // total 11678720 fl = 46.7 MB

    // ---- one-time: transposes, weight fusion, bias fusion ----
    wtrans_all_k<<<dim3(24, 16, 82), 256, 0, stream>>>(
        sWqkv, sWo, sfW1, sfW2, cWqk, cWv, cWo, cfW1, cfW2, mWp, wb);
    wfuse_k<<<dim3(8, 16, 18), 256, 0, stream>>>(tW1, tWo, tcW1, tcWo, tW1f);
    bfuse_k<<<dim3(2, 18), 256, 0, stream>>>(sbo, sfW1, sfb1, cbo, cfW1, cfb1, bfb);

    auto gemmb = [&](const float* A0, const float* A1, const __bf16* Bt,
                     const float* bias, const float* R, float* C,
                     int M, int K, int Nn, int ldc, float scale) {
        gemm_bf_k<<<dim3(Nn / 64, M / 32), 256, 0, stream>>>(A0, A1, Bt, bias, R, C, M, K, Nn, ldc, scale);
    };

    const float SELF_SCALE  = 0.125f;               // DH^-0.5
    const float CROSS_SCALE = 0.35355339059327373f; // DH^-0.25

    init_k<<<2304, 256, 0, stream>>>(desc0, desc1, kpts0, kpts1, Wr, x, encc, encs);

    for (int l = 0; l < NL; ++l) {
        // ---- self block (both images batched) ----
        gemmb(x, nullptr, tWqkv + (size_t)l * 196608, sbqkv + (size_t)l * 768,
              nullptr, qkv, 2048, 256, 768, 768, 1.0f);
        splitrope_k<<<2048, 256, 0, stream>>>(qkv, encc, encs, qh, kh, vh);
        attn_k<<<dim3(64, 8), 256, 0, stream>>>(qh, kh, vh, msg, SELF_SCALE, 0);
        // FFN1' : pre = x@W1a + msg@Wf + bfused    (Wo folded into Wf)
        gemmb(x, msg, tW1f + (size_t)l * 262144, bfb + (size_t)l * 512,
              nullptr, pre, 2048, 512, 512, 512, 1.0f);
        lngelu_k<<<512, 256, 0, stream>>>(pre, sfg + (size_t)l * 512, sfbt + (size_t)l * 512);
        gemmb(pre, nullptr, tW2 + (size_t)l * 131072, sfb2 + (size_t)l * 256,
              x, x, 2048, 512, 256, 256, 1.0f);

        // ---- cross block ----
        gemm_hm2_k<<<dim3(8, 64), 256, 0, stream>>>(
            x, tcQk + (size_t)l * 65536, cbqk + (size_t)l * 256,
            tcV + (size_t)l * 65536, cbv + (size_t)l * 256,
            qh, vh, CROSS_SCALE);
        attn_k<<<dim3(64, 8), 256, 0, stream>>>(qh, qh, vh, msg, 1.0f, 1);
        gemmb(x, msg, tW1f + (size_t)(9 + l) * 262144, bfb + (size_t)(9 + l) * 512,
              nullptr, pre, 2048, 512, 512, 512, 1.0f);
        lngelu_k<<<512, 256, 0, stream>>>(pre, cfg + (size_t)l * 512, cfbt + (size_t)l * 512);
        gemmb(pre, nullptr, tcW2 + (size_t)l * 131072, cfb2 + (size_t)l * 256,
              x, x, 2048, 512, 256, 256, 1.0f);
    }

    // ---- assignment head ----
    const float MD_SCALE = 0.25f; // D^-0.25
    gemmb(x, nullptr, tmWp, mbp, nullptr, md, 2048, 256, 256, 256, MD_SCALE);
    z_k<<<2048, 256, 0, stream>>>(x, mWz, mbz, zb);
    gemm_f32t_k<<<dim3(16, 32), 256, 0, stream>>>(md, md + 1024 * 256, sim, 256, 1024);
    lse_k<<<2048, 256, 0, stream>>>(sim, rlsb, clsb);
    const int W = NTOK + 1;
    assemble_k<<<(W * W + 255) / 256, 256, 0, stream>>>(sim, rlsb, clsb, zb, zb + 1024, (float*)d_out);
}

// Round 13
// 987.280 us; speedup vs baseline: 19.4418x; 1.0443x over previous
//
#include <hip/hip_runtime.h>
#include <cmath>

// LightGlue forward. All GEMMs + attention in bf16 MFMA. Q/K/V written bf16
// head-major directly by the qkv GEMM epilogue (RoPE fused via lane-shuffle,
// weights column-permuted at the one-time transpose). msg and LN+GELU outputs
// stored bf16 by their producers. Wo folded into W1 (Wf = Wo@W1b).
// N=1024, D=256, H=4, DH=64, L=9. Batched over both images (M=2048).
#define NTOK 1024
#define DM   256
#define NH   4
#define DH   64
#define NL   9

typedef __attribute__((ext_vector_type(8))) __bf16 bf16x8;
typedef __attribute__((ext_vector_type(4))) __bf16 bf16x4;
typedef __attribute__((ext_vector_type(4))) float  f32x4;

__device__ __forceinline__ float logsigf(float x) {
    return fminf(x, 0.0f) - log1pf(expf(-fabsf(x)));
}

__device__ __forceinline__ __bf16 f2bf(float f) {
    unsigned u = __float_as_uint(f);
    u = (u + 0x7FFFu + ((u >> 16) & 1u)) >> 16;          // round-nearest-even
    unsigned short s = (unsigned short)u;
    return __builtin_bit_cast(__bf16, s);
}

// ---------------------------------------------------------------------------
// All weight transposes in ONE dispatch. fp32 [K][N] (batched) -> bf16 [N][K].
// For the qkv group (z<9) output rows are PERMUTED: n' = t*256 + h*64 + d
// (orig n = h*192 + d*3 + t) so the GEMM tile maps 1:1 to (type, head).
// Grid (24, 16, 82).
// ---------------------------------------------------------------------------
__global__ __launch_bounds__(256) void wtrans_all_k(
    const float* __restrict__ sWqkv, const float* __restrict__ sWo,
    const float* __restrict__ sfW1,  const float* __restrict__ sfW2,
    const float* __restrict__ cWqk,  const float* __restrict__ cWv,
    const float* __restrict__ cWo,   const float* __restrict__ cfW1,
    const float* __restrict__ cfW2,  const float* __restrict__ mWp,
    __bf16* __restrict__ wb)
{
    const int z = blockIdx.z;
    const float* src; __bf16* dst; int K, N, b;
    if      (z <  9) { src = sWqkv; dst = wb;            K = 256; N = 768; b = z;      }
    else if (z < 18) { src = sWo;   dst = wb + 1769472;  K = 256; N = 256; b = z - 9;  }
    else if (z < 27) { src = sfW1;  dst = wb + 2359296;  K = 512; N = 512; b = z - 18; }
    else if (z < 36) { src = sfW2;  dst = wb + 4718592;  K = 512; N = 256; b = z - 27; }
    else if (z < 45) { src = cWqk;  dst = wb + 5898240;  K = 256; N = 256; b = z - 36; }
    else if (z < 54) { src = cWv;   dst = wb + 6488064;  K = 256; N = 256; b = z - 45; }
    else if (z < 63) { src = cWo;   dst = wb + 7077888;  K = 256; N = 256; b = z - 54; }
    else if (z < 72) { src = cfW1;  dst = wb + 7667712;  K = 512; N = 512; b = z - 63; }
    else if (z < 81) { src = cfW2;  dst = wb + 10027008; K = 512; N = 256; b = z - 72; }
    else             { src = mWp;   dst = wb + 11206656; K = 256; N = 256; b = 0;      }
    const int n0 = blockIdx.x * 32, k0 = blockIdx.y * 32;
    if (n0 >= N || k0 >= K) return;
    src += (size_t)b * K * N;
    dst += (size_t)b * K * N;

    __shared__ __bf16 t[32][36];
    const int tx = threadIdx.x & 31, ty = threadIdx.x >> 5;
    #pragma unroll
    for (int i = 0; i < 4; ++i) {
        int k = ty + i * 8;
        t[tx][k] = f2bf(src[(size_t)(k0 + k) * N + n0 + tx]);
    }
    __syncthreads();
    const int nr = threadIdx.x >> 3, kc = (threadIdx.x & 7) * 4;
    bf16x4 v = *(const bf16x4*)&t[nr][kc];
    int outr = n0 + nr;
    if (z < 9) {
        int h = outr / 192, r = outr % 192;
        outr = (r % 3) * 256 + h * 64 + (r / 3);
    }
    *(bf16x4*)&dst[(size_t)outr * K + k0 + kc] = v;
}

// ---------------------------------------------------------------------------
// Weight fusion: tW1f[z][o][0:256] = tW1[z][o][0:256] (copy, bx<4);
// tW1f[z][o][256+k] = sum_m tW1[z][o][256+m] * tWo[z][m][k]  (bx>=4, MFMA).
// ---------------------------------------------------------------------------
__global__ __launch_bounds__(256) void wfuse_k(
    const __bf16* __restrict__ tW1s, const __bf16* __restrict__ tWos,
    const __bf16* __restrict__ tW1c, const __bf16* __restrict__ tWoc,
    __bf16* __restrict__ tW1f)
{
    const int z = blockIdx.z, bx = blockIdx.x, tid = threadIdx.x;
    const __bf16* A  = (z < 9) ? tW1s + (size_t)z * 262144 : tW1c + (size_t)(z - 9) * 262144;
    const __bf16* B  = (z < 9) ? tWos + (size_t)z * 65536  : tWoc + (size_t)(z - 9) * 65536;
    __bf16* dst      = tW1f + (size_t)z * 262144;
    const int row0 = blockIdx.y * 32;

    if (bx < 4) {
        const int row = tid >> 3, kc = (tid & 7) * 8;
        bf16x8 v = *(const bf16x8*)&A[(size_t)(row0 + row) * 512 + bx * 64 + kc];
        *(bf16x8*)&dst[(size_t)(row0 + row) * 512 + bx * 64 + kc] = v;
        return;
    }

    __shared__ __bf16 As[8][32][40];
    __shared__ __bf16 Bs[8][64][40];
    const int w = tid >> 6, l = tid & 63;
    const int col0 = (bx - 4) * 64;
    const int wr = (w >> 1) * 16, wc = (w & 1) * 32;
    f32x4 acc0 = {0.f, 0.f, 0.f, 0.f};
    f32x4 acc1 = {0.f, 0.f, 0.f, 0.f};

    const int ar = tid >> 3, ac = (tid & 7) * 4;
    const int tnr = tid >> 3, tkc = (tid & 7) * 8;

    #pragma unroll
    for (int c = 0; c < 8; ++c) {
        bf16x4 av = *(const bf16x4*)&A[(size_t)(row0 + ar) * 512 + 256 + c * 32 + ac];
        *(bf16x4*)&As[c][ar][ac] = av;
        bf16x8 bv = *(const bf16x8*)&B[(size_t)(c * 32 + tnr) * 256 + col0 + tkc];
        #pragma unroll
        for (int e = 0; e < 8; ++e) Bs[c][tkc + e][tnr] = bv[e];
    }
    __syncthreads();
    #pragma unroll
    for (int c = 0; c < 8; ++c) {
        bf16x8 af  = *(const bf16x8*)&As[c][wr + (l & 15)][(l >> 4) * 8];
        bf16x8 bf0 = *(const bf16x8*)&Bs[c][wc + (l & 15)][(l >> 4) * 8];
        bf16x8 bf1 = *(const bf16x8*)&Bs[c][wc + 16 + (l & 15)][(l >> 4) * 8];
        acc0 = __builtin_amdgcn_mfma_f32_16x16x32_bf16(af, bf0, acc0, 0, 0, 0);
        acc1 = __builtin_amdgcn_mfma_f32_16x16x32_bf16(af, bf1, acc1, 0, 0, 0);
    }
    #pragma unroll
    for (int t2 = 0; t2 < 2; ++t2) {
        f32x4 a = t2 ? acc1 : acc0;
        int cc = col0 + wc + t2 * 16 + (l & 15);
        #pragma unroll
        for (int rg = 0; rg < 4; ++rg) {
            int rr = row0 + wr + (l >> 4) * 4 + rg;
            dst[(size_t)rr * 512 + 256 + cc] = f2bf(a[rg]);
        }
    }
}

// bfused[z][o] = b1[z][o] + sum_m bo[z][m] * W1[z][256+m][o]   (fp32)
__global__ __launch_bounds__(256) void bfuse_k(
    const float* __restrict__ sbo, const float* __restrict__ sfW1,
    const float* __restrict__ sfb1, const float* __restrict__ cbo,
    const float* __restrict__ cfW1, const float* __restrict__ cfb1,
    float* __restrict__ bf)
{
    const int z = blockIdx.y;
    const float* bo = (z < 9) ? sbo + z * 256 : cbo + (z - 9) * 256;
    const float* W1 = (z < 9) ? sfW1 + (size_t)z * 262144 : cfW1 + (size_t)(z - 9) * 262144;
    const float* b1 = (z < 9) ? sfb1 + z * 512 : cfb1 + (z - 9) * 512;
    const int o = blockIdx.x * 256 + threadIdx.x;
    float acc = 0.f;
    for (int m = 0; m < 256; ++m)
        acc += bo[m] * W1[(size_t)(256 + m) * 512 + o];
    bf[(size_t)z * 512 + o] = b1[o] + acc;
}

// ---------------------------------------------------------------------------
// qkv GEMM with fused RoPE + head-major bf16 store. K=256, Nn=768 (permuted:
// col' = t*256 + h*64 + d). Grid (12, 64). Each 64-col tile = one (t, h).
// RoPE pair d^1 lives in the adjacent column = lane^1 -> __shfl_xor.
// ---------------------------------------------------------------------------
__global__ __launch_bounds__(256) void gemm_qkv_k(
    const float* __restrict__ A, const __bf16* __restrict__ Bt,
    const float* __restrict__ bias,   // original order [768]
    const float* __restrict__ encc, const float* __restrict__ encs,
    __bf16* __restrict__ qh, __bf16* __restrict__ kh, __bf16* __restrict__ vh)
{
    __shared__ __bf16 As[8][32][40];
    __shared__ __bf16 Bs[8][64][40];
    const int tid = threadIdx.x;
    const int w = tid >> 6, l = tid & 63;
    const int row0 = blockIdx.y * 32, col0 = blockIdx.x * 64;
    const int wr = (w >> 1) * 16, wc = (w & 1) * 32;
    const int quad = l >> 4, l16 = l & 15;
    f32x4 acc0 = {0.f, 0.f, 0.f, 0.f};
    f32x4 acc1 = {0.f, 0.f, 0.f, 0.f};

    const int ar = tid >> 3, ac = (tid & 7) * 4;
    const int bnr = tid >> 2, bkc = (tid & 3) * 8;

    #pragma unroll
    for (int c = 0; c < 8; ++c) {
        const int k0 = c * 32;
        float4 v = *(const float4*)&A[(size_t)(row0 + ar) * 256 + k0 + ac];
        __bf16* d = &As[c][ar][ac];
        d[0] = f2bf(v.x); d[1] = f2bf(v.y); d[2] = f2bf(v.z); d[3] = f2bf(v.w);
        bf16x8 bv = *(const bf16x8*)&Bt[(size_t)(col0 + bnr) * 256 + k0 + bkc];
        *(bf16x8*)&Bs[c][bnr][bkc] = bv;
    }
    __syncthreads();
    #pragma unroll
    for (int c = 0; c < 8; ++c) {
        bf16x8 af  = *(const bf16x8*)&As[c][wr + l16][quad * 8];
        bf16x8 bf0 = *(const bf16x8*)&Bs[c][wc + l16][quad * 8];
        bf16x8 bf1 = *(const bf16x8*)&Bs[c][wc + 16 + l16][quad * 8];
        acc0 = __builtin_amdgcn_mfma_f32_16x16x32_bf16(af, bf0, acc0, 0, 0, 0);
        acc1 = __builtin_amdgcn_mfma_f32_16x16x32_bf16(af, bf1, acc1, 0, 0, 0);
    }

    // ---- epilogue: bias + RoPE (q,k) + head-major bf16 store ----
    const int typ = col0 >> 8;            // 0=q 1=k 2=v
    const int hh  = (col0 & 255) >> 6;
    __bf16* dst = (typ == 0) ? qh : (typ == 1) ? kh : vh;
    #pragma unroll
    for (int t2 = 0; t2 < 2; ++t2) {
        f32x4 a = t2 ? acc1 : acc0;
        const int d = wc + t2 * 16 + l16;
        const float bvv = bias[hh * 192 + d * 3 + typ];
        float full[4], pair[4];
        #pragma unroll
        for (int rg = 0; rg < 4; ++rg) full[rg] = a[rg] + bvv;
        #pragma unroll
        for (int rg = 0; rg < 4; ++rg) pair[rg] = __shfl_xor(full[rg], 1);
        const float sgn = (d & 1) ? 1.0f : -1.0f;
        #pragma unroll
        for (int rg = 0; rg < 4; ++rg) {
            int rr = row0 + wr + quad * 4 + rg;
            float outv;
            if (typ == 2) {
                outv = full[rg];
            } else {
                float c = encc[(size_t)rr * 64 + d];
                float s = encs[(size_t)rr * 64 + d];
                outv = full[rg] * c + sgn * pair[rg] * s;
            }
            int im = rr >> 10, n = rr & 1023;
            dst[(((size_t)(im * 4 + hh)) * 1024 + n) * 64 + d] = f2bf(outv);
        }
    }
}

// ---------------------------------------------------------------------------
// Deep-staged bf16-MFMA GEMM: C = (A @ B + bias)*scale. fp32 A0 (cols<256),
// OPTIONAL bf16 A1b (cols>=256, ld 256). bf16 B [Nn][K]. fp32 C.
// ---------------------------------------------------------------------------
__global__ __launch_bounds__(256) void gemm_bf_k(
    const float* __restrict__ A0, const __bf16* __restrict__ A1b,
    const __bf16* __restrict__ Bt, const float* __restrict__ bias,
    float* __restrict__ C, int M, int K, int Nn, int ldc, float scale)
{
    __shared__ __bf16 As[8][32][40];
    __shared__ __bf16 Bs[8][64][40];
    const int tid = threadIdx.x;
    const int w = tid >> 6, l = tid & 63;
    const int row0 = blockIdx.y * 32, col0 = blockIdx.x * 64;
    const int wr = (w >> 1) * 16, wc = (w & 1) * 32;
    f32x4 acc0 = {0.f, 0.f, 0.f, 0.f};
    f32x4 acc1 = {0.f, 0.f, 0.f, 0.f};

    const int ar = tid >> 3, ac = (tid & 7) * 4;
    const int bnr = tid >> 2, bkc = (tid & 3) * 8;

    for (int p0 = 0; p0 < K; p0 += 256) {
        #pragma unroll
        for (int c = 0; c < 8; ++c) {
            const int k0 = p0 + c * 32;
            int kk = k0 + ac;
            if (A1b && kk >= 256) {
                bf16x4 v = *(const bf16x4*)&A1b[(size_t)(row0 + ar) * 256 + (kk - 256)];
                *(bf16x4*)&As[c][ar][ac] = v;
            } else {
                const float* src = A1b ? &A0[(size_t)(row0 + ar) * 256 + kk]
                                       : &A0[(size_t)(row0 + ar) * K + kk];
                float4 v = *(const float4*)src;
                __bf16* d = &As[c][ar][ac];
                d[0] = f2bf(v.x); d[1] = f2bf(v.y); d[2] = f2bf(v.z); d[3] = f2bf(v.w);
            }
            bf16x8 bv = *(const bf16x8*)&Bt[(size_t)(col0 + bnr) * K + k0 + bkc];
            *(bf16x8*)&Bs[c][bnr][bkc] = bv;
        }
        __syncthreads();
        #pragma unroll
        for (int c = 0; c < 8; ++c) {
            bf16x8 af  = *(const bf16x8*)&As[c][wr + (l & 15)][(l >> 4) * 8];
            bf16x8 bf0 = *(const bf16x8*)&Bs[c][wc + (l & 15)][(l >> 4) * 8];
            bf16x8 bf1 = *(const bf16x8*)&Bs[c][wc + 16 + (l & 15)][(l >> 4) * 8];
            acc0 = __builtin_amdgcn_mfma_f32_16x16x32_bf16(af, bf0, acc0, 0, 0, 0);
            acc1 = __builtin_amdgcn_mfma_f32_16x16x32_bf16(af, bf1, acc1, 0, 0, 0);
        }
        __syncthreads();
    }

    #pragma unroll
    for (int t2 = 0; t2 < 2; ++t2) {
        f32x4 a = t2 ? acc1 : acc0;
        int cc = col0 + wc + t2 * 16 + (l & 15);
        float bvv = bias ? bias[cc] : 0.0f;
        #pragma unroll
        for (int rg = 0; rg < 4; ++rg) {
            int rr = row0 + wr + (l >> 4) * 4 + rg;
            C[(size_t)rr * ldc + cc] = (a[rg] + bvv) * scale;
        }
    }
}

// ---------------------------------------------------------------------------
// FFN2 GEMM: bf16 A [M][512], bf16 B [Nn][512], fp32 C with residual R.
// K=512 (2 phases). Grid (Nn/64, M/32).
// ---------------------------------------------------------------------------
__global__ __launch_bounds__(256) void gemm_bfa_k(
    const __bf16* __restrict__ Ab, const __bf16* __restrict__ Bt,
    const float* __restrict__ bias, const float* __restrict__ R,
    float* __restrict__ C, int Nn)
{
    __shared__ __bf16 As[8][32][40];
    __shared__ __bf16 Bs[8][64][40];
    const int tid = threadIdx.x;
    const int w = tid >> 6, l = tid & 63;
    const int row0 = blockIdx.y * 32, col0 = blockIdx.x * 64;
    const int wr = (w >> 1) * 16, wc = (w & 1) * 32;
    f32x4 acc0 = {0.f, 0.f, 0.f, 0.f};
    f32x4 acc1 = {0.f, 0.f, 0.f, 0.f};

    const int ar = tid >> 3, ac = (tid & 7) * 4;
    const int bnr = tid >> 2, bkc = (tid & 3) * 8;

    for (int p0 = 0; p0 < 512; p0 += 256) {
        #pragma unroll
        for (int c = 0; c < 8; ++c) {
            const int k0 = p0 + c * 32;
            bf16x4 av = *(const bf16x4*)&Ab[(size_t)(row0 + ar) * 512 + k0 + ac];
            *(bf16x4*)&As[c][ar][ac] = av;
            bf16x8 bv = *(const bf16x8*)&Bt[(size_t)(col0 + bnr) * 512 + k0 + bkc];
            *(bf16x8*)&Bs[c][bnr][bkc] = bv;
        }
        __syncthreads();
        #pragma unroll
        for (int c = 0; c < 8; ++c) {
            bf16x8 af  = *(const bf16x8*)&As[c][wr + (l & 15)][(l >> 4) * 8];
            bf16x8 bf0 = *(const bf16x8*)&Bs[c][wc + (l & 15)][(l >> 4) * 8];
            bf16x8 bf1 = *(const bf16x8*)&Bs[c][wc + 16 + (l & 15)][(l >> 4) * 8];
            acc0 = __builtin_amdgcn_mfma_f32_16x16x32_bf16(af, bf0, acc0, 0, 0, 0);
            acc1 = __builtin_amdgcn_mfma_f32_16x16x32_bf16(af, bf1, acc1, 0, 0, 0);
        }
        __syncthreads();
    }

    #pragma unroll
    for (int t2 = 0; t2 < 2; ++t2) {
        f32x4 a = t2 ? acc1 : acc0;
        int cc = col0 + wc + t2 * 16 + (l & 15);
        float bvv = bias[cc];
        #pragma unroll
        for (int rg = 0; rg < 4; ++rg) {
            int rr = row0 + wr + (l >> 4) * 4 + rg;
            C[(size_t)rr * Nn + cc] = a[rg] + bvv + R[(size_t)rr * Nn + cc];
        }
    }
}

// ---------------------------------------------------------------------------
// Cross qk+v fused GEMM (deep-staged, K=256): grid (8, 64). bx<4 -> Wq, else Wv.
// ---------------------------------------------------------------------------
__global__ __launch_bounds__(256) void gemm_hm2_k(
    const float* __restrict__ A, const __bf16* __restrict__ Btq,
    const float* __restrict__ bq, const __bf16* __restrict__ Btv,
    const float* __restrict__ bv, __bf16* __restrict__ outq,
    __bf16* __restrict__ outv, float scaleq)
{
    const int bx = blockIdx.x;
    const __bf16* Bt  = (bx < 4) ? Btq : Btv;
    const float* bias = (bx < 4) ? bq : bv;
    __bf16* C         = (bx < 4) ? outq : outv;
    const float scale = (bx < 4) ? scaleq : 1.0f;

    __shared__ __bf16 As[8][32][40];
    __shared__ __bf16 Bs[8][64][40];
    const int tid = threadIdx.x;
    const int w = tid >> 6, l = tid & 63;
    const int row0 = blockIdx.y * 32, col0 = (bx & 3) * 64;
    const int wr = (w >> 1) * 16, wc = (w & 1) * 32;
    f32x4 acc0 = {0.f, 0.f, 0.f, 0.f};
    f32x4 acc1 = {0.f, 0.f, 0.f, 0.f};

    const int ar = tid >> 3, ac = (tid & 7) * 4;
    const int bnr = tid >> 2, bkc = (tid & 3) * 8;

    #pragma unroll
    for (int c = 0; c < 8; ++c) {
        const int k0 = c * 32;
        float4 v = *(const float4*)&A[(size_t)(row0 + ar) * 256 + k0 + ac];
        __bf16* d = &As[c][ar][ac];
        d[0] = f2bf(v.x); d[1] = f2bf(v.y); d[2] = f2bf(v.z); d[3] = f2bf(v.w);
        bf16x8 bv8 = *(const bf16x8*)&Bt[(size_t)(col0 + bnr) * 256 + k0 + bkc];
        *(bf16x8*)&Bs[c][bnr][bkc] = bv8;
    }
    __syncthreads();
    #pragma unroll
    for (int c = 0; c < 8; ++c) {
        bf16x8 af  = *(const bf16x8*)&As[c][wr + (l & 15)][(l >> 4) * 8];
        bf16x8 bf0 = *(const bf16x8*)&Bs[c][wc + (l & 15)][(l >> 4) * 8];
        bf16x8 bf1 = *(const bf16x8*)&Bs[c][wc + 16 + (l & 15)][(l >> 4) * 8];
        acc0 = __builtin_amdgcn_mfma_f32_16x16x32_bf16(af, bf0, acc0, 0, 0, 0);
        acc1 = __builtin_amdgcn_mfma_f32_16x16x32_bf16(af, bf1, acc1, 0, 0, 0);
    }

    #pragma unroll
    for (int t2 = 0; t2 < 2; ++t2) {
        f32x4 a = t2 ? acc1 : acc0;
        int cc = col0 + wc + t2 * 16 + (l & 15);
        float bvv = bias ? bias[cc] : 0.0f;
        int h = cc >> 6, d = cc & 63;
        #pragma unroll
        for (int rg = 0; rg < 4; ++rg) {
            int rr = row0 + wr + (l >> 4) * 4 + rg;
            int im = rr >> 10, n = rr & 1023;
            C[(((size_t)(im * 4 + h)) * 1024 + n) * 64 + d] = f2bf((a[rg] + bvv) * scale);
        }
    }
}

// ---------------------------------------------------------------------------
// sim = A @ B^T, fp32 A,B (both activations), K=256, deep-staged.
// ---------------------------------------------------------------------------
__global__ __launch_bounds__(256) void gemm_f32t_k(
    const float* __restrict__ A, const float* __restrict__ B,
    float* __restrict__ C, int K, int Nn)
{
    __shared__ __bf16 As[8][32][40];
    __shared__ __bf16 Bs[8][64][40];
    const int tid = threadIdx.x;
    const int w = tid >> 6, l = tid & 63;
    const int row0 = blockIdx.y * 32, col0 = blockIdx.x * 64;
    const int wr = (w >> 1) * 16, wc = (w & 1) * 32;
    f32x4 acc0 = {0.f, 0.f, 0.f, 0.f};
    f32x4 acc1 = {0.f, 0.f, 0.f, 0.f};

    const int ar = tid >> 3, ac = (tid & 7) * 4;
    const int tnr = tid >> 2, tkc = (tid & 3) * 8;

    #pragma unroll
    for (int c = 0; c < 8; ++c) {
        const int k0 = c * 32;
        float4 v = *(const float4*)&A[(size_t)(row0 + ar) * K + k0 + ac];
        __bf16* d = &As[c][ar][ac];
        d[0] = f2bf(v.x); d[1] = f2bf(v.y); d[2] = f2bf(v.z); d[3] = f2bf(v.w);
        float4 a = *(const float4*)&B[(size_t)(col0 + tnr) * K + k0 + tkc];
        float4 b = *(const float4*)&B[(size_t)(col0 + tnr) * K + k0 + tkc + 4];
        __bf16* d2 = &Bs[c][tnr][tkc];
        d2[0] = f2bf(a.x); d2[1] = f2bf(a.y); d2[2] = f2bf(a.z); d2[3] = f2bf(a.w);
        d2[4] = f2bf(b.x); d2[5] = f2bf(b.y); d2[6] = f2bf(b.z); d2[7] = f2bf(b.w);
    }
    __syncthreads();
    #pragma unroll
    for (int c = 0; c < 8; ++c) {
        bf16x8 af  = *(const bf16x8*)&As[c][wr + (l & 15)][(l >> 4) * 8];
        bf16x8 bf0 = *(const bf16x8*)&Bs[c][wc + (l & 15)][(l >> 4) * 8];
        bf16x8 bf1 = *(const bf16x8*)&Bs[c][wc + 16 + (l & 15)][(l >> 4) * 8];
        acc0 = __builtin_amdgcn_mfma_f32_16x16x32_bf16(af, bf0, acc0, 0, 0, 0);
        acc1 = __builtin_amdgcn_mfma_f32_16x16x32_bf16(af, bf1, acc1, 0, 0, 0);
    }

    #pragma unroll
    for (int t2 = 0; t2 < 2; ++t2) {
        f32x4 a = t2 ? acc1 : acc0;
        int cc = col0 + wc + t2 * 16 + (l & 15);
        #pragma unroll
        for (int rg = 0; rg < 4; ++rg) {
            int rr = row0 + wr + (l >> 4) * 4 + rg;
            C[(size_t)rr * Nn + cc] = a[rg];
        }
    }
}

// ---------------------------------------------------------------------------
// Fused init: desc copies + posenc for both images. Grid 2304 x 256.
// ---------------------------------------------------------------------------
__global__ __launch_bounds__(256) void init_k(
    const float* __restrict__ desc0, const float* __restrict__ desc1,
    const float* __restrict__ kpts0, const float* __restrict__ kpts1,
    const float* __restrict__ Wr, float* __restrict__ x,
    float* __restrict__ encc, float* __restrict__ encs)
{
    int idx = blockIdx.x * 256 + threadIdx.x;
    if (idx < 524288) {
        x[idx] = (idx < 262144) ? desc0[idx] : desc1[idx - 262144];
    } else {
        int p = idx - 524288;
        int im = p >> 15, q = p & 32767;
        int i = q >> 5, f = q & 31;
        const float* kp = im ? kpts1 : kpts0;
        float* ec = encc + im * 65536;
        float* es = encs + im * 65536;
        float pr = kp[i * 2] * Wr[f] + kp[i * 2 + 1] * Wr[32 + f];
        float c = cosf(pr), s = sinf(pr);
        ec[i * 64 + 2 * f] = c; ec[i * 64 + 2 * f + 1] = c;
        es[i * 64 + 2 * f] = s; es[i * 64 + 2 * f + 1] = s;
    }
}

// ---------------------------------------------------------------------------
// Attention v6: flash-style bf16 MFMA with K/V register prefetch pipelining.
// Output msg written bf16 [2048][256].
// ---------------------------------------------------------------------------
__global__ __launch_bounds__(256) void attn_k(
    const __bf16* __restrict__ Qg, const __bf16* __restrict__ Kg,
    const __bf16* __restrict__ Vg, __bf16* __restrict__ out,
    float scale, int cross)
{
    const int qt = blockIdx.x, hv = blockIdx.y;
    const int kvh = cross ? (hv ^ 4) : hv;
    const int tid = threadIdx.x;
    const int w = tid >> 6, lane = tid & 63;
    const int quad = lane >> 4, l16 = lane & 15;
    const int n0 = qt * 16;

    __shared__ __align__(16) char smem[44032];
    char* base = smem + w * 11008;
    __bf16* kb  = (__bf16*)(base);          // 32 x 72
    __bf16* vtb = (__bf16*)(base + 4608);   // 64 x 40
    __bf16* ptb = (__bf16*)(base + 9728);   // 16 x 40

    bf16x8 qf[2];
    {
        const bf16x8* Qp = (const bf16x8*)(Qg + (((size_t)hv * 1024) + n0 + l16) * 64);
        qf[0] = Qp[quad];
        qf[1] = Qp[4 + quad];
    }

    const __bf16* Kbase = Kg + (size_t)kvh * 1024 * 64;
    const __bf16* Vbase = Vg + (size_t)kvh * 1024 * 64;

    float m[4] = {-1e30f, -1e30f, -1e30f, -1e30f};
    float lsum[4] = {0.f, 0.f, 0.f, 0.f};
    f32x4 o[4] = {{0,0,0,0},{0,0,0,0},{0,0,0,0},{0,0,0,0}};

    const int kj = lane >> 1, kd = (lane & 1) * 32;
    const int vjp = lane & 15, vd0 = (lane >> 4) * 16;

    bf16x8 kr[4];
    uint4  vr[4];
    {
        const int j0 = w * 256;
        const bf16x8* kp = (const bf16x8*)(Kbase + (size_t)(j0 + kj) * 64 + kd);
        kr[0] = kp[0]; kr[1] = kp[1]; kr[2] = kp[2]; kr[3] = kp[3];
        const uint4* va = (const uint4*)(Vbase + (size_t)(j0 + 2 * vjp) * 64 + vd0);
        const uint4* vb = (const uint4*)(Vbase + (size_t)(j0 + 2 * vjp + 1) * 64 + vd0);
        vr[0] = va[0]; vr[1] = va[1]; vr[2] = vb[0]; vr[3] = vb[1];
    }

    for (int t = 0; t < 8; ++t) {
        {
            __bf16* krow = kb + kj * 72 + kd;
            *(bf16x8*)(krow)      = kr[0];
            *(bf16x8*)(krow + 8)  = kr[1];
            *(bf16x8*)(krow + 16) = kr[2];
            *(bf16x8*)(krow + 24) = kr[3];
            #pragma unroll
            for (int g = 0; g < 2; ++g) {
                uint4 ua = vr[g], ub = vr[2 + g];
                unsigned au[4] = {ua.x, ua.y, ua.z, ua.w};
                unsigned bu[4] = {ub.x, ub.y, ub.z, ub.w};
                #pragma unroll
                for (int e = 0; e < 4; ++e) {
                    int i = g * 8 + e * 2;
                    unsigned pk0 = ((bu[e] & 0xFFFFu) << 16) | (au[e] & 0xFFFFu);
                    unsigned pk1 = (bu[e] & 0xFFFF0000u) | (au[e] >> 16);
                    *(unsigned*)((char*)vtb + ((vd0 + i) * 40 + 2 * vjp) * 2)     = pk0;
                    *(unsigned*)((char*)vtb + ((vd0 + i + 1) * 40 + 2 * vjp) * 2) = pk1;
                }
            }
        }
        if (t < 7) {
            const int j1 = w * 256 + (t + 1) * 32;
            const bf16x8* kp = (const bf16x8*)(Kbase + (size_t)(j1 + kj) * 64 + kd);
            kr[0] = kp[0]; kr[1] = kp[1]; kr[2] = kp[2]; kr[3] = kp[3];
            const uint4* va = (const uint4*)(Vbase + (size_t)(j1 + 2 * vjp) * 64 + vd0);
            const uint4* vb = (const uint4*)(Vbase + (size_t)(j1 + 2 * vjp + 1) * 64 + vd0);
            vr[0] = va[0]; vr[1] = va[1]; vr[2] = vb[0]; vr[3] = vb[1];
        }

        f32x4 s0 = {0,0,0,0}, s1 = {0,0,0,0};
        #pragma unroll
        for (int kt = 0; kt < 2; ++kt) {
            bf16x8 k0 = *(const bf16x8*)(kb + (0 * 16 + l16) * 72 + kt * 32 + quad * 8);
            bf16x8 k1 = *(const bf16x8*)(kb + (1 * 16 + l16) * 72 + kt * 32 + quad * 8);
            s0 = __builtin_amdgcn_mfma_f32_16x16x32_bf16(qf[kt], k0, s0, 0, 0, 0);
            s1 = __builtin_amdgcn_mfma_f32_16x16x32_bf16(qf[kt], k1, s1, 0, 0, 0);
        }

        float rm[4], p0[4], p1[4], rs[4];
        #pragma unroll
        for (int r = 0; r < 4; ++r) {
            s0[r] *= scale; s1[r] *= scale;
            rm[r] = fmaxf(s0[r], s1[r]);
        }
        #pragma unroll
        for (int ofs = 1; ofs < 16; ofs <<= 1)
            #pragma unroll
            for (int r = 0; r < 4; ++r)
                rm[r] = fmaxf(rm[r], __shfl_xor(rm[r], ofs));
        #pragma unroll
        for (int r = 0; r < 4; ++r) {
            float mn = fmaxf(m[r], rm[r]);
            float alpha = __expf(m[r] - mn);
            m[r] = mn;
            p0[r] = __expf(s0[r] - mn);
            p1[r] = __expf(s1[r] - mn);
            rs[r] = p0[r] + p1[r];
            lsum[r] *= alpha;
            #pragma unroll
            for (int dt = 0; dt < 4; ++dt) o[dt][r] *= alpha;
        }
        #pragma unroll
        for (int ofs = 1; ofs < 16; ofs <<= 1)
            #pragma unroll
            for (int r = 0; r < 4; ++r)
                rs[r] += __shfl_xor(rs[r], ofs);
        #pragma unroll
        for (int r = 0; r < 4; ++r) lsum[r] += rs[r];

        #pragma unroll
        for (int r = 0; r < 4; ++r) {
            ptb[(quad * 4 + r) * 40 + l16]      = f2bf(p0[r]);
            ptb[(quad * 4 + r) * 40 + 16 + l16] = f2bf(p1[r]);
        }
        bf16x8 pf = *(const bf16x8*)(ptb + l16 * 40 + quad * 8);
        #pragma unroll
        for (int dt = 0; dt < 4; ++dt) {
            bf16x8 vf = *(const bf16x8*)(vtb + (dt * 16 + l16) * 40 + quad * 8);
            o[dt] = __builtin_amdgcn_mfma_f32_16x16x32_bf16(pf, vf, o[dt], 0, 0, 0);
        }
    }

    __syncthreads();
    float* Om = (float*)smem;          // [64][64] : row = w*16 + q
    float* mm = Om + 4096;             // [64]
    float* lm = mm + 64;               // [64]
    #pragma unroll
    for (int dt = 0; dt < 4; ++dt)
        #pragma unroll
        for (int r = 0; r < 4; ++r)
            Om[(w * 16 + quad * 4 + r) * 64 + dt * 16 + l16] = o[dt][r];
    if (l16 == 0) {
        #pragma unroll
        for (int r = 0; r < 4; ++r) {
            mm[w * 16 + quad * 4 + r] = m[r];
            lm[w * 16 + quad * 4 + r] = lsum[r];
        }
    }
    __syncthreads();

    const int q = tid >> 4, dg = tid & 15;
    float M = -1e30f;
    #pragma unroll
    for (int w2 = 0; w2 < 4; ++w2) M = fmaxf(M, mm[w2 * 16 + q]);
    float L = 0.f;
    float4 acc = {0.f, 0.f, 0.f, 0.f};
    #pragma unroll
    for (int w2 = 0; w2 < 4; ++w2) {
        float e = __expf(mm[w2 * 16 + q] - M);
        L += e * lm[w2 * 16 + q];
        float4 ov = *(const float4*)&Om[(w2 * 16 + q) * 64 + dg * 4];
        acc.x += e * ov.x; acc.y += e * ov.y; acc.z += e * ov.z; acc.w += e * ov.w;
    }
    float inv = 1.0f / L;
    bf16x4 ob;
    ob[0] = f2bf(acc.x * inv); ob[1] = f2bf(acc.y * inv);
    ob[2] = f2bf(acc.z * inv); ob[3] = f2bf(acc.w * inv);
    int row = (hv >> 2) * 1024 + n0 + q;
    *(bf16x4*)&out[(size_t)row * 256 + (hv & 3) * 64 + dg * 4] = ob;
}

// ---------------------------------------------------------------------------
// LayerNorm (512) + exact GELU, wave-per-row, fp32 in -> bf16 out.
// ---------------------------------------------------------------------------
__global__ __launch_bounds__(256) void lngelu_k(
    const float* __restrict__ x, __bf16* __restrict__ outb,
    const float* __restrict__ g, const float* __restrict__ beta)
{
    int row = blockIdx.x * 4 + (threadIdx.x >> 6);
    int lane = threadIdx.x & 63;
    const float* xr = x + (size_t)row * 512;
    __bf16* ob = outb + (size_t)row * 512;
    float4 v0 = *(const float4*)&xr[lane * 4];
    float4 v1 = *(const float4*)&xr[256 + lane * 4];
    float s = v0.x + v0.y + v0.z + v0.w + v1.x + v1.y + v1.z + v1.w;
    #pragma unroll
    for (int ofs = 1; ofs < 64; ofs <<= 1) s += __shfl_xor(s, ofs);
    float mu = s * (1.0f / 512.0f);
    float d0x = v0.x - mu, d0y = v0.y - mu, d0z = v0.z - mu, d0w = v0.w - mu;
    float d1x = v1.x - mu, d1y = v1.y - mu, d1z = v1.z - mu, d1w = v1.w - mu;
    float vv = d0x*d0x + d0y*d0y + d0z*d0z + d0w*d0w
             + d1x*d1x + d1y*d1y + d1z*d1z + d1w*d1w;
    #pragma unroll
    for (int ofs = 1; ofs < 64; ofs <<= 1) vv += __shfl_xor(vv, ofs);
    float rstd = rsqrtf(vv * (1.0f / 512.0f) + 1e-5f);
    const float IS2 = 0.70710678118654752f;
    bf16x4 o0, o1;
    {
        float4 gg = *(const float4*)&g[lane * 4];
        float4 bb = *(const float4*)&beta[lane * 4];
        float y;
        y = d0x * rstd * gg.x + bb.x; o0[0] = f2bf(0.5f * y * (1.0f + erff(y * IS2)));
        y = d0y * rstd * gg.y + bb.y; o0[1] = f2bf(0.5f * y * (1.0f + erff(y * IS2)));
        y = d0z * rstd * gg.z + bb.z; o0[2] = f2bf(0.5f * y * (1.0f + erff(y * IS2)));
        y = d0w * rstd * gg.w + bb.w; o0[3] = f2bf(0.5f * y * (1.0f + erff(y * IS2)));
    }
    {
        float4 gg = *(const float4*)&g[256 + lane * 4];
        float4 bb = *(const float4*)&beta[256 + lane * 4];
        float y;
        y = d1x * rstd * gg.x + bb.x; o1[0] = f2bf(0.5f * y * (1.0f + erff(y * IS2)));
        y = d1y * rstd * gg.y + bb.y; o1[1] = f2bf(0.5f * y * (1.0f + erff(y * IS2)));
        y = d1z * rstd * gg.z + bb.z; o1[2] = f2bf(0.5f * y * (1.0f + erff(y * IS2)));
        y = d1w * rstd * gg.w + bb.w; o1[3] = f2bf(0.5f * y * (1.0f + erff(y * IS2)));
    }
    *(bf16x4*)&ob[lane * 4]       = o0;
    *(bf16x4*)&ob[256 + lane * 4] = o1;
}

__global__ __launch_bounds__(256) void z_k(
    const float* __restrict__ x, const float* __restrict__ Wz,
    const float* __restrict__ bz, float* __restrict__ z)
{
    int row = blockIdx.x, t = threadIdx.x;
    __shared__ float red[256];
    red[t] = x[(size_t)row * 256 + t] * Wz[t];
    __syncthreads();
    for (int s = 128; s > 0; s >>= 1) {
        if (t < s) red[t] += red[t + s];
        __syncthreads();
    }
    if (t == 0) z[row] = red[0] + bz[0];
}

// Row lse (blocks 0..1023) and col lse (blocks 1024..2047) in one dispatch.
__global__ __launch_bounds__(256) void lse_k(
    const float* __restrict__ sim, float* __restrict__ rls,
    float* __restrict__ cls)
{
    const int b = blockIdx.x, t = threadIdx.x;
    const int isCol = b >> 10, rc = b & 1023;
    const size_t base = isCol ? (size_t)rc : (size_t)rc * 1024;
    const size_t stride = isCol ? 1024 : 1;
    __shared__ float red[256];
    float mx = -1e30f;
    for (int j = t; j < NTOK; j += 256) mx = fmaxf(mx, sim[base + stride * j]);
    red[t] = mx; __syncthreads();
    for (int s = 128; s > 0; s >>= 1) {
        if (t < s) red[t] = fmaxf(red[t], red[t + s]);
        __syncthreads();
    }
    mx = red[0]; __syncthreads();
    float sum = 0.0f;
    for (int j = t; j < NTOK; j += 256) sum += expf(sim[base + stride * j] - mx);
    red[t] = sum; __syncthreads();
    for (int s = 128; s > 0; s >>= 1) {
        if (t < s) red[t] += red[t + s];
        __syncthreads();
    }
    if (t == 0) (isCol ? cls : rls)[rc] = mx + logf(red[0]);
}

__global__ __launch_bounds__(256) void assemble_k(
    const float* __restrict__ sim, const float* __restrict__ rls,
    const float* __restrict__ cls, const float* __restrict__ z0,
    const float* __restrict__ z1, float* __restrict__ out)
{
    int idx = blockIdx.x * 256 + threadIdx.x;
    const int W = NTOK + 1;
    if (idx >= W * W) return;
    int i = idx / W, j = idx % W;
    float v;
    if (i < NTOK && j < NTOK) {
        v = 2.0f * sim[(size_t)i * NTOK + j] - rls[i] - cls[j] + logsigf(z0[i]) + logsigf(z1[j]);
    } else if (i < NTOK) {
        v = logsigf(-z0[i]);
    } else if (j < NTOK) {
        v = logsigf(-z1[j]);
    } else {
        v = 0.0f;
    }
    out[idx] = v;
}

// ---------------------------------------------------------------------------
extern "C" void kernel_launch(void* const* d_in, const int* in_sizes, int n_in,
                              void* d_out, int out_size, void* d_ws, size_t ws_size,
                              hipStream_t stream)
{
    const float* desc0 = (const float*)d_in[0];
    const float* desc1 = (const float*)d_in[1];
    const float* kpts0 = (const float*)d_in[2];
    const float* kpts1 = (const float*)d_in[3];
    const float* Wr    = (const float*)d_in[4];
    const float* sWqkv = (const float*)d_in[5];
    const float* sbqkv = (const float*)d_in[6];
    const float* sWo   = (const float*)d_in[7];
    const float* sbo   = (const float*)d_in[8];
    const float* sfW1  = (const float*)d_in[9];
    const float* sfb1  = (const float*)d_in[10];
    const float* sfg   = (const float*)d_in[11];
    const float* sfbt  = (const float*)d_in[12];
    const float* sfW2  = (const float*)d_in[13];
    const float* sfb2  = (const float*)d_in[14];
    const float* cWqk  = (const float*)d_in[15];
    const float* cbqk  = (const float*)d_in[16];
    const float* cWv   = (const float*)d_in[17];
    const float* cbv   = (const float*)d_in[18];
    const float* cWo   = (const float*)d_in[19];
    const float* cbo   = (const float*)d_in[20];
    const float* cfW1  = (const float*)d_in[21];
    const float* cfb1  = (const float*)d_in[22];
    const float* cfg   = (const float*)d_in[23];
    const float* cfbt  = (const float*)d_in[24];
    const float* cfW2  = (const float*)d_in[25];
    const float* cfb2  = (const float*)d_in[26];
    const float* mWp   = (const float*)d_in[27];
    const float* mbp   = (const float*)d_in[28];
    const float* mWz   = (const float*)d_in[29];
    const float* mbz   = (const float*)d_in[30];

    float* ws = (float*)d_ws;
    // Layout (float units):
    float*  x    = ws;                      // 524288  [2048][256] fp32
    float*  encc = ws + 524288;             // 131072  [2048][64]
    float*  encs = ws + 655360;             // 131072
    float*  pre  = ws + 786432;             // 1048576 [2048][512] fp32
    __bf16* preb = (__bf16*)(ws + 1835008); // 524288 fl = [2048][512] bf16
    __bf16* qh   = (__bf16*)(ws + 2359296); // 262144 fl
    __bf16* kh   = (__bf16*)(ws + 2621440); // 262144 fl
    __bf16* vh   = (__bf16*)(ws + 2883584); // 262144 fl
    __bf16* msgb = (__bf16*)(ws + 3145728); // 131072 fl = [2048][256] bf16
    float*  zb   = ws + 3276800;            // 2048
    float*  rlsb = ws + 3278848;            // 1024
    float*  clsb = ws + 3279872;            // 1024
    float*  sim  = pre;                     // 1048576 (assignment; pre dead)
    float*  md   = ws + 1835008;            // 524288  (assignment; preb dead)

    // bf16 pre-transposed weights [N][K]
    __bf16* wb    = (__bf16*)(ws + 3280896);
    __bf16* tWqkv = wb;                     // 9*768*256 (rows permuted t*256+h*64+d)
    __bf16* tWo   = tWqkv + 1769472;
    __bf16* tW1   = tWo   + 589824;
    __bf16* tW2   = tW1   + 2359296;
    __bf16* tcQk  = tW2   + 1179648;
    __bf16* tcV   = tcQk  + 589824;
    __bf16* tcWo  = tcV   + 589824;
    __bf16* tcW1  = tcWo  + 589824;
    __bf16* tcW2  = tcW1  + 2359296;
    __bf16* tmWp  = tcW2  + 1179648;        // 65536   (wb total 11272192 bf16)
    __bf16* tW1f  = (__bf16*)(ws + 8916992);   // 4718592 bf16 = 2359296 fl
    float*  bfb   = ws + 11276288;             // 18*512 = 9216 fl  (total 45.1 MB)

    // ---- one-time: transposes (+qkv perm), weight fusion, bias fusion ----
    wtrans_all_k<<<dim3(24, 16, 82), 256, 0, stream>>>(
        sWqkv, sWo, sfW1, sfW2, cWqk, cWv, cWo, cfW1, cfW2, mWp, wb);
    wfuse_k<<<dim3(8, 16, 18), 256, 0, stream>>>(tW1, tWo, tcW1, tcWo, tW1f);
    bfuse_k<<<dim3(2, 18), 256, 0, stream>>>(sbo, sfW1, sfb1, cbo, cfW1, cfb1, bfb);

    const float SELF_SCALE  = 0.125f;               // DH^-0.5
    const float CROSS_SCALE = 0.35355339059327373f; // DH^-0.25

    init_k<<<2304, 256, 0, stream>>>(desc0, desc1, kpts0, kpts1, Wr, x, encc, encs);

    for (int l = 0; l < NL; ++l) {
        // ---- self block ----
        gemm_qkv_k<<<dim3(12, 64), 256, 0, stream>>>(
            x, tWqkv + (size_t)l * 196608, sbqkv + (size_t)l * 768,
            encc, encs, qh, kh, vh);
        attn_k<<<dim3(64, 8), 256, 0, stream>>>(qh, kh, vh, msgb, SELF_SCALE, 0);
        gemm_bf_k<<<dim3(8, 64), 256, 0, stream>>>(
            x, msgb, tW1f + (size_t)l * 262144, bfb + (size_t)l * 512,
            pre, 2048, 512, 512, 512, 1.0f);
        lngelu_k<<<512, 256, 0, stream>>>(pre, preb, sfg + (size_t)l * 512, sfbt + (size_t)l * 512);
        gemm_bfa_k<<<dim3(4, 64), 256, 0, stream>>>(
            preb, tW2 + (size_t)l * 131072, sfb2 + (size_t)l * 256, x, x, 256);

        // ---- cross block ----
        gemm_hm2_k<<<dim3(8, 64), 256, 0, stream>>>(
            x, tcQk + (size_t)l * 65536, cbqk + (size_t)l * 256,
            tcV + (size_t)l * 65536, cbv + (size_t)l * 256,
            qh, vh, CROSS_SCALE);
        attn_k<<<dim3(64, 8), 256, 0, stream>>>(qh, qh, vh, msgb, 1.0f, 1);
        gemm_bf_k<<<dim3(8, 64), 256, 0, stream>>>(
            x, msgb, tW1f + (size_t)(9 + l) * 262144, bfb + (size_t)(9 + l) * 512,
            pre, 2048, 512, 512, 512, 1.0f);
        lngelu_k<<<512, 256, 0, stream>>>(pre, preb, cfg + (size_t)l * 512, cfbt + (size_t)l * 512);
        gemm_bfa_k<<<dim3(4, 64), 256, 0, stream>>>(
            preb, tcW2 + (size_t)l * 131072, cfb2 + (size_t)l * 256, x, x, 256);
    }

    // ---- assignment head ----
    const float MD_SCALE = 0.25f; // D^-0.25
    gemm_bf_k<<<dim3(4, 64), 256, 0, stream>>>(
        x, nullptr, tmWp, mbp, md, 2048, 256, 256, 256, MD_SCALE);
    z_k<<<2048, 256, 0, stream>>>(x, mWz, mbz, zb);
    gemm_f32t_k<<<dim3(16, 32), 256, 0, stream>>>(md, md + 1024 * 256, sim, 256, 1024);
    lse_k<<<2048, 256, 0, stream>>>(sim, rlsb, clsb);
    const int W = NTOK + 1;
    assemble_k<<<(W * W + 255) / 256, 256, 0, stream>>>(sim, rlsb, clsb, zb, zb + 1024, (float*)d_out);
}